// Round 9
// baseline (217.567 us; speedup 1.0000x reference)
//
#include <hip/hip_runtime.h>
#include <hip/hip_cooperative_groups.h>
#include <hip/hip_bf16.h>
#include <stdint.h>

namespace cg = cooperative_groups;

#define DD 4
#define NVERT 5
#define NPTS 1024
#define BATCH 4
#define M0 5120           /* NPTS*NVERT */
#define CIN 64
#define COUT 64
#define NF 31
#define KTOT 1984         /* NF*CIN */
#define CAP 16384
#define CAPMASK (CAP-1)
#define SENTV 1073741824  /* 2^30, > any valid code (<128^4) */
#define ZROW (BATCH*M0)   /* zero row index in table_bf */
#define NB 256
#define NT 512
#define NTILES (BATCH*(M0/64))   /* 320 conv tiles */

using bf16x8 = __attribute__((ext_vector_type(8))) short;
using f32x4  = __attribute__((ext_vector_type(4))) float;

__device__ __forceinline__ unsigned short f2bf(float x){
  unsigned int u = __float_as_uint(x);
  u = (u + 0x7FFFu + ((u >> 16) & 1u)) >> 16;
  return (unsigned short)u;
}

__device__ __forceinline__ uint32_t hslot(int code){
  return (((uint32_t)code * 2654435761u) >> 18) & CAPMASK;
}

struct Params {
  const float* data; const float* feat; const float* wk;
  const float* bias; const float* bmul; float* out;
  int* codes_pv; float* bary_pv; int* idx_pv;
  int* hash_code; int* hash_uid; int* ucount; int* ukeys;
  float* table; float* out_lat;
  unsigned short* bp; unsigned short* table_bf;
  float* dat_t; int* nuid;
};

// ---- shared simplex math (device inline) ----
__device__ __forceinline__ void pv_math(const float* feat, int g, int* code_out, float* bary_out){
  int p = g / NVERT, kk = g % NVERT;
  int b = p >> 10, n = p & 1023;
  const float* fb = feat + (size_t)b * DD * NPTS + n;
  float f0 = fb[0], f1 = fb[NPTS], f2 = fb[2 * NPTS], f3 = fb[3 * NPTS];

  float elev[5];
  elev[0] =  f0 * 2.886751345948129f  + f1 * 1.6666666666666667f + f2 * 1.1785113019775793f + f3 * 0.9128709291752769f;
  elev[1] = -f0 * 2.886751345948129f  + f1 * 1.6666666666666667f + f2 * 1.1785113019775793f + f3 * 0.9128709291752769f;
  elev[2] =  f1 * -3.3333333333333335f + f2 * 1.1785113019775793f + f3 * 0.9128709291752769f;
  elev[3] =  f2 * -3.535533905932738f  + f3 * 0.9128709291752769f;
  elev[4] =  f3 * -3.6514837167011076f;

  int gi[5]; float diff[5]; int sum = 0;
  #pragma unroll
  for (int i = 0; i < 5; i++){
    float gg = rintf(elev[i] * 0.2f) * 5.0f;
    gi[i] = (int)rintf(gg);
    sum += gi[i];
    diff[i] = elev[i] - gg;
  }
  int s = sum / 5;

  int rank[5];
  #pragma unroll
  for (int i = 0; i < 5; i++){
    int r = 0;
    #pragma unroll
    for (int j = 0; j < 5; j++)
      r += (diff[j] > diff[i]) || (diff[j] == diff[i] && j < i);
    rank[i] = r + s;
  }
  #pragma unroll
  for (int i = 0; i < 5; i++){
    if (rank[i] < 0)      { rank[i] += NVERT; gi[i] += NVERT; }
    else if (rank[i] > DD){ rank[i] -= NVERT; gi[i] -= NVERT; }
  }

  float bary[6] = {0.f,0.f,0.f,0.f,0.f,0.f};
  #pragma unroll
  for (int i = 0; i < 5; i++){
    float tt = (elev[i] - (float)gi[i]) * 0.2f;
    bary[DD - rank[i]]    += tt;
    bary[NVERT - rank[i]] += 1.0f - tt;
  }
  bary[0] += 1.0f + bary[5];

  float bk = bary[0];
  #pragma unroll
  for (int i = 1; i < 5; i++) if (i == kk) bk = bary[i];

  int code = 0;
  #pragma unroll
  for (int j = 0; j < DD; j++){
    int add = (rank[j] >= NVERT - kk) ? (kk - NVERT) : kk;
    int key = gi[j] + add;
    key = min(63, max(-64, key));
    code += (key + 64) << (7 * j);
  }
  *code_out = code;
  *bary_out = bk;
}

// ======================= MEGA (cooperative) ================================
__global__ __launch_bounds__(NT, 2) void k_mega(Params P){
  cg::grid_group grid = cg::this_grid();
  int bid = blockIdx.x, tid = threadIdx.x;
  int t = bid * NT + tid;                       // [0, 131072)

  __shared__ union {
    float tile[64][65];
    int   lhash[1024];
    struct { int gidx[64 * 33]; float red[4][64][17]; } c;
    float stile[32][65];
  } S;

  // ===== PHASE A: init + bp + dat_t + pmath =====
  for (int i = t; i < BATCH * CAP; i += NB * NT){ P.hash_code[i] = SENTV; P.hash_uid[i] = -1; }
  if (t < BATCH) P.ucount[t] = 0;
  {
    float4* t4 = (float4*)P.table;
    float4 z = {0.f,0.f,0.f,0.f};
    for (int i = t; i < BATCH * M0 * CIN / 4; i += NB * NT) t4[i] = z;
  }
  for (int e = t; e < COUT * KTOT; e += NB * NT){
    int o = e / KTOT, k = e % KTOT;
    int f = k >> 6, c = k & 63;
    P.bp[e] = f2bf(P.wk[(o * CIN + c) * NF + f]);
  }
  if (t < 8){
    bf16x8 z = {0,0,0,0,0,0,0,0};
    *(bf16x8*)(P.table_bf + ((size_t)ZROW << 6) + t * 8) = z;
  }
  if (bid < 64){
    int b = bid >> 4, n0 = (bid & 15) * 64;
    int nl = tid & 63, w8 = tid >> 6;
    #pragma unroll
    for (int i = 0; i < 8; i++){
      int c = w8 * 8 + i;
      S.tile[c][nl] = P.data[(((size_t)b * 64 + c) << 10) + n0 + nl];
    }
    __syncthreads();
    #pragma unroll
    for (int i = 0; i < 8; i++){
      int nn = w8 * 8 + i;
      P.dat_t[(((size_t)b << 10) + n0 + nn) * 64 + nl] = S.tile[nl][nn];
    }
  }
  for (int g = t; g < BATCH * M0; g += NB * NT){
    int code; float bk;
    pv_math(P.feat, g, &code, &bk);
    P.codes_pv[g] = code;
    P.bary_pv[g]  = bk;
  }
  grid.sync();

  // ===== PHASE B: insert (LDS dedupe + wave-agg uid) =====
  if (bid < BATCH * M0 / NT){                   // 40 blocks; 10/batch exact
    S.lhash[tid] = SENTV; S.lhash[tid + 512] = SENTV;
    __syncthreads();
    int g = t;
    int b = g / M0;
    int code = P.codes_pv[g];

    uint32_t lh = (((uint32_t)code * 2654435761u) >> 22) & 1023;
    bool rep = false;
    while (true){
      int prev = atomicCAS(&S.lhash[lh], SENTV, code);
      if (prev == SENTV){ rep = true; break; }
      if (prev == code) break;
      lh = (lh + 1) & 1023;
    }

    int myslot = -1;
    if (rep){
      int* hc = P.hash_code + b * CAP;
      uint32_t h = hslot(code);
      while (true){
        int prev = atomicCAS(&hc[h], SENTV, code);
        if (prev == SENTV){ myslot = (int)h; break; }
        if (prev == code) break;
        h = (h + 1) & CAPMASK;
      }
    }

    unsigned long long mask = __ballot(myslot >= 0);
    if (mask){
      int lane = tid & 63;
      int cnt = __popcll(mask);
      int leader = __ffsll((unsigned long long)mask) - 1;
      int base = 0;
      if (lane == leader) base = atomicAdd(&P.ucount[b], cnt);
      base = __shfl(base, leader);
      if (myslot >= 0){
        int rank = __popcll(mask & ((1ull << lane) - 1ull));
        int uid = base + rank;
        P.hash_uid[b * CAP + myslot] = uid;
        int* uk = P.ukeys + ((size_t)(b * M0 + uid)) * DD;
        #pragma unroll
        for (int j = 0; j < DD; j++) uk[j] = ((code >> (7 * j)) & 127) - 64;
      }
    }
  }
  grid.sync();

  // ===== PHASE C: splat (per wave) + neighbor lookups =====
  {
    int wid = t >> 6, lane = tid & 63;
    for (int p = wid; p < BATCH * NPTS; p += NB * NT / 64){
      int b = p >> 10;
      float v = P.dat_t[((size_t)p << 6) + lane];
      int uid = 0; float wb = 0.f;
      if (lane < NVERT){
        int code = P.codes_pv[p * NVERT + lane];
        const int* hc = P.hash_code + b * CAP;
        uint32_t h = hslot(code);
        while (hc[h] != code) h = (h + 1) & CAPMASK;
        uid = P.hash_uid[b * CAP + h];
        wb  = P.bary_pv[p * NVERT + lane];
        P.idx_pv[p * NVERT + lane] = uid;
      }
      int rot = p % NVERT;
      #pragma unroll
      for (int kq = 0; kq < NVERT; kq++){
        int kk = kq + rot; if (kk >= NVERT) kk -= NVERT;
        int   u_k = __shfl(uid, kk);
        float w_k = __shfl(wb,  kk);
        atomicAdd(&P.table[(((size_t)(b * M0 + u_k)) << 6) + lane], v * w_k);
      }
    }
  }
  for (int e = t; e < BATCH * M0 * 32; e += NB * NT){
    int f = e & 31;
    int idx = e >> 5;
    int b = idx / M0, m = idx - b * M0;
    int g = ZROW;
    if (f < NF && m < P.ucount[b]){
      const int* uk = P.ukeys + ((size_t)idx) * DD;
      int pc = __popc(f);
      int code = 0;
      #pragma unroll
      for (int j = 0; j < DD; j++){
        int key = uk[j] + 5 * ((f >> j) & 1) - pc;
        key = min(63, max(-64, key));
        code += (key + 64) << (7 * j);
      }
      const int* hc = P.hash_code + b * CAP;
      uint32_t h = hslot(code);
      while (true){
        int v = hc[h];
        if (v == code){ g = b * M0 + P.hash_uid[b * CAP + h]; break; }
        if (v == SENTV) break;
        h = (h + 1) & CAPMASK;
      }
    }
    P.nuid[e] = g;
  }
  grid.sync();

  // ===== PHASE D: table fp32 -> bf16 =====
  for (int g = t; g < BATCH * M0 * CIN / 8; g += NB * NT){
    size_t base = (size_t)g * 8;
    const float4* s4 = (const float4*)(P.table + base);
    float4 x = s4[0], y = s4[1];
    bf16x8 v;
    v[0] = (short)f2bf(x.x); v[1] = (short)f2bf(x.y);
    v[2] = (short)f2bf(x.z); v[3] = (short)f2bf(x.w);
    v[4] = (short)f2bf(y.x); v[5] = (short)f2bf(y.y);
    v[6] = (short)f2bf(y.z); v[7] = (short)f2bf(y.w);
    *(bf16x8*)(P.table_bf + base) = v;
  }
  grid.sync();

  // ===== PHASE E: convolution (MFMA), grid-strided over 320 tiles =====
  for (int blk = bid; blk < NTILES; blk += NB){
    int b  = blk / (M0 / 64);
    int m0 = (blk % (M0 / 64)) * 64;
    if (m0 >= P.ucount[b]) continue;            // block-uniform skip

    {
      int base = (b * M0 + m0) << 5;
      #pragma unroll
      for (int i = 0; i < 4; i++){
        int idx = tid + i * 512;
        S.c.gidx[(idx >> 5) * 33 + (idx & 31)] = P.nuid[base + idx];
      }
    }
    __syncthreads();

    int lane = tid & 63, wave = tid >> 6;
    int wm = wave & 1, wo = (wave >> 1) & 1, wk = wave >> 2;
    int arow = wm * 32 + (lane & 15);
    int acol = (lane >> 4) * 8;
    int bcol = wo * 32 + (lane & 15);
    const unsigned short* bpp0 = P.bp + (size_t)bcol * KTOT + acol;
    const unsigned short* bpp1 = bpp0 + (size_t)16 * KTOT;

    f32x4 acc00 = {0.f,0.f,0.f,0.f}, acc01 = {0.f,0.f,0.f,0.f};
    f32x4 acc10 = {0.f,0.f,0.f,0.f}, acc11 = {0.f,0.f,0.f,0.f};

    int ks0 = wk * 32, ks1 = wk ? 62 : 32;
    #pragma unroll 4
    for (int ks = ks0; ks < ks1; ks++){
      int f  = ks >> 1;
      int c0 = (ks & 1) << 5;
      int g0 = S.c.gidx[arow * 33 + f];
      int g1 = S.c.gidx[(arow + 16) * 33 + f];
      bf16x8 a0 = *(const bf16x8*)(P.table_bf + (((size_t)g0) << 6) + c0 + acol);
      bf16x8 a1 = *(const bf16x8*)(P.table_bf + (((size_t)g1) << 6) + c0 + acol);
      bf16x8 b0 = *(const bf16x8*)(bpp0 + (ks << 5));
      bf16x8 b1 = *(const bf16x8*)(bpp1 + (ks << 5));
      acc00 = __builtin_amdgcn_mfma_f32_16x16x32_bf16(a0, b0, acc00, 0, 0, 0);
      acc01 = __builtin_amdgcn_mfma_f32_16x16x32_bf16(a0, b1, acc01, 0, 0, 0);
      acc10 = __builtin_amdgcn_mfma_f32_16x16x32_bf16(a1, b0, acc10, 0, 0, 0);
      acc11 = __builtin_amdgcn_mfma_f32_16x16x32_bf16(a1, b1, acc11, 0, 0, 0);
    }

    int wl = wave & 3;
    if (wk == 1){
      #pragma unroll
      for (int q = 0; q < 4; q++){
        S.c.red[wl][lane][q]      = acc00[q];
        S.c.red[wl][lane][4 + q]  = acc01[q];
        S.c.red[wl][lane][8 + q]  = acc10[q];
        S.c.red[wl][lane][12 + q] = acc11[q];
      }
    }
    __syncthreads();
    if (wk == 0){
      #pragma unroll
      for (int q = 0; q < 4; q++){
        acc00[q] += S.c.red[wl][lane][q];
        acc01[q] += S.c.red[wl][lane][4 + q];
        acc10[q] += S.c.red[wl][lane][8 + q];
        acc11[q] += S.c.red[wl][lane][12 + q];
      }
      // C/D layout: col = lane&15, row = (lane>>4)*4 + q (m89-verified)
      int q4 = (lane >> 4) * 4, col = lane & 15;
      #pragma unroll
      for (int i = 0; i < 2; i++){
        f32x4 ai0 = (i == 0) ? acc00 : acc10;
        f32x4 ai1 = (i == 0) ? acc01 : acc11;
        #pragma unroll
        for (int q = 0; q < 4; q++){
          int m = m0 + wm * 32 + i * 16 + q4 + q;
          float* orow = P.out_lat + (((size_t)(b * M0 + m)) << 6);
          orow[wo * 32 + col]      = ai0[q];
          orow[wo * 32 + 16 + col] = ai1[q];
        }
      }
    }
    __syncthreads();                            // protect LDS reuse next tile
  }
  grid.sync();

  // ===== PHASE F: slice + bias + transpose =====
  if (bid < BATCH * 32){
    int b = bid >> 5, n0 = (bid & 31) * 32;
    int wave = tid >> 6, o = tid & 63;
    float bo = P.bias[o];
    #pragma unroll
    for (int i = 0; i < 4; i++){
      int n = wave * 4 + i;
      int p = (b << 10) + n0 + n;
      float acc = bo * P.bmul[n0 + n];
      int base = p * NVERT;
      #pragma unroll
      for (int kk = 0; kk < NVERT; kk++){
        int u = P.idx_pv[base + kk];
        acc += P.bary_pv[base + kk] * P.out_lat[(((size_t)(b * M0 + u)) << 6) + o];
      }
      S.stile[n][o] = acc;
    }
    __syncthreads();
    int nl = tid & 31, ob = (tid >> 5) * 4;
    #pragma unroll
    for (int i = 0; i < 4; i++){
      int o2 = ob + i;
      P.out[(((size_t)b * 64 + o2) << 10) + n0 + nl] = S.stile[nl][o2];
    }
  }
}

// ======================= FALLBACK pipeline (round-7 verified) ==============
__global__ void k_setup(const float* __restrict__ wk, const float* __restrict__ data,
                        int* __restrict__ hc, int* __restrict__ hu, int* __restrict__ uc,
                        float4* __restrict__ table4, unsigned short* __restrict__ bp,
                        float* __restrict__ dat_t){
  int bid = blockIdx.x, tid = threadIdx.x;
  if (bid < 64){
    __shared__ float tile[64][65];
    int b = bid >> 4, n0 = (bid & 15) * 64;
    int nl = tid & 63;
    #pragma unroll
    for (int i = 0; i < 16; i++){
      int c = (tid >> 6) * 16 + i;
      tile[c][nl] = data[(((size_t)b * 64 + c) << 10) + n0 + nl];
    }
    __syncthreads();
    #pragma unroll
    for (int i = 0; i < 16; i++){
      int nn = (tid >> 6) * 16 + i;
      dat_t[(((size_t)b << 10) + n0 + nn) * 64 + (tid & 63)] = tile[tid & 63][nn];
    }
  } else if (bid < 560){
    int e = (bid - 64) * 256 + tid;
    if (e < COUT * KTOT){
      int o = e / KTOT, k = e % KTOT;
      int f = k >> 6, c = k & 63;
      bp[e] = f2bf(wk[(o * CIN + c) * NF + f]);
    }
  } else {
    int g = (bid - 560) * 256 + tid;
    int stride = 464 * 256;
    for (int i = g; i < BATCH * CAP; i += stride){ hc[i] = SENTV; hu[i] = -1; }
    if (g < BATCH) uc[g] = 0;
    float4 z = {0.f,0.f,0.f,0.f};
    for (int i = g; i < BATCH * M0 * CIN / 4; i += stride) table4[i] = z;
  }
}

__global__ void k_pmath(const float* __restrict__ feat,
                        int* __restrict__ codes_pv, float* __restrict__ bary_pv){
  int g = blockIdx.x * 256 + threadIdx.x;
  int code; float bk;
  pv_math(feat, g, &code, &bk);
  codes_pv[g] = code;
  bary_pv[g]  = bk;
}

__global__ void k_insert(const int* __restrict__ codes_pv,
                         int* __restrict__ hash_code, int* __restrict__ hash_uid,
                         int* __restrict__ ucount, int* __restrict__ ukeys){
  __shared__ int lhash[512];
  int tid = threadIdx.x;
  lhash[tid] = SENTV; lhash[tid + 256] = SENTV;
  __syncthreads();

  int g = blockIdx.x * 256 + tid;
  int b = g / M0;
  int code = codes_pv[g];

  uint32_t lh = (((uint32_t)code * 2654435761u) >> 21) & 511;
  bool rep = false;
  while (true){
    int prev = atomicCAS(&lhash[lh], SENTV, code);
    if (prev == SENTV){ rep = true; break; }
    if (prev == code) break;
    lh = (lh + 1) & 511;
  }

  int myslot = -1;
  if (rep){
    int* hc = hash_code + b * CAP;
    uint32_t h = hslot(code);
    while (true){
      int prev = atomicCAS(&hc[h], SENTV, code);
      if (prev == SENTV){ myslot = (int)h; break; }
      if (prev == code) break;
      h = (h + 1) & CAPMASK;
    }
  }

  unsigned long long mask = __ballot(myslot >= 0);
  if (mask){
    int lane = tid & 63;
    int cnt = __popcll(mask);
    int leader = __ffsll((unsigned long long)mask) - 1;
    int base = 0;
    if (lane == leader) base = atomicAdd(&ucount[b], cnt);
    base = __shfl(base, leader);
    if (myslot >= 0){
      int rank = __popcll(mask & ((1ull << lane) - 1ull));
      int uid = base + rank;
      hash_uid[b * CAP + myslot] = uid;
      int* uk = ukeys + ((size_t)(b * M0 + uid)) * DD;
      #pragma unroll
      for (int j = 0; j < DD; j++) uk[j] = ((code >> (7 * j)) & 127) - 64;
    }
  }
}

__global__ void k_sn(const float* __restrict__ dat_t, const int* __restrict__ codes_pv,
                     const float* __restrict__ bary_pv, const int* __restrict__ hash_code,
                     const int* __restrict__ hash_uid, const int* __restrict__ ucount,
                     const int* __restrict__ ukeys,
                     int* __restrict__ idx_pv, float* __restrict__ table,
                     int* __restrict__ nuid){
  int bid = blockIdx.x, tid = threadIdx.x;
  if (bid < BATCH * NPTS / 4){
    __shared__ int   us[4][8];
    __shared__ float wbs[4][8];
    int w = tid >> 6, lane = tid & 63;
    int p = bid * 4 + w;
    int b = p >> 10;
    float v = dat_t[((size_t)p << 6) + lane];
    if (lane < NVERT){
      int code = codes_pv[p * NVERT + lane];
      const int* hc = hash_code + b * CAP;
      uint32_t h = hslot(code);
      while (hc[h] != code) h = (h + 1) & CAPMASK;
      int uid = hash_uid[b * CAP + h];
      us[w][lane]  = uid;
      wbs[w][lane] = bary_pv[p * NVERT + lane];
      idx_pv[p * NVERT + lane] = uid;
    }
    __syncthreads();
    int rot = p % NVERT;
    #pragma unroll
    for (int kq = 0; kq < NVERT; kq++){
      int kk = kq + rot; if (kk >= NVERT) kk -= NVERT;
      atomicAdd(&table[(((size_t)(b * M0 + us[w][kk])) << 6) + lane], v * wbs[w][kk]);
    }
  } else {
    int e = (bid - BATCH * NPTS / 4) * 256 + tid;
    int f = e & 31;
    int idx = e >> 5;
    int b = idx / M0, m = idx - b * M0;
    int g = ZROW;
    if (f < NF && m < ucount[b]){
      const int* uk = ukeys + ((size_t)idx) * DD;
      int pc = __popc(f);
      int code = 0;
      #pragma unroll
      for (int j = 0; j < DD; j++){
        int key = uk[j] + 5 * ((f >> j) & 1) - pc;
        key = min(63, max(-64, key));
        code += (key + 64) << (7 * j);
      }
      const int* hc = hash_code + b * CAP;
      uint32_t h = hslot(code);
      while (true){
        int v = hc[h];
        if (v == code){ g = b * M0 + hash_uid[b * CAP + h]; break; }
        if (v == SENTV) break;
        h = (h + 1) & CAPMASK;
      }
    }
    nuid[e] = g;
  }
}

__global__ void k_tobf(const float* __restrict__ table, unsigned short* __restrict__ table_bf){
  int g = blockIdx.x * blockDim.x + threadIdx.x;
  size_t base = (size_t)g * 8;
  const float4* s4 = (const float4*)(table + base);
  float4 x = s4[0], y = s4[1];
  bf16x8 v;
  v[0] = (short)f2bf(x.x); v[1] = (short)f2bf(x.y);
  v[2] = (short)f2bf(x.z); v[3] = (short)f2bf(x.w);
  v[4] = (short)f2bf(y.x); v[5] = (short)f2bf(y.y);
  v[6] = (short)f2bf(y.z); v[7] = (short)f2bf(y.w);
  *(bf16x8*)(table_bf + base) = v;
  if (g < 8){
    bf16x8 z = {0,0,0,0,0,0,0,0};
    *(bf16x8*)(table_bf + ((size_t)ZROW << 6) + g * 8) = z;
  }
}

__launch_bounds__(512)
__global__ void k_conv(const int* __restrict__ ucount, const int* __restrict__ nuid,
                       const unsigned short* __restrict__ table_bf,
                       const unsigned short* __restrict__ bp,
                       float* __restrict__ out_lat){
  __shared__ int gidx_s[64 * 33];
  __shared__ float red[4][64][17];

  int blk = blockIdx.x;
  int b   = blk / (M0 / 64);
  int m0  = (blk % (M0 / 64)) * 64;
  if (m0 >= ucount[b]) return;

  int tid = threadIdx.x;
  {
    int base = (b * M0 + m0) << 5;
    #pragma unroll
    for (int i = 0; i < 4; i++){
      int idx = tid + i * 512;
      gidx_s[(idx >> 5) * 33 + (idx & 31)] = nuid[base + idx];
    }
  }
  __syncthreads();

  int lane = tid & 63, wave = tid >> 6;
  int wm = wave & 1, wo = (wave >> 1) & 1, wk = wave >> 2;
  int arow = wm * 32 + (lane & 15);
  int acol = (lane >> 4) * 8;
  int bcol = wo * 32 + (lane & 15);
  const unsigned short* bpp0 = bp + (size_t)bcol * KTOT + acol;
  const unsigned short* bpp1 = bpp0 + (size_t)16 * KTOT;

  f32x4 acc00 = {0.f,0.f,0.f,0.f}, acc01 = {0.f,0.f,0.f,0.f};
  f32x4 acc10 = {0.f,0.f,0.f,0.f}, acc11 = {0.f,0.f,0.f,0.f};

  int ks0 = wk * 32, ks1 = wk ? 62 : 32;
  #pragma unroll 4
  for (int ks = ks0; ks < ks1; ks++){
    int f  = ks >> 1;
    int c0 = (ks & 1) << 5;
    int g0 = gidx_s[arow * 33 + f];
    int g1 = gidx_s[(arow + 16) * 33 + f];
    bf16x8 a0 = *(const bf16x8*)(table_bf + (((size_t)g0) << 6) + c0 + acol);
    bf16x8 a1 = *(const bf16x8*)(table_bf + (((size_t)g1) << 6) + c0 + acol);
    bf16x8 b0 = *(const bf16x8*)(bpp0 + (ks << 5));
    bf16x8 b1 = *(const bf16x8*)(bpp1 + (ks << 5));
    acc00 = __builtin_amdgcn_mfma_f32_16x16x32_bf16(a0, b0, acc00, 0, 0, 0);
    acc01 = __builtin_amdgcn_mfma_f32_16x16x32_bf16(a0, b1, acc01, 0, 0, 0);
    acc10 = __builtin_amdgcn_mfma_f32_16x16x32_bf16(a1, b0, acc10, 0, 0, 0);
    acc11 = __builtin_amdgcn_mfma_f32_16x16x32_bf16(a1, b1, acc11, 0, 0, 0);
  }

  int wl = wave & 3;
  if (wk == 1){
    #pragma unroll
    for (int q = 0; q < 4; q++){
      red[wl][lane][q]      = acc00[q];
      red[wl][lane][4 + q]  = acc01[q];
      red[wl][lane][8 + q]  = acc10[q];
      red[wl][lane][12 + q] = acc11[q];
    }
  }
  __syncthreads();
  if (wk == 0){
    #pragma unroll
    for (int q = 0; q < 4; q++){
      acc00[q] += red[wl][lane][q];
      acc01[q] += red[wl][lane][4 + q];
      acc10[q] += red[wl][lane][8 + q];
      acc11[q] += red[wl][lane][12 + q];
    }
    int q4 = (lane >> 4) * 4, col = lane & 15;
    #pragma unroll
    for (int i = 0; i < 2; i++){
      f32x4 ai0 = (i == 0) ? acc00 : acc10;
      f32x4 ai1 = (i == 0) ? acc01 : acc11;
      #pragma unroll
      for (int q = 0; q < 4; q++){
        int m = m0 + wm * 32 + i * 16 + q4 + q;
        float* orow = out_lat + (((size_t)(b * M0 + m)) << 6);
        orow[wo * 32 + col]      = ai0[q];
        orow[wo * 32 + 16 + col] = ai1[q];
      }
    }
  }
}

__global__ void k_slice(const float* __restrict__ bary_pv, const int* __restrict__ idx_pv,
                        const float* __restrict__ out_lat, const float* __restrict__ bias,
                        const float* __restrict__ bmul, float* __restrict__ out){
  __shared__ float tile[32][65];
  int b = blockIdx.x >> 5, n0 = (blockIdx.x & 31) * 32;
  int tid = threadIdx.x;
  int wave = tid >> 6, o = tid & 63;
  float bo = bias[o];
  #pragma unroll
  for (int i = 0; i < 8; i++){
    int n = wave * 8 + i;
    int p = (b << 10) + n0 + n;
    float acc = bo * bmul[n0 + n];
    int base = p * NVERT;
    #pragma unroll
    for (int kk = 0; kk < NVERT; kk++){
      int u = idx_pv[base + kk];
      acc += bary_pv[base + kk] * out_lat[(((size_t)(b * M0 + u)) << 6) + o];
    }
    tile[n][o] = acc;
  }
  __syncthreads();
  int nl = tid & 31, ob = (tid >> 5) * 8;
  #pragma unroll
  for (int i = 0; i < 8; i++){
    int o2 = ob + i;
    out[(((size_t)b * 64 + o2) << 10) + n0 + nl] = tile[nl][o2];
  }
}

extern "C" void kernel_launch(void* const* d_in, const int* in_sizes, int n_in,
                              void* d_out, int out_size, void* d_ws, size_t ws_size,
                              hipStream_t stream){
  char* ws = (char*)d_ws;
  size_t off = 0;
  auto alloc = [&](size_t bytes){
    void* p = ws + off;
    off = (off + bytes + 255) & ~(size_t)255;
    return p;
  };

  Params P;
  P.data = (const float*)d_in[0];
  P.feat = (const float*)d_in[1];
  P.wk   = (const float*)d_in[2];
  P.bias = (const float*)d_in[3];
  P.bmul = (const float*)d_in[4];
  P.out  = (float*)d_out;

  P.codes_pv = (int*)  alloc((size_t)BATCH * M0 * 4);
  P.bary_pv  = (float*)alloc((size_t)BATCH * M0 * 4);
  P.idx_pv   = (int*)  alloc((size_t)BATCH * M0 * 4);
  P.hash_code= (int*)  alloc((size_t)BATCH * CAP * 4);
  P.hash_uid = (int*)  alloc((size_t)BATCH * CAP * 4);
  P.ucount   = (int*)  alloc(256);
  P.ukeys    = (int*)  alloc((size_t)BATCH * M0 * DD * 4);
  P.table    = (float*)alloc((size_t)BATCH * M0 * CIN * 4);
  P.out_lat  = (float*)alloc((size_t)BATCH * M0 * COUT * 4);
  P.bp       = (unsigned short*)alloc((size_t)COUT * KTOT * 2);
  P.table_bf = (unsigned short*)alloc(((size_t)BATCH * M0 + 8) * CIN * 2);
  P.dat_t    = (float*)alloc((size_t)BATCH * NPTS * CIN * 4);
  P.nuid     = (int*)  alloc((size_t)BATCH * M0 * 32 * 4);

  // capture-safe, deterministic decision: device attribute + launch status
  int dev = 0, coop = 0;
  hipGetDevice(&dev);
  hipDeviceGetAttribute(&coop, hipDeviceAttributeCooperativeLaunch, dev);

  hipError_t err = hipErrorUnknown;
  if (coop){
    void* args[] = { &P };
    err = hipLaunchCooperativeKernel((const void*)k_mega, dim3(NB), dim3(NT), args, 0, stream);
  }
  if (err != hipSuccess){
    // fallback: round-7-verified 7-kernel pipeline
    k_setup <<<1024, 256, 0, stream>>>(P.wk, P.data, P.hash_code, P.hash_uid, P.ucount,
                                       (float4*)P.table, P.bp, P.dat_t);
    k_pmath <<<BATCH * M0 / 256, 256, 0, stream>>>(P.feat, P.codes_pv, P.bary_pv);
    k_insert<<<BATCH * M0 / 256, 256, 0, stream>>>(P.codes_pv, P.hash_code, P.hash_uid,
                                                   P.ucount, P.ukeys);
    k_sn    <<<BATCH * NPTS / 4 + BATCH * M0 * 32 / 256, 256, 0, stream>>>(
              P.dat_t, P.codes_pv, P.bary_pv, P.hash_code, P.hash_uid, P.ucount, P.ukeys,
              P.idx_pv, P.table, P.nuid);
    k_tobf  <<<BATCH * M0 * CIN / 8 / 256, 256, 0, stream>>>(P.table, P.table_bf);
    k_conv  <<<BATCH * (M0 / 64), 512, 0, stream>>>(P.ucount, P.nuid, P.table_bf, P.bp, P.out_lat);
    k_slice <<<BATCH * 32, 256, 0, stream>>>(P.bary_pv, P.idx_pv, P.out_lat, P.bias, P.bmul, P.out);
  }
}

// Round 10
// 71.756 us; speedup vs baseline: 3.0320x; 3.0320x over previous
//
#include <hip/hip_runtime.h>
#include <hip/hip_bf16.h>
#include <stdint.h>

#define DD 4
#define NVERT 5
#define NPTS 1024
#define BATCH 4
#define M0 5120           /* NPTS*NVERT */
#define CIN 64
#define COUT 64
#define NF 31
#define KTOT 1984         /* NF*CIN */
#define CAP 16384
#define CAPMASK (CAP-1)
#define SENTV 1073741824  /* 2^30, > any valid code (<128^4) */
#define ZROW (BATCH*M0)   /* zero row index in fp32 table */

using bf16x8 = __attribute__((ext_vector_type(8))) short;
using f32x4  = __attribute__((ext_vector_type(4))) float;

__device__ __forceinline__ unsigned short f2bf(float x){
  unsigned int u = __float_as_uint(x);
  u = (u + 0x7FFFu + ((u >> 16) & 1u)) >> 16;
  return (unsigned short)u;
}

// hardware RTNE f32->bf16 (compiler packs pairs into v_cvt_pk_bf16_f32)
__device__ __forceinline__ short f2bf_hw(float x){
  __hip_bfloat16 h = __float2bfloat16(x);
  return *reinterpret_cast<short*>(&h);
}

__device__ __forceinline__ uint32_t hslot(int code){
  return (((uint32_t)code * 2654435761u) >> 18) & CAPMASK;
}

// ---- shared simplex math ----
__device__ __forceinline__ void pv_math(const float* feat, int g, int* code_out, float* bary_out){
  int p = g / NVERT, kk = g % NVERT;
  int b = p >> 10, n = p & 1023;
  const float* fb = feat + (size_t)b * DD * NPTS + n;
  float f0 = fb[0], f1 = fb[NPTS], f2 = fb[2 * NPTS], f3 = fb[3 * NPTS];

  float elev[5];
  elev[0] =  f0 * 2.886751345948129f  + f1 * 1.6666666666666667f + f2 * 1.1785113019775793f + f3 * 0.9128709291752769f;
  elev[1] = -f0 * 2.886751345948129f  + f1 * 1.6666666666666667f + f2 * 1.1785113019775793f + f3 * 0.9128709291752769f;
  elev[2] =  f1 * -3.3333333333333335f + f2 * 1.1785113019775793f + f3 * 0.9128709291752769f;
  elev[3] =  f2 * -3.535533905932738f  + f3 * 0.9128709291752769f;
  elev[4] =  f3 * -3.6514837167011076f;

  int gi[5]; float diff[5]; int sum = 0;
  #pragma unroll
  for (int i = 0; i < 5; i++){
    float gg = rintf(elev[i] * 0.2f) * 5.0f;
    gi[i] = (int)rintf(gg);
    sum += gi[i];
    diff[i] = elev[i] - gg;
  }
  int s = sum / 5;

  int rank[5];
  #pragma unroll
  for (int i = 0; i < 5; i++){
    int r = 0;
    #pragma unroll
    for (int j = 0; j < 5; j++)
      r += (diff[j] > diff[i]) || (diff[j] == diff[i] && j < i);
    rank[i] = r + s;
  }
  #pragma unroll
  for (int i = 0; i < 5; i++){
    if (rank[i] < 0)      { rank[i] += NVERT; gi[i] += NVERT; }
    else if (rank[i] > DD){ rank[i] -= NVERT; gi[i] -= NVERT; }
  }

  float bary[6] = {0.f,0.f,0.f,0.f,0.f,0.f};
  #pragma unroll
  for (int i = 0; i < 5; i++){
    float tt = (elev[i] - (float)gi[i]) * 0.2f;
    bary[DD - rank[i]]    += tt;
    bary[NVERT - rank[i]] += 1.0f - tt;
  }
  bary[0] += 1.0f + bary[5];

  float bk = bary[0];
  #pragma unroll
  for (int i = 1; i < 5; i++) if (i == kk) bk = bary[i];

  int code = 0;
  #pragma unroll
  for (int j = 0; j < DD; j++){
    int add = (rank[j] >= NVERT - kk) ? (kk - NVERT) : kk;
    int key = gi[j] + add;
    key = min(63, max(-64, key));
    code += (key + 64) << (7 * j);
  }
  *code_out = code;
  *bary_out = bk;
}

// ============ A: init + bp + dat_t + pmath (disjoint block ranges) ========
__global__ void k_a(const float* __restrict__ wk, const float* __restrict__ data,
                    const float* __restrict__ feat,
                    int* __restrict__ hc, int* __restrict__ hu, int* __restrict__ uc,
                    float4* __restrict__ table4, unsigned short* __restrict__ bp,
                    float* __restrict__ dat_t,
                    int* __restrict__ codes_pv, float* __restrict__ bary_pv){
  int bid = blockIdx.x, tid = threadIdx.x;
  if (bid < 64){
    // ---- data transpose [b][c][n] -> dat_t [b*n][c] ----
    __shared__ float tile[64][65];
    int b = bid >> 4, n0 = (bid & 15) * 64;
    int nl = tid & 63;
    #pragma unroll
    for (int i = 0; i < 16; i++){
      int c = (tid >> 6) * 16 + i;
      tile[c][nl] = data[(((size_t)b * 64 + c) << 10) + n0 + nl];
    }
    __syncthreads();
    #pragma unroll
    for (int i = 0; i < 16; i++){
      int nn = (tid >> 6) * 16 + i;
      dat_t[(((size_t)b << 10) + n0 + nn) * 64 + (tid & 63)] = tile[tid & 63][nn];
    }
  } else if (bid < 144){
    // ---- pmath: 80 blocks cover BATCH*M0 = 20480 exactly ----
    int g = (bid - 64) * 256 + tid;
    int code; float bk;
    pv_math(feat, g, &code, &bk);
    codes_pv[g] = code;
    bary_pv[g]  = bk;
  } else if (bid < 640){
    // ---- weights -> Bprep[o][k] bf16: 496 blocks cover 126976 exactly ----
    int e = (bid - 144) * 256 + tid;
    int o = e / KTOT, k = e % KTOT;
    int f = k >> 6, c = k & 63;
    bp[e] = f2bf(wk[(o * CIN + c) * NF + f]);
  } else {
    // ---- init hash + ucount + zero table (incl zero row) ----
    int g = (bid - 640) * 256 + tid;
    int stride = 384 * 256;
    for (int i = g; i < BATCH * CAP; i += stride){ hc[i] = SENTV; hu[i] = -1; }
    if (g < BATCH) uc[g] = 0;
    float4 z = {0.f,0.f,0.f,0.f};
    for (int i = g; i < (BATCH * M0 + 1) * CIN / 4; i += stride) table4[i] = z;
  }
}

// ============ insert: LDS dedupe + global CAS + wave-aggregated uid =======
__global__ void k_insert(const int* __restrict__ codes_pv,
                         int* __restrict__ hash_code, int* __restrict__ hash_uid,
                         int* __restrict__ ucount, int* __restrict__ ukeys){
  __shared__ int lhash[512];
  int tid = threadIdx.x;
  lhash[tid] = SENTV; lhash[tid + 256] = SENTV;
  __syncthreads();

  int g = blockIdx.x * 256 + tid;       // blocks never straddle batches
  int b = g / M0;
  int code = codes_pv[g];

  uint32_t lh = (((uint32_t)code * 2654435761u) >> 21) & 511;
  bool rep = false;
  while (true){
    int prev = atomicCAS(&lhash[lh], SENTV, code);
    if (prev == SENTV){ rep = true; break; }
    if (prev == code) break;
    lh = (lh + 1) & 511;
  }

  int myslot = -1;
  if (rep){
    int* hc = hash_code + b * CAP;
    uint32_t h = hslot(code);
    while (true){
      int prev = atomicCAS(&hc[h], SENTV, code);
      if (prev == SENTV){ myslot = (int)h; break; }
      if (prev == code) break;
      h = (h + 1) & CAPMASK;
    }
  }

  unsigned long long mask = __ballot(myslot >= 0);
  if (mask){
    int lane = tid & 63;
    int cnt = __popcll(mask);
    int leader = __ffsll((unsigned long long)mask) - 1;
    int base = 0;
    if (lane == leader) base = atomicAdd(&ucount[b], cnt);
    base = __shfl(base, leader);
    if (myslot >= 0){
      int rank = __popcll(mask & ((1ull << lane) - 1ull));
      int uid = base + rank;
      hash_uid[b * CAP + myslot] = uid;
      int* uk = ukeys + ((size_t)(b * M0 + uid)) * DD;
      #pragma unroll
      for (int j = 0; j < DD; j++) uk[j] = ((code >> (7 * j)) & 127) - 64;
    }
  }
}

// ============ fused: splat (blocks < 1024) + neighbor lookups (rest) ======
__global__ void k_sn(const float* __restrict__ dat_t, const int* __restrict__ codes_pv,
                     const float* __restrict__ bary_pv, const int* __restrict__ hash_code,
                     const int* __restrict__ hash_uid, const int* __restrict__ ucount,
                     const int* __restrict__ ukeys,
                     int* __restrict__ idx_pv, float* __restrict__ table,
                     int* __restrict__ nuid){
  int bid = blockIdx.x, tid = threadIdx.x;
  if (bid < BATCH * NPTS / 4){
    __shared__ int   us[4][8];
    __shared__ float wbs[4][8];
    int w = tid >> 6, lane = tid & 63;
    int p = bid * 4 + w;
    int b = p >> 10;
    float v = dat_t[((size_t)p << 6) + lane];
    if (lane < NVERT){
      int code = codes_pv[p * NVERT + lane];
      const int* hc = hash_code + b * CAP;
      uint32_t h = hslot(code);
      while (hc[h] != code) h = (h + 1) & CAPMASK;
      int uid = hash_uid[b * CAP + h];
      us[w][lane]  = uid;
      wbs[w][lane] = bary_pv[p * NVERT + lane];
      idx_pv[p * NVERT + lane] = uid;
    }
    __syncthreads();
    int rot = p % NVERT;
    #pragma unroll
    for (int kq = 0; kq < NVERT; kq++){
      int kk = kq + rot; if (kk >= NVERT) kk -= NVERT;
      atomicAdd(&table[(((size_t)(b * M0 + us[w][kk])) << 6) + lane], v * wbs[w][kk]);
    }
  } else {
    int e = (bid - BATCH * NPTS / 4) * 256 + tid;   // [0, BATCH*M0*32)
    int f = e & 31;
    int idx = e >> 5;
    int b = idx / M0, m = idx - b * M0;
    int g = ZROW;
    if (f < NF && m < ucount[b]){
      const int* uk = ukeys + ((size_t)idx) * DD;
      int pc = __popc(f);
      int code = 0;
      #pragma unroll
      for (int j = 0; j < DD; j++){
        int key = uk[j] + 5 * ((f >> j) & 1) - pc;
        key = min(63, max(-64, key));
        code += (key + 64) << (7 * j);
      }
      const int* hc = hash_code + b * CAP;
      uint32_t h = hslot(code);
      while (true){
        int v = hc[h];
        if (v == code){ g = b * M0 + hash_uid[b * CAP + h]; break; }
        if (v == SENTV) break;
        h = (h + 1) & CAPMASK;
      }
    }
    nuid[e] = g;
  }
}

// ============ convolution: fp32 gathers + in-register bf16 cvt + MFMA =====
__launch_bounds__(512)
__global__ void k_conv(const int* __restrict__ ucount, const int* __restrict__ nuid,
                       const float* __restrict__ table,
                       const unsigned short* __restrict__ bp,
                       float* __restrict__ out_lat){
  __shared__ int gidx_s[64 * 33];
  __shared__ float red[4][64][17];

  int blk = blockIdx.x;
  int b   = blk / (M0 / 64);
  int m0  = (blk % (M0 / 64)) * 64;
  if (m0 >= ucount[b]) return;

  int tid = threadIdx.x;
  {
    int base = (b * M0 + m0) << 5;
    #pragma unroll
    for (int i = 0; i < 4; i++){
      int idx = tid + i * 512;
      gidx_s[(idx >> 5) * 33 + (idx & 31)] = nuid[base + idx];
    }
  }
  __syncthreads();

  int lane = tid & 63, wave = tid >> 6;
  int wm = wave & 1, wo = (wave >> 1) & 1, wk = wave >> 2;
  int arow = wm * 32 + (lane & 15);
  int acol = (lane >> 4) * 8;
  int bcol = wo * 32 + (lane & 15);
  const unsigned short* bpp0 = bp + (size_t)bcol * KTOT + acol;
  const unsigned short* bpp1 = bpp0 + (size_t)16 * KTOT;

  f32x4 acc00 = {0.f,0.f,0.f,0.f}, acc01 = {0.f,0.f,0.f,0.f};
  f32x4 acc10 = {0.f,0.f,0.f,0.f}, acc11 = {0.f,0.f,0.f,0.f};

  int ks0 = wk * 32, ks1 = wk ? 62 : 32;
  #pragma unroll 4
  for (int ks = ks0; ks < ks1; ks++){
    int f  = ks >> 1;
    int c0 = (ks & 1) << 5;
    int g0 = gidx_s[arow * 33 + f];
    int g1 = gidx_s[(arow + 16) * 33 + f];
    const float4* p0 = (const float4*)(table + (((size_t)g0) << 6) + c0 + acol);
    const float4* p1 = (const float4*)(table + (((size_t)g1) << 6) + c0 + acol);
    float4 x0 = p0[0], y0 = p0[1];
    float4 x1 = p1[0], y1 = p1[1];
    bf16x8 a0, a1;
    a0[0]=f2bf_hw(x0.x); a0[1]=f2bf_hw(x0.y); a0[2]=f2bf_hw(x0.z); a0[3]=f2bf_hw(x0.w);
    a0[4]=f2bf_hw(y0.x); a0[5]=f2bf_hw(y0.y); a0[6]=f2bf_hw(y0.z); a0[7]=f2bf_hw(y0.w);
    a1[0]=f2bf_hw(x1.x); a1[1]=f2bf_hw(x1.y); a1[2]=f2bf_hw(x1.z); a1[3]=f2bf_hw(x1.w);
    a1[4]=f2bf_hw(y1.x); a1[5]=f2bf_hw(y1.y); a1[6]=f2bf_hw(y1.z); a1[7]=f2bf_hw(y1.w);
    bf16x8 b0 = *(const bf16x8*)(bpp0 + (ks << 5));
    bf16x8 b1 = *(const bf16x8*)(bpp1 + (ks << 5));
    acc00 = __builtin_amdgcn_mfma_f32_16x16x32_bf16(a0, b0, acc00, 0, 0, 0);
    acc01 = __builtin_amdgcn_mfma_f32_16x16x32_bf16(a0, b1, acc01, 0, 0, 0);
    acc10 = __builtin_amdgcn_mfma_f32_16x16x32_bf16(a1, b0, acc10, 0, 0, 0);
    acc11 = __builtin_amdgcn_mfma_f32_16x16x32_bf16(a1, b1, acc11, 0, 0, 0);
  }

  int wl = wave & 3;
  if (wk == 1){
    #pragma unroll
    for (int q = 0; q < 4; q++){
      red[wl][lane][q]      = acc00[q];
      red[wl][lane][4 + q]  = acc01[q];
      red[wl][lane][8 + q]  = acc10[q];
      red[wl][lane][12 + q] = acc11[q];
    }
  }
  __syncthreads();
  if (wk == 0){
    #pragma unroll
    for (int q = 0; q < 4; q++){
      acc00[q] += red[wl][lane][q];
      acc01[q] += red[wl][lane][4 + q];
      acc10[q] += red[wl][lane][8 + q];
      acc11[q] += red[wl][lane][12 + q];
    }
    // C/D layout: col = lane&15, row = (lane>>4)*4 + q (m89-verified)
    int q4 = (lane >> 4) * 4, col = lane & 15;
    #pragma unroll
    for (int i = 0; i < 2; i++){
      f32x4 ai0 = (i == 0) ? acc00 : acc10;
      f32x4 ai1 = (i == 0) ? acc01 : acc11;
      #pragma unroll
      for (int q = 0; q < 4; q++){
        int m = m0 + wm * 32 + i * 16 + q4 + q;
        float* orow = out_lat + (((size_t)(b * M0 + m)) << 6);
        orow[wo * 32 + col]      = ai0[q];
        orow[wo * 32 + 16 + col] = ai1[q];
      }
    }
  }
}

// ============ slice + bias + transpose to [b][o][n], 32-row tiles =========
__global__ void k_slice(const float* __restrict__ bary_pv, const int* __restrict__ idx_pv,
                        const float* __restrict__ out_lat, const float* __restrict__ bias,
                        const float* __restrict__ bmul, float* __restrict__ out){
  __shared__ float tile[32][65];
  int b = blockIdx.x >> 5, n0 = (blockIdx.x & 31) * 32;
  int tid = threadIdx.x;
  int wave = tid >> 6, o = tid & 63;
  float bo = bias[o];
  #pragma unroll
  for (int i = 0; i < 8; i++){
    int n = wave * 8 + i;
    int p = (b << 10) + n0 + n;
    float acc = bo * bmul[n0 + n];
    int base = p * NVERT;
    #pragma unroll
    for (int kk = 0; kk < NVERT; kk++){
      int u = idx_pv[base + kk];
      acc += bary_pv[base + kk] * out_lat[(((size_t)(b * M0 + u)) << 6) + o];
    }
    tile[n][o] = acc;
  }
  __syncthreads();
  int nl = tid & 31, ob = (tid >> 5) * 8;
  #pragma unroll
  for (int i = 0; i < 8; i++){
    int o2 = ob + i;
    out[(((size_t)b * 64 + o2) << 10) + n0 + nl] = tile[nl][o2];
  }
}

extern "C" void kernel_launch(void* const* d_in, const int* in_sizes, int n_in,
                              void* d_out, int out_size, void* d_ws, size_t ws_size,
                              hipStream_t stream){
  const float* data = (const float*)d_in[0];
  const float* feat = (const float*)d_in[1];
  const float* wk   = (const float*)d_in[2];
  const float* bias = (const float*)d_in[3];
  const float* bmul = (const float*)d_in[4];
  float* out = (float*)d_out;

  char* ws = (char*)d_ws;
  size_t off = 0;
  auto alloc = [&](size_t bytes){
    void* p = ws + off;
    off = (off + bytes + 255) & ~(size_t)255;
    return p;
  };
  int*   codes_pv = (int*)  alloc((size_t)BATCH * M0 * 4);
  float* bary_pv  = (float*)alloc((size_t)BATCH * M0 * 4);
  int*   idx_pv   = (int*)  alloc((size_t)BATCH * M0 * 4);
  int*   hash_code= (int*)  alloc((size_t)BATCH * CAP * 4);
  int*   hash_uid = (int*)  alloc((size_t)BATCH * CAP * 4);
  int*   ucount   = (int*)  alloc(256);
  int*   ukeys    = (int*)  alloc((size_t)BATCH * M0 * DD * 4);
  float* table    = (float*)alloc(((size_t)BATCH * M0 + 1) * CIN * 4);  // +1 zero row
  float* out_lat  = (float*)alloc((size_t)BATCH * M0 * COUT * 4);
  unsigned short* bp = (unsigned short*)alloc((size_t)COUT * KTOT * 2);
  float* dat_t    = (float*)alloc((size_t)BATCH * NPTS * CIN * 4);
  int*   nuid     = (int*)  alloc((size_t)BATCH * M0 * 32 * 4);

  k_a     <<<1024, 256, 0, stream>>>(wk, data, feat, hash_code, hash_uid, ucount,
                                     (float4*)table, bp, dat_t, codes_pv, bary_pv);
  k_insert<<<BATCH * M0 / 256, 256, 0, stream>>>(codes_pv, hash_code, hash_uid, ucount, ukeys);
  k_sn    <<<BATCH * NPTS / 4 + BATCH * M0 * 32 / 256, 256, 0, stream>>>(
            dat_t, codes_pv, bary_pv, hash_code, hash_uid, ucount, ukeys,
            idx_pv, table, nuid);
  k_conv  <<<BATCH * (M0 / 64), 512, 0, stream>>>(ucount, nuid, table, bp, out_lat);
  k_slice <<<BATCH * 32, 256, 0, stream>>>(bary_pv, idx_pv, out_lat, bias, bmul, out);
}

// Round 11
// 62.209 us; speedup vs baseline: 3.4973x; 1.1535x over previous
//
#include <hip/hip_runtime.h>
#include <hip/hip_bf16.h>
#include <stdint.h>

#define DD 4
#define NVERT 5
#define NPTS 1024
#define BATCH 4
#define M0 5120           /* NPTS*NVERT */
#define CIN 64
#define COUT 64
#define NF 31
#define KTOT 1984         /* NF*CIN */
#define CAP 16384
#define CAPMASK (CAP-1)
#define SENTV 1073741824  /* 2^30, > any valid code (<128^4) */
#define ZROW (BATCH*M0)   /* zero row index in table_bf */

using bf16x8 = __attribute__((ext_vector_type(8))) short;
using f32x4  = __attribute__((ext_vector_type(4))) float;

__device__ __forceinline__ unsigned short f2bf(float x){
  unsigned int u = __float_as_uint(x);
  u = (u + 0x7FFFu + ((u >> 16) & 1u)) >> 16;
  return (unsigned short)u;
}

__device__ __forceinline__ uint32_t hslot(int code){
  return (((uint32_t)code * 2654435761u) >> 18) & CAPMASK;
}

// ---- shared simplex math ----
__device__ __forceinline__ void pv_math(const float* feat, int g, int* code_out, float* bary_out){
  int p = g / NVERT, kk = g % NVERT;
  int b = p >> 10, n = p & 1023;
  const float* fb = feat + (size_t)b * DD * NPTS + n;
  float f0 = fb[0], f1 = fb[NPTS], f2 = fb[2 * NPTS], f3 = fb[3 * NPTS];

  float elev[5];
  elev[0] =  f0 * 2.886751345948129f  + f1 * 1.6666666666666667f + f2 * 1.1785113019775793f + f3 * 0.9128709291752769f;
  elev[1] = -f0 * 2.886751345948129f  + f1 * 1.6666666666666667f + f2 * 1.1785113019775793f + f3 * 0.9128709291752769f;
  elev[2] =  f1 * -3.3333333333333335f + f2 * 1.1785113019775793f + f3 * 0.9128709291752769f;
  elev[3] =  f2 * -3.535533905932738f  + f3 * 0.9128709291752769f;
  elev[4] =  f3 * -3.6514837167011076f;

  int gi[5]; float diff[5]; int sum = 0;
  #pragma unroll
  for (int i = 0; i < 5; i++){
    float gg = rintf(elev[i] * 0.2f) * 5.0f;
    gi[i] = (int)rintf(gg);
    sum += gi[i];
    diff[i] = elev[i] - gg;
  }
  int s = sum / 5;

  int rank[5];
  #pragma unroll
  for (int i = 0; i < 5; i++){
    int r = 0;
    #pragma unroll
    for (int j = 0; j < 5; j++)
      r += (diff[j] > diff[i]) || (diff[j] == diff[i] && j < i);
    rank[i] = r + s;
  }
  #pragma unroll
  for (int i = 0; i < 5; i++){
    if (rank[i] < 0)      { rank[i] += NVERT; gi[i] += NVERT; }
    else if (rank[i] > DD){ rank[i] -= NVERT; gi[i] -= NVERT; }
  }

  float bary[6] = {0.f,0.f,0.f,0.f,0.f,0.f};
  #pragma unroll
  for (int i = 0; i < 5; i++){
    float tt = (elev[i] - (float)gi[i]) * 0.2f;
    bary[DD - rank[i]]    += tt;
    bary[NVERT - rank[i]] += 1.0f - tt;
  }
  bary[0] += 1.0f + bary[5];

  float bk = bary[0];
  #pragma unroll
  for (int i = 1; i < 5; i++) if (i == kk) bk = bary[i];

  int code = 0;
  #pragma unroll
  for (int j = 0; j < DD; j++){
    int add = (rank[j] >= NVERT - kk) ? (kk - NVERT) : kk;
    int key = gi[j] + add;
    key = min(63, max(-64, key));
    code += (key + 64) << (7 * j);
  }
  *code_out = code;
  *bary_out = bk;
}

// ============ A: init + bp + dat_t + pmath (disjoint block ranges) ========
__global__ void k_a(const float* __restrict__ wk, const float* __restrict__ data,
                    const float* __restrict__ feat,
                    int* __restrict__ hc, int* __restrict__ hu, int* __restrict__ uc,
                    float4* __restrict__ table4, unsigned short* __restrict__ bp,
                    float* __restrict__ dat_t,
                    int* __restrict__ codes_pv, float* __restrict__ bary_pv){
  int bid = blockIdx.x, tid = threadIdx.x;
  if (bid < 64){
    __shared__ float tile[64][65];
    int b = bid >> 4, n0 = (bid & 15) * 64;
    int nl = tid & 63;
    #pragma unroll
    for (int i = 0; i < 16; i++){
      int c = (tid >> 6) * 16 + i;
      tile[c][nl] = data[(((size_t)b * 64 + c) << 10) + n0 + nl];
    }
    __syncthreads();
    #pragma unroll
    for (int i = 0; i < 16; i++){
      int nn = (tid >> 6) * 16 + i;
      dat_t[(((size_t)b << 10) + n0 + nn) * 64 + (tid & 63)] = tile[tid & 63][nn];
    }
  } else if (bid < 144){
    int g = (bid - 64) * 256 + tid;
    int code; float bk;
    pv_math(feat, g, &code, &bk);
    codes_pv[g] = code;
    bary_pv[g]  = bk;
  } else if (bid < 640){
    int e = (bid - 144) * 256 + tid;
    int o = e / KTOT, k = e % KTOT;
    int f = k >> 6, c = k & 63;
    bp[e] = f2bf(wk[(o * CIN + c) * NF + f]);
  } else {
    int g = (bid - 640) * 256 + tid;
    int stride = 384 * 256;
    for (int i = g; i < BATCH * CAP; i += stride){ hc[i] = SENTV; hu[i] = -1; }
    if (g < BATCH) uc[g] = 0;
    float4 z = {0.f,0.f,0.f,0.f};
    for (int i = g; i < BATCH * M0 * CIN / 4; i += stride) table4[i] = z;
  }
}

// ============ insert: LDS dedupe + global CAS + wave-aggregated uid =======
__global__ void k_insert(const int* __restrict__ codes_pv,
                         int* __restrict__ hash_code, int* __restrict__ hash_uid,
                         int* __restrict__ ucount, int* __restrict__ ukeys){
  __shared__ int lhash[512];
  int tid = threadIdx.x;
  lhash[tid] = SENTV; lhash[tid + 256] = SENTV;
  __syncthreads();

  int g = blockIdx.x * 256 + tid;
  int b = g / M0;
  int code = codes_pv[g];

  uint32_t lh = (((uint32_t)code * 2654435761u) >> 21) & 511;
  bool rep = false;
  while (true){
    int prev = atomicCAS(&lhash[lh], SENTV, code);
    if (prev == SENTV){ rep = true; break; }
    if (prev == code) break;
    lh = (lh + 1) & 511;
  }

  int myslot = -1;
  if (rep){
    int* hc = hash_code + b * CAP;
    uint32_t h = hslot(code);
    while (true){
      int prev = atomicCAS(&hc[h], SENTV, code);
      if (prev == SENTV){ myslot = (int)h; break; }
      if (prev == code) break;
      h = (h + 1) & CAPMASK;
    }
  }

  unsigned long long mask = __ballot(myslot >= 0);
  if (mask){
    int lane = tid & 63;
    int cnt = __popcll(mask);
    int leader = __ffsll((unsigned long long)mask) - 1;
    int base = 0;
    if (lane == leader) base = atomicAdd(&ucount[b], cnt);
    base = __shfl(base, leader);
    if (myslot >= 0){
      int rank = __popcll(mask & ((1ull << lane) - 1ull));
      int uid = base + rank;
      hash_uid[b * CAP + myslot] = uid;
      int* uk = ukeys + ((size_t)(b * M0 + uid)) * DD;
      #pragma unroll
      for (int j = 0; j < DD; j++) uk[j] = ((code >> (7 * j)) & 127) - 64;
    }
  }
}

// ============ fused: splat (blocks < 1024) + neighbor lookups (rest) ======
__global__ void k_sn(const float* __restrict__ dat_t, const int* __restrict__ codes_pv,
                     const float* __restrict__ bary_pv, const int* __restrict__ hash_code,
                     const int* __restrict__ hash_uid, const int* __restrict__ ucount,
                     const int* __restrict__ ukeys,
                     int* __restrict__ idx_pv, float* __restrict__ table,
                     int* __restrict__ nuid){
  int bid = blockIdx.x, tid = threadIdx.x;
  if (bid < BATCH * NPTS / 4){
    __shared__ int   us[4][8];
    __shared__ float wbs[4][8];
    int w = tid >> 6, lane = tid & 63;
    int p = bid * 4 + w;
    int b = p >> 10;
    float v = dat_t[((size_t)p << 6) + lane];
    if (lane < NVERT){
      int code = codes_pv[p * NVERT + lane];
      const int* hc = hash_code + b * CAP;
      uint32_t h = hslot(code);
      while (hc[h] != code) h = (h + 1) & CAPMASK;
      int uid = hash_uid[b * CAP + h];
      us[w][lane]  = uid;
      wbs[w][lane] = bary_pv[p * NVERT + lane];
      idx_pv[p * NVERT + lane] = uid;
    }
    __syncthreads();
    int rot = p % NVERT;
    #pragma unroll
    for (int kq = 0; kq < NVERT; kq++){
      int kk = kq + rot; if (kk >= NVERT) kk -= NVERT;
      atomicAdd(&table[(((size_t)(b * M0 + us[w][kk])) << 6) + lane], v * wbs[w][kk]);
    }
  } else {
    int e = (bid - BATCH * NPTS / 4) * 256 + tid;
    int f = e & 31;
    int idx = e >> 5;
    int b = idx / M0, m = idx - b * M0;
    int g = ZROW;
    if (f < NF && m < ucount[b]){
      const int* uk = ukeys + ((size_t)idx) * DD;
      int pc = __popc(f);
      int code = 0;
      #pragma unroll
      for (int j = 0; j < DD; j++){
        int key = uk[j] + 5 * ((f >> j) & 1) - pc;
        key = min(63, max(-64, key));
        code += (key + 64) << (7 * j);
      }
      const int* hc = hash_code + b * CAP;
      uint32_t h = hslot(code);
      while (true){
        int v = hc[h];
        if (v == code){ g = b * M0 + hash_uid[b * CAP + h]; break; }
        if (v == SENTV) break;
        h = (h + 1) & CAPMASK;
      }
    }
    nuid[e] = g;
  }
}

// ============ table fp32 -> bf16 (+ zero row) ==============================
__global__ void k_tobf(const float* __restrict__ table, unsigned short* __restrict__ table_bf){
  int g = blockIdx.x * blockDim.x + threadIdx.x;
  size_t base = (size_t)g * 8;
  const float4* s4 = (const float4*)(table + base);
  float4 x = s4[0], y = s4[1];
  bf16x8 v;
  v[0] = (short)f2bf(x.x); v[1] = (short)f2bf(x.y);
  v[2] = (short)f2bf(x.z); v[3] = (short)f2bf(x.w);
  v[4] = (short)f2bf(y.x); v[5] = (short)f2bf(y.y);
  v[6] = (short)f2bf(y.z); v[7] = (short)f2bf(y.w);
  *(bf16x8*)(table_bf + base) = v;
  if (g < 8){
    bf16x8 z = {0,0,0,0,0,0,0,0};
    *(bf16x8*)(table_bf + ((size_t)ZROW << 6) + g * 8) = z;
  }
}

// ============ conv: 16 waves, 4-way k-split, prefetched bf16 gathers ======
__launch_bounds__(1024, 4)
__global__ void k_conv(const int* __restrict__ ucount, const int* __restrict__ nuid,
                       const unsigned short* __restrict__ table_bf,
                       const unsigned short* __restrict__ bp,
                       float* __restrict__ out_lat){
  __shared__ int gidx_s[64 * 33];
  __shared__ float red[3][4][64][17];

  int blk = blockIdx.x;
  int b   = blk / (M0 / 64);
  int m0  = (blk % (M0 / 64)) * 64;
  if (m0 >= ucount[b]) return;

  int tid = threadIdx.x;
  {
    int base = (b * M0 + m0) << 5;
    #pragma unroll
    for (int i = 0; i < 2; i++){
      int idx = tid + i * 1024;
      gidx_s[(idx >> 5) * 33 + (idx & 31)] = nuid[base + idx];
    }
  }
  __syncthreads();

  int lane = tid & 63, wave = tid >> 6;
  int wm = wave & 1, wo = (wave >> 1) & 1, wk = wave >> 2;
  int arow = wm * 32 + (lane & 15);
  int acol = (lane >> 4) * 8;
  int bcol = wo * 32 + (lane & 15);
  const unsigned short* bpp0 = bp + (size_t)bcol * KTOT + acol;
  const unsigned short* bpp1 = bpp0 + (size_t)16 * KTOT;

  f32x4 acc00 = {0.f,0.f,0.f,0.f}, acc01 = {0.f,0.f,0.f,0.f};
  f32x4 acc10 = {0.f,0.f,0.f,0.f}, acc11 = {0.f,0.f,0.f,0.f};

  const int kstart[5] = {0, 16, 32, 47, 62};
  int ks0 = kstart[wk], ks1 = kstart[wk + 1];
  int klast = ks1 - 1;

  // prefetch stage 0
  int fP = ks0 >> 1, cP = (ks0 & 1) << 5;
  bf16x8 a0 = *(const bf16x8*)(table_bf + (((size_t)gidx_s[arow * 33 + fP]) << 6) + cP + acol);
  bf16x8 a1 = *(const bf16x8*)(table_bf + (((size_t)gidx_s[(arow + 16) * 33 + fP]) << 6) + cP + acol);

  #pragma unroll 2
  for (int ks = ks0; ks < ks1; ks++){
    bf16x8 ca0 = a0, ca1 = a1;
    // branch-free prefetch of next iteration (clamped; last iter re-loads itself)
    int ksn = ks + 1 > klast ? klast : ks + 1;
    int fn = ksn >> 1, c0n = (ksn & 1) << 5;
    a0 = *(const bf16x8*)(table_bf + (((size_t)gidx_s[arow * 33 + fn]) << 6) + c0n + acol);
    a1 = *(const bf16x8*)(table_bf + (((size_t)gidx_s[(arow + 16) * 33 + fn]) << 6) + c0n + acol);

    bf16x8 b0 = *(const bf16x8*)(bpp0 + (ks << 5));
    bf16x8 b1 = *(const bf16x8*)(bpp1 + (ks << 5));
    acc00 = __builtin_amdgcn_mfma_f32_16x16x32_bf16(ca0, b0, acc00, 0, 0, 0);
    acc01 = __builtin_amdgcn_mfma_f32_16x16x32_bf16(ca0, b1, acc01, 0, 0, 0);
    acc10 = __builtin_amdgcn_mfma_f32_16x16x32_bf16(ca1, b0, acc10, 0, 0, 0);
    acc11 = __builtin_amdgcn_mfma_f32_16x16x32_bf16(ca1, b1, acc11, 0, 0, 0);
  }

  int quad = wm * 2 + wo;
  if (wk > 0){
    #pragma unroll
    for (int q = 0; q < 4; q++){
      red[wk - 1][quad][lane][q]      = acc00[q];
      red[wk - 1][quad][lane][4 + q]  = acc01[q];
      red[wk - 1][quad][lane][8 + q]  = acc10[q];
      red[wk - 1][quad][lane][12 + q] = acc11[q];
    }
  }
  __syncthreads();
  if (wk == 0){
    #pragma unroll
    for (int r = 0; r < 3; r++){
      #pragma unroll
      for (int q = 0; q < 4; q++){
        acc00[q] += red[r][quad][lane][q];
        acc01[q] += red[r][quad][lane][4 + q];
        acc10[q] += red[r][quad][lane][8 + q];
        acc11[q] += red[r][quad][lane][12 + q];
      }
    }
    // C/D layout: col = lane&15, row = (lane>>4)*4 + q (m89-verified)
    int q4 = (lane >> 4) * 4, col = lane & 15;
    #pragma unroll
    for (int i = 0; i < 2; i++){
      f32x4 ai0 = (i == 0) ? acc00 : acc10;
      f32x4 ai1 = (i == 0) ? acc01 : acc11;
      #pragma unroll
      for (int q = 0; q < 4; q++){
        int m = m0 + wm * 32 + i * 16 + q4 + q;
        float* orow = out_lat + (((size_t)(b * M0 + m)) << 6);
        orow[wo * 32 + col]      = ai0[q];
        orow[wo * 32 + 16 + col] = ai1[q];
      }
    }
  }
}

// ============ slice + bias + transpose to [b][o][n], 32-row tiles =========
__global__ void k_slice(const float* __restrict__ bary_pv, const int* __restrict__ idx_pv,
                        const float* __restrict__ out_lat, const float* __restrict__ bias,
                        const float* __restrict__ bmul, float* __restrict__ out){
  __shared__ float tile[32][65];
  int b = blockIdx.x >> 5, n0 = (blockIdx.x & 31) * 32;
  int tid = threadIdx.x;
  int wave = tid >> 6, o = tid & 63;
  float bo = bias[o];
  #pragma unroll
  for (int i = 0; i < 8; i++){
    int n = wave * 8 + i;
    int p = (b << 10) + n0 + n;
    float acc = bo * bmul[n0 + n];
    int base = p * NVERT;
    #pragma unroll
    for (int kk = 0; kk < NVERT; kk++){
      int u = idx_pv[base + kk];
      acc += bary_pv[base + kk] * out_lat[(((size_t)(b * M0 + u)) << 6) + o];
    }
    tile[n][o] = acc;
  }
  __syncthreads();
  int nl = tid & 31, ob = (tid >> 5) * 8;
  #pragma unroll
  for (int i = 0; i < 8; i++){
    int o2 = ob + i;
    out[(((size_t)b * 64 + o2) << 10) + n0 + nl] = tile[nl][o2];
  }
}

extern "C" void kernel_launch(void* const* d_in, const int* in_sizes, int n_in,
                              void* d_out, int out_size, void* d_ws, size_t ws_size,
                              hipStream_t stream){
  const float* data = (const float*)d_in[0];
  const float* feat = (const float*)d_in[1];
  const float* wk   = (const float*)d_in[2];
  const float* bias = (const float*)d_in[3];
  const float* bmul = (const float*)d_in[4];
  float* out = (float*)d_out;

  char* ws = (char*)d_ws;
  size_t off = 0;
  auto alloc = [&](size_t bytes){
    void* p = ws + off;
    off = (off + bytes + 255) & ~(size_t)255;
    return p;
  };
  int*   codes_pv = (int*)  alloc((size_t)BATCH * M0 * 4);
  float* bary_pv  = (float*)alloc((size_t)BATCH * M0 * 4);
  int*   idx_pv   = (int*)  alloc((size_t)BATCH * M0 * 4);
  int*   hash_code= (int*)  alloc((size_t)BATCH * CAP * 4);
  int*   hash_uid = (int*)  alloc((size_t)BATCH * CAP * 4);
  int*   ucount   = (int*)  alloc(256);
  int*   ukeys    = (int*)  alloc((size_t)BATCH * M0 * DD * 4);
  float* table    = (float*)alloc((size_t)BATCH * M0 * CIN * 4);
  float* out_lat  = (float*)alloc((size_t)BATCH * M0 * COUT * 4);
  unsigned short* bp       = (unsigned short*)alloc((size_t)COUT * KTOT * 2);
  unsigned short* table_bf = (unsigned short*)alloc(((size_t)BATCH * M0 + 8) * CIN * 2);
  float* dat_t    = (float*)alloc((size_t)BATCH * NPTS * CIN * 4);
  int*   nuid     = (int*)  alloc((size_t)BATCH * M0 * 32 * 4);

  k_a     <<<1024, 256, 0, stream>>>(wk, data, feat, hash_code, hash_uid, ucount,
                                     (float4*)table, bp, dat_t, codes_pv, bary_pv);
  k_insert<<<BATCH * M0 / 256, 256, 0, stream>>>(codes_pv, hash_code, hash_uid, ucount, ukeys);
  k_sn    <<<BATCH * NPTS / 4 + BATCH * M0 * 32 / 256, 256, 0, stream>>>(
            dat_t, codes_pv, bary_pv, hash_code, hash_uid, ucount, ukeys,
            idx_pv, table, nuid);
  k_tobf  <<<BATCH * M0 * CIN / 8 / 256, 256, 0, stream>>>(table, table_bf);
  k_conv  <<<BATCH * (M0 / 64), 1024, 0, stream>>>(ucount, nuid, table_bf, bp, out_lat);
  k_slice <<<BATCH * 32, 256, 0, stream>>>(bary_pv, idx_pv, out_lat, bias, bmul, out);
}

// Round 12
// 62.134 us; speedup vs baseline: 3.5016x; 1.0012x over previous
//
#include <hip/hip_runtime.h>
#include <hip/hip_bf16.h>
#include <stdint.h>

#define DD 4
#define NVERT 5
#define NPTS 1024
#define BATCH 4
#define M0 5120           /* NPTS*NVERT */
#define CIN 64
#define COUT 64
#define NF 31
#define KTOT 1984         /* NF*CIN */
#define CAP 16384
#define CAPMASK (CAP-1)
#define SENTV 1073741824  /* 2^30, > any valid code (<128^4) */
#define ZROW (BATCH*M0)   /* zero row index in table_bf */

using bf16x8 = __attribute__((ext_vector_type(8))) short;
using f32x4  = __attribute__((ext_vector_type(4))) float;

__device__ __forceinline__ unsigned short f2bf(float x){
  unsigned int u = __float_as_uint(x);
  u = (u + 0x7FFFu + ((u >> 16) & 1u)) >> 16;
  return (unsigned short)u;
}

__device__ __forceinline__ uint32_t hslot(int code){
  return (((uint32_t)code * 2654435761u) >> 18) & CAPMASK;
}

// ---- shared simplex math ----
__device__ __forceinline__ void pv_math(const float* feat, int g, int* code_out, float* bary_out){
  int p = g / NVERT, kk = g % NVERT;
  int b = p >> 10, n = p & 1023;
  const float* fb = feat + (size_t)b * DD * NPTS + n;
  float f0 = fb[0], f1 = fb[NPTS], f2 = fb[2 * NPTS], f3 = fb[3 * NPTS];

  float elev[5];
  elev[0] =  f0 * 2.886751345948129f  + f1 * 1.6666666666666667f + f2 * 1.1785113019775793f + f3 * 0.9128709291752769f;
  elev[1] = -f0 * 2.886751345948129f  + f1 * 1.6666666666666667f + f2 * 1.1785113019775793f + f3 * 0.9128709291752769f;
  elev[2] =  f1 * -3.3333333333333335f + f2 * 1.1785113019775793f + f3 * 0.9128709291752769f;
  elev[3] =  f2 * -3.535533905932738f  + f3 * 0.9128709291752769f;
  elev[4] =  f3 * -3.6514837167011076f;

  int gi[5]; float diff[5]; int sum = 0;
  #pragma unroll
  for (int i = 0; i < 5; i++){
    float gg = rintf(elev[i] * 0.2f) * 5.0f;
    gi[i] = (int)rintf(gg);
    sum += gi[i];
    diff[i] = elev[i] - gg;
  }
  int s = sum / 5;

  int rank[5];
  #pragma unroll
  for (int i = 0; i < 5; i++){
    int r = 0;
    #pragma unroll
    for (int j = 0; j < 5; j++)
      r += (diff[j] > diff[i]) || (diff[j] == diff[i] && j < i);
    rank[i] = r + s;
  }
  #pragma unroll
  for (int i = 0; i < 5; i++){
    if (rank[i] < 0)      { rank[i] += NVERT; gi[i] += NVERT; }
    else if (rank[i] > DD){ rank[i] -= NVERT; gi[i] -= NVERT; }
  }

  float bary[6] = {0.f,0.f,0.f,0.f,0.f,0.f};
  #pragma unroll
  for (int i = 0; i < 5; i++){
    float tt = (elev[i] - (float)gi[i]) * 0.2f;
    bary[DD - rank[i]]    += tt;
    bary[NVERT - rank[i]] += 1.0f - tt;
  }
  bary[0] += 1.0f + bary[5];

  float bk = bary[0];
  #pragma unroll
  for (int i = 1; i < 5; i++) if (i == kk) bk = bary[i];

  int code = 0;
  #pragma unroll
  for (int j = 0; j < DD; j++){
    int add = (rank[j] >= NVERT - kk) ? (kk - NVERT) : kk;
    int key = gi[j] + add;
    key = min(63, max(-64, key));
    code += (key + 64) << (7 * j);
  }
  *code_out = code;
  *bary_out = bk;
}

// ============ A: init + bp + dat_t + pmath (disjoint block ranges) ========
__global__ void k_a(const float* __restrict__ wk, const float* __restrict__ data,
                    const float* __restrict__ feat,
                    int* __restrict__ hc, int* __restrict__ hu, int* __restrict__ uc,
                    float4* __restrict__ table4, unsigned short* __restrict__ bp,
                    float* __restrict__ dat_t,
                    int* __restrict__ codes_pv, float* __restrict__ bary_pv){
  int bid = blockIdx.x, tid = threadIdx.x;
  if (bid < 64){
    __shared__ float tile[64][65];
    int b = bid >> 4, n0 = (bid & 15) * 64;
    int nl = tid & 63;
    #pragma unroll
    for (int i = 0; i < 16; i++){
      int c = (tid >> 6) * 16 + i;
      tile[c][nl] = data[(((size_t)b * 64 + c) << 10) + n0 + nl];
    }
    __syncthreads();
    #pragma unroll
    for (int i = 0; i < 16; i++){
      int nn = (tid >> 6) * 16 + i;
      dat_t[(((size_t)b << 10) + n0 + nn) * 64 + (tid & 63)] = tile[tid & 63][nn];
    }
  } else if (bid < 144){
    int g = (bid - 64) * 256 + tid;
    int code; float bk;
    pv_math(feat, g, &code, &bk);
    codes_pv[g] = code;
    bary_pv[g]  = bk;
  } else if (bid < 640){
    int e = (bid - 144) * 256 + tid;
    int o = e / KTOT, k = e % KTOT;
    int f = k >> 6, c = k & 63;
    bp[e] = f2bf(wk[(o * CIN + c) * NF + f]);
  } else {
    int g = (bid - 640) * 256 + tid;
    int stride = 384 * 256;
    for (int i = g; i < BATCH * CAP; i += stride){ hc[i] = SENTV; hu[i] = -1; }
    if (g < BATCH) uc[g] = 0;
    float4 z = {0.f,0.f,0.f,0.f};
    for (int i = g; i < BATCH * M0 * CIN / 4; i += stride) table4[i] = z;
  }
}

// ============ insert: LDS dedupe + global CAS + wave-aggregated uid =======
__global__ void k_insert(const int* __restrict__ codes_pv,
                         int* __restrict__ hash_code, int* __restrict__ hash_uid,
                         int* __restrict__ ucount, int* __restrict__ ukeys){
  __shared__ int lhash[512];
  int tid = threadIdx.x;
  lhash[tid] = SENTV; lhash[tid + 256] = SENTV;
  __syncthreads();

  int g = blockIdx.x * 256 + tid;
  int b = g / M0;
  int code = codes_pv[g];

  uint32_t lh = (((uint32_t)code * 2654435761u) >> 21) & 511;
  bool rep = false;
  while (true){
    int prev = atomicCAS(&lhash[lh], SENTV, code);
    if (prev == SENTV){ rep = true; break; }
    if (prev == code) break;
    lh = (lh + 1) & 511;
  }

  int myslot = -1;
  if (rep){
    int* hc = hash_code + b * CAP;
    uint32_t h = hslot(code);
    while (true){
      int prev = atomicCAS(&hc[h], SENTV, code);
      if (prev == SENTV){ myslot = (int)h; break; }
      if (prev == code) break;
      h = (h + 1) & CAPMASK;
    }
  }

  unsigned long long mask = __ballot(myslot >= 0);
  if (mask){
    int lane = tid & 63;
    int cnt = __popcll(mask);
    int leader = __ffsll((unsigned long long)mask) - 1;
    int base = 0;
    if (lane == leader) base = atomicAdd(&ucount[b], cnt);
    base = __shfl(base, leader);
    if (myslot >= 0){
      int rank = __popcll(mask & ((1ull << lane) - 1ull));
      int uid = base + rank;
      hash_uid[b * CAP + myslot] = uid;
      int* uk = ukeys + ((size_t)(b * M0 + uid)) * DD;
      #pragma unroll
      for (int j = 0; j < DD; j++) uk[j] = ((code >> (7 * j)) & 127) - 64;
    }
  }
}

// ============ fused: splat (blocks < 1024) + neighbor lookups (rest) ======
__global__ void k_sn(const float* __restrict__ dat_t, const int* __restrict__ codes_pv,
                     const float* __restrict__ bary_pv, const int* __restrict__ hash_code,
                     const int* __restrict__ hash_uid, const int* __restrict__ ucount,
                     const int* __restrict__ ukeys,
                     int* __restrict__ idx_pv, float* __restrict__ table,
                     int* __restrict__ nuid){
  int bid = blockIdx.x, tid = threadIdx.x;
  if (bid < BATCH * NPTS / 4){
    __shared__ int   us[4][8];
    __shared__ float wbs[4][8];
    int w = tid >> 6, lane = tid & 63;
    int p = bid * 4 + w;
    int b = p >> 10;
    float v = dat_t[((size_t)p << 6) + lane];
    if (lane < NVERT){
      int code = codes_pv[p * NVERT + lane];
      const int* hc = hash_code + b * CAP;
      uint32_t h = hslot(code);
      while (hc[h] != code) h = (h + 1) & CAPMASK;
      int uid = hash_uid[b * CAP + h];
      us[w][lane]  = uid;
      wbs[w][lane] = bary_pv[p * NVERT + lane];
      idx_pv[p * NVERT + lane] = uid;
    }
    __syncthreads();
    int rot = p % NVERT;
    #pragma unroll
    for (int kq = 0; kq < NVERT; kq++){
      int kk = kq + rot; if (kk >= NVERT) kk -= NVERT;
      atomicAdd(&table[(((size_t)(b * M0 + us[w][kk])) << 6) + lane], v * wbs[w][kk]);
    }
  } else {
    int e = (bid - BATCH * NPTS / 4) * 256 + tid;
    int f = e & 31;
    int idx = e >> 5;
    int b = idx / M0, m = idx - b * M0;
    int g = ZROW;
    if (f < NF && m < ucount[b]){
      const int* uk = ukeys + ((size_t)idx) * DD;
      int pc = __popc(f);
      int code = 0;
      #pragma unroll
      for (int j = 0; j < DD; j++){
        int key = uk[j] + 5 * ((f >> j) & 1) - pc;
        key = min(63, max(-64, key));
        code += (key + 64) << (7 * j);
      }
      const int* hc = hash_code + b * CAP;
      uint32_t h = hslot(code);
      while (true){
        int v = hc[h];
        if (v == code){ g = b * M0 + hash_uid[b * CAP + h]; break; }
        if (v == SENTV) break;
        h = (h + 1) & CAPMASK;
      }
    }
    nuid[e] = g;
  }
}

// ============ table fp32 -> bf16 (+ zero row) ==============================
__global__ void k_tobf(const float* __restrict__ table, unsigned short* __restrict__ table_bf){
  int g = blockIdx.x * blockDim.x + threadIdx.x;
  size_t base = (size_t)g * 8;
  const float4* s4 = (const float4*)(table + base);
  float4 x = s4[0], y = s4[1];
  bf16x8 v;
  v[0] = (short)f2bf(x.x); v[1] = (short)f2bf(x.y);
  v[2] = (short)f2bf(x.z); v[3] = (short)f2bf(x.w);
  v[4] = (short)f2bf(y.x); v[5] = (short)f2bf(y.y);
  v[6] = (short)f2bf(y.z); v[7] = (short)f2bf(y.w);
  *(bf16x8*)(table_bf + base) = v;
  if (g < 8){
    bf16x8 z = {0,0,0,0,0,0,0,0};
    *(bf16x8*)(table_bf + ((size_t)ZROW << 6) + g * 8) = z;
  }
}

// ============ conv: 16 waves, 4-way f-split, batched prefetched gathers ===
__launch_bounds__(1024, 4)
__global__ void k_conv(const int* __restrict__ ucount, const int* __restrict__ nuid,
                       const unsigned short* __restrict__ table_bf,
                       const unsigned short* __restrict__ bp,
                       float* __restrict__ out_lat){
  __shared__ int gidx_s[64 * 33];
  __shared__ float red[3][4][64][17];

  int blk = blockIdx.x;
  int b   = blk / (M0 / 64);
  int m0  = (blk % (M0 / 64)) * 64;
  if (m0 >= ucount[b]) return;

  int tid = threadIdx.x;
  {
    int base = (b * M0 + m0) << 5;
    #pragma unroll
    for (int i = 0; i < 2; i++){
      int idx = tid + i * 1024;
      gidx_s[(idx >> 5) * 33 + (idx & 31)] = nuid[base + idx];
    }
  }
  __syncthreads();

  int lane = tid & 63, wave = tid >> 6;
  int wm = wave & 1, wo = (wave >> 1) & 1, wk = wave >> 2;
  int arow = wm * 32 + (lane & 15);
  int acol = (lane >> 4) * 8;
  int bcol = wo * 32 + (lane & 15);
  const unsigned short* bpp0 = bp + (size_t)bcol * KTOT + acol;
  const unsigned short* bpp1 = bpp0 + (size_t)16 * KTOT;

  f32x4 acc00 = {0.f,0.f,0.f,0.f}, acc01 = {0.f,0.f,0.f,0.f};
  f32x4 acc10 = {0.f,0.f,0.f,0.f}, acc11 = {0.f,0.f,0.f,0.f};

  const int kfs[5] = {0, 8, 16, 24, 31};
  int f0 = kfs[wk], f1 = kfs[wk + 1], flast = f1 - 1;

  // prefetch iteration f0: both rows x both 32-col halves (4 independent gathers)
  const unsigned short* r0p = table_bf + (((size_t)gidx_s[arow * 33 + f0]) << 6) + acol;
  const unsigned short* r1p = table_bf + (((size_t)gidx_s[(arow + 16) * 33 + f0]) << 6) + acol;
  bf16x8 A00 = *(const bf16x8*)(r0p);
  bf16x8 A01 = *(const bf16x8*)(r0p + 32);
  bf16x8 A10 = *(const bf16x8*)(r1p);
  bf16x8 A11 = *(const bf16x8*)(r1p + 32);

  #pragma unroll 2
  for (int f = f0; f < f1; f++){
    bf16x8 c00 = A00, c01 = A01, c10 = A10, c11 = A11;
    // batched branch-free prefetch of next f (clamped; last iter reloads itself)
    int fn = f + 1 > flast ? flast : f + 1;
    const unsigned short* n0p = table_bf + (((size_t)gidx_s[arow * 33 + fn]) << 6) + acol;
    const unsigned short* n1p = table_bf + (((size_t)gidx_s[(arow + 16) * 33 + fn]) << 6) + acol;
    A00 = *(const bf16x8*)(n0p);
    A01 = *(const bf16x8*)(n0p + 32);
    A10 = *(const bf16x8*)(n1p);
    A11 = *(const bf16x8*)(n1p + 32);

    int ks2 = f << 1;
    bf16x8 B00 = *(const bf16x8*)(bpp0 + (ks2 << 5));          // b0, half0
    bf16x8 B01 = *(const bf16x8*)(bpp0 + ((ks2 + 1) << 5));    // b0, half1
    bf16x8 B10 = *(const bf16x8*)(bpp1 + (ks2 << 5));          // b1, half0
    bf16x8 B11 = *(const bf16x8*)(bpp1 + ((ks2 + 1) << 5));    // b1, half1

    acc00 = __builtin_amdgcn_mfma_f32_16x16x32_bf16(c00, B00, acc00, 0, 0, 0);
    acc00 = __builtin_amdgcn_mfma_f32_16x16x32_bf16(c01, B01, acc00, 0, 0, 0);
    acc01 = __builtin_amdgcn_mfma_f32_16x16x32_bf16(c00, B10, acc01, 0, 0, 0);
    acc01 = __builtin_amdgcn_mfma_f32_16x16x32_bf16(c01, B11, acc01, 0, 0, 0);
    acc10 = __builtin_amdgcn_mfma_f32_16x16x32_bf16(c10, B00, acc10, 0, 0, 0);
    acc10 = __builtin_amdgcn_mfma_f32_16x16x32_bf16(c11, B01, acc10, 0, 0, 0);
    acc11 = __builtin_amdgcn_mfma_f32_16x16x32_bf16(c10, B10, acc11, 0, 0, 0);
    acc11 = __builtin_amdgcn_mfma_f32_16x16x32_bf16(c11, B11, acc11, 0, 0, 0);
  }

  int quad = wm * 2 + wo;
  if (wk > 0){
    #pragma unroll
    for (int q = 0; q < 4; q++){
      red[wk - 1][quad][lane][q]      = acc00[q];
      red[wk - 1][quad][lane][4 + q]  = acc01[q];
      red[wk - 1][quad][lane][8 + q]  = acc10[q];
      red[wk - 1][quad][lane][12 + q] = acc11[q];
    }
  }
  __syncthreads();
  if (wk == 0){
    #pragma unroll
    for (int r = 0; r < 3; r++){
      #pragma unroll
      for (int q = 0; q < 4; q++){
        acc00[q] += red[r][quad][lane][q];
        acc01[q] += red[r][quad][lane][4 + q];
        acc10[q] += red[r][quad][lane][8 + q];
        acc11[q] += red[r][quad][lane][12 + q];
      }
    }
    // C/D layout: col = lane&15, row = (lane>>4)*4 + q (m89-verified)
    int q4 = (lane >> 4) * 4, col = lane & 15;
    #pragma unroll
    for (int i = 0; i < 2; i++){
      f32x4 ai0 = (i == 0) ? acc00 : acc10;
      f32x4 ai1 = (i == 0) ? acc01 : acc11;
      #pragma unroll
      for (int q = 0; q < 4; q++){
        int m = m0 + wm * 32 + i * 16 + q4 + q;
        float* orow = out_lat + (((size_t)(b * M0 + m)) << 6);
        orow[wo * 32 + col]      = ai0[q];
        orow[wo * 32 + 16 + col] = ai1[q];
      }
    }
  }
}

// ============ slice + bias + transpose to [b][o][n], 32-row tiles =========
__global__ void k_slice(const float* __restrict__ bary_pv, const int* __restrict__ idx_pv,
                        const float* __restrict__ out_lat, const float* __restrict__ bias,
                        const float* __restrict__ bmul, float* __restrict__ out){
  __shared__ float tile[32][65];
  int b = blockIdx.x >> 5, n0 = (blockIdx.x & 31) * 32;
  int tid = threadIdx.x;
  int wave = tid >> 6, o = tid & 63;
  float bo = bias[o];
  #pragma unroll
  for (int i = 0; i < 8; i++){
    int n = wave * 8 + i;
    int p = (b << 10) + n0 + n;
    float acc = bo * bmul[n0 + n];
    int base = p * NVERT;
    #pragma unroll
    for (int kk = 0; kk < NVERT; kk++){
      int u = idx_pv[base + kk];
      acc += bary_pv[base + kk] * out_lat[(((size_t)(b * M0 + u)) << 6) + o];
    }
    tile[n][o] = acc;
  }
  __syncthreads();
  int nl = tid & 31, ob = (tid >> 5) * 8;
  #pragma unroll
  for (int i = 0; i < 8; i++){
    int o2 = ob + i;
    out[(((size_t)b * 64 + o2) << 10) + n0 + nl] = tile[nl][o2];
  }
}

extern "C" void kernel_launch(void* const* d_in, const int* in_sizes, int n_in,
                              void* d_out, int out_size, void* d_ws, size_t ws_size,
                              hipStream_t stream){
  const float* data = (const float*)d_in[0];
  const float* feat = (const float*)d_in[1];
  const float* wk   = (const float*)d_in[2];
  const float* bias = (const float*)d_in[3];
  const float* bmul = (const float*)d_in[4];
  float* out = (float*)d_out;

  char* ws = (char*)d_ws;
  size_t off = 0;
  auto alloc = [&](size_t bytes){
    void* p = ws + off;
    off = (off + bytes + 255) & ~(size_t)255;
    return p;
  };
  int*   codes_pv = (int*)  alloc((size_t)BATCH * M0 * 4);
  float* bary_pv  = (float*)alloc((size_t)BATCH * M0 * 4);
  int*   idx_pv   = (int*)  alloc((size_t)BATCH * M0 * 4);
  int*   hash_code= (int*)  alloc((size_t)BATCH * CAP * 4);
  int*   hash_uid = (int*)  alloc((size_t)BATCH * CAP * 4);
  int*   ucount   = (int*)  alloc(256);
  int*   ukeys    = (int*)  alloc((size_t)BATCH * M0 * DD * 4);
  float* table    = (float*)alloc((size_t)BATCH * M0 * CIN * 4);
  float* out_lat  = (float*)alloc((size_t)BATCH * M0 * COUT * 4);
  unsigned short* bp       = (unsigned short*)alloc((size_t)COUT * KTOT * 2);
  unsigned short* table_bf = (unsigned short*)alloc(((size_t)BATCH * M0 + 8) * CIN * 2);
  float* dat_t    = (float*)alloc((size_t)BATCH * NPTS * CIN * 4);
  int*   nuid     = (int*)  alloc((size_t)BATCH * M0 * 32 * 4);

  k_a     <<<1024, 256, 0, stream>>>(wk, data, feat, hash_code, hash_uid, ucount,
                                     (float4*)table, bp, dat_t, codes_pv, bary_pv);
  k_insert<<<BATCH * M0 / 256, 256, 0, stream>>>(codes_pv, hash_code, hash_uid, ucount, ukeys);
  k_sn    <<<BATCH * NPTS / 4 + BATCH * M0 * 32 / 256, 256, 0, stream>>>(
            dat_t, codes_pv, bary_pv, hash_code, hash_uid, ucount, ukeys,
            idx_pv, table, nuid);
  k_tobf  <<<BATCH * M0 * CIN / 8 / 256, 256, 0, stream>>>(table, table_bf);
  k_conv  <<<BATCH * (M0 / 64), 1024, 0, stream>>>(ucount, nuid, table_bf, bp, out_lat);
  k_slice <<<BATCH * 32, 256, 0, stream>>>(bary_pv, idx_pv, out_lat, bias, bmul, out);
}

// Round 13
// 52.409 us; speedup vs baseline: 4.1513x; 1.1856x over previous
//
#include <hip/hip_runtime.h>
#include <hip/hip_bf16.h>
#include <stdint.h>

#define DD 4
#define NVERT 5
#define NPTS 1024
#define BATCH 4
#define M0 5120           /* NPTS*NVERT */
#define CIN 64
#define COUT 64
#define NF 31
#define KTOT 1984         /* NF*CIN */
#define CAP 16384
#define CAPMASK (CAP-1)
#define SENTV 1073741824  /* 2^30, > any valid code (<128^4) */
#define ZROW (BATCH*M0)   /* zero row index in table_bf */

using bf16x8 = __attribute__((ext_vector_type(8))) short;
using f32x4  = __attribute__((ext_vector_type(4))) float;

__device__ __forceinline__ unsigned short f2bf(float x){
  unsigned int u = __float_as_uint(x);
  u = (u + 0x7FFFu + ((u >> 16) & 1u)) >> 16;
  return (unsigned short)u;
}

__device__ __forceinline__ uint32_t hslot(int code){
  return (((uint32_t)code * 2654435761u) >> 18) & CAPMASK;
}

// ---- shared simplex math ----
__device__ __forceinline__ void pv_math(const float* feat, int g, int* code_out, float* bary_out){
  int p = g / NVERT, kk = g % NVERT;
  int b = p >> 10, n = p & 1023;
  const float* fb = feat + (size_t)b * DD * NPTS + n;
  float f0 = fb[0], f1 = fb[NPTS], f2 = fb[2 * NPTS], f3 = fb[3 * NPTS];

  float elev[5];
  elev[0] =  f0 * 2.886751345948129f  + f1 * 1.6666666666666667f + f2 * 1.1785113019775793f + f3 * 0.9128709291752769f;
  elev[1] = -f0 * 2.886751345948129f  + f1 * 1.6666666666666667f + f2 * 1.1785113019775793f + f3 * 0.9128709291752769f;
  elev[2] =  f1 * -3.3333333333333335f + f2 * 1.1785113019775793f + f3 * 0.9128709291752769f;
  elev[3] =  f2 * -3.535533905932738f  + f3 * 0.9128709291752769f;
  elev[4] =  f3 * -3.6514837167011076f;

  int gi[5]; float diff[5]; int sum = 0;
  #pragma unroll
  for (int i = 0; i < 5; i++){
    float gg = rintf(elev[i] * 0.2f) * 5.0f;
    gi[i] = (int)rintf(gg);
    sum += gi[i];
    diff[i] = elev[i] - gg;
  }
  int s = sum / 5;

  int rank[5];
  #pragma unroll
  for (int i = 0; i < 5; i++){
    int r = 0;
    #pragma unroll
    for (int j = 0; j < 5; j++)
      r += (diff[j] > diff[i]) || (diff[j] == diff[i] && j < i);
    rank[i] = r + s;
  }
  #pragma unroll
  for (int i = 0; i < 5; i++){
    if (rank[i] < 0)      { rank[i] += NVERT; gi[i] += NVERT; }
    else if (rank[i] > DD){ rank[i] -= NVERT; gi[i] -= NVERT; }
  }

  float bary[6] = {0.f,0.f,0.f,0.f,0.f,0.f};
  #pragma unroll
  for (int i = 0; i < 5; i++){
    float tt = (elev[i] - (float)gi[i]) * 0.2f;
    bary[DD - rank[i]]    += tt;
    bary[NVERT - rank[i]] += 1.0f - tt;
  }
  bary[0] += 1.0f + bary[5];

  float bk = bary[0];
  #pragma unroll
  for (int i = 1; i < 5; i++) if (i == kk) bk = bary[i];

  int code = 0;
  #pragma unroll
  for (int j = 0; j < DD; j++){
    int add = (rank[j] >= NVERT - kk) ? (kk - NVERT) : kk;
    int key = gi[j] + add;
    key = min(63, max(-64, key));
    code += (key + 64) << (7 * j);
  }
  *code_out = code;
  *bary_out = bk;
}

// ============ A: init + bpf + dat_t + pmath (disjoint block ranges) =======
__global__ void k_a(const float* __restrict__ wk, const float* __restrict__ data,
                    const float* __restrict__ feat,
                    int* __restrict__ hc, int* __restrict__ hu, int* __restrict__ uc,
                    float4* __restrict__ table4, unsigned short* __restrict__ bpf,
                    float* __restrict__ dat_t,
                    int* __restrict__ codes_pv, float* __restrict__ bary_pv){
  int bid = blockIdx.x, tid = threadIdx.x;
  if (bid < 64){
    __shared__ float tile[64][65];
    int b = bid >> 4, n0 = (bid & 15) * 64;
    int nl = tid & 63;
    #pragma unroll
    for (int i = 0; i < 16; i++){
      int c = (tid >> 6) * 16 + i;
      tile[c][nl] = data[(((size_t)b * 64 + c) << 10) + n0 + nl];
    }
    __syncthreads();
    #pragma unroll
    for (int i = 0; i < 16; i++){
      int nn = (tid >> 6) * 16 + i;
      dat_t[(((size_t)b << 10) + n0 + nn) * 64 + (tid & 63)] = tile[tid & 63][nn];
    }
  } else if (bid < 144){
    int g = (bid - 64) * 256 + tid;
    int code; float bk;
    pv_math(feat, g, &code, &bk);
    codes_pv[g] = code;
    bary_pv[g]  = bk;
  } else if (bid < 640){
    // ---- weights -> fragment-ordered bpf: 496 blocks cover 126976 exactly
    // e = frag*512 + lane*8 + j ; frag = (f*2+h)*4 + g
    // col = g*16 + (lane&15) ; c = h*32 + (lane>>4)*8 + j ; B[col][f*64+c]
    int e = (bid - 144) * 256 + tid;
    int frag = e >> 9, l = (e >> 3) & 63, j = e & 7;
    int f = frag >> 3, h = (frag >> 2) & 1, g = frag & 3;
    int col = g * 16 + (l & 15);
    int c = h * 32 + ((l >> 4) << 3) + j;
    bpf[e] = f2bf(wk[(col * CIN + c) * NF + f]);
  } else {
    int g = (bid - 640) * 256 + tid;
    int stride = 384 * 256;
    for (int i = g; i < BATCH * CAP; i += stride){ hc[i] = SENTV; hu[i] = -1; }
    if (g < BATCH) uc[g] = 0;
    float4 z = {0.f,0.f,0.f,0.f};
    for (int i = g; i < BATCH * M0 * CIN / 4; i += stride) table4[i] = z;
  }
}

// ============ insert: LDS dedupe + global CAS + wave-aggregated uid =======
__global__ void k_insert(const int* __restrict__ codes_pv,
                         int* __restrict__ hash_code, int* __restrict__ hash_uid,
                         int* __restrict__ ucount, int* __restrict__ ukeys){
  __shared__ int lhash[512];
  int tid = threadIdx.x;
  lhash[tid] = SENTV; lhash[tid + 256] = SENTV;
  __syncthreads();

  int g = blockIdx.x * 256 + tid;
  int b = g / M0;
  int code = codes_pv[g];

  uint32_t lh = (((uint32_t)code * 2654435761u) >> 21) & 511;
  bool rep = false;
  while (true){
    int prev = atomicCAS(&lhash[lh], SENTV, code);
    if (prev == SENTV){ rep = true; break; }
    if (prev == code) break;
    lh = (lh + 1) & 511;
  }

  int myslot = -1;
  if (rep){
    int* hc = hash_code + b * CAP;
    uint32_t h = hslot(code);
    while (true){
      int prev = atomicCAS(&hc[h], SENTV, code);
      if (prev == SENTV){ myslot = (int)h; break; }
      if (prev == code) break;
      h = (h + 1) & CAPMASK;
    }
  }

  unsigned long long mask = __ballot(myslot >= 0);
  if (mask){
    int lane = tid & 63;
    int cnt = __popcll(mask);
    int leader = __ffsll((unsigned long long)mask) - 1;
    int base = 0;
    if (lane == leader) base = atomicAdd(&ucount[b], cnt);
    base = __shfl(base, leader);
    if (myslot >= 0){
      int rank = __popcll(mask & ((1ull << lane) - 1ull));
      int uid = base + rank;
      hash_uid[b * CAP + myslot] = uid;
      int* uk = ukeys + ((size_t)(b * M0 + uid)) * DD;
      #pragma unroll
      for (int j = 0; j < DD; j++) uk[j] = ((code >> (7 * j)) & 127) - 64;
    }
  }
}

// ============ fused: splat (blocks < 1024) + neighbor lookups (rest) ======
__global__ void k_sn(const float* __restrict__ dat_t, const int* __restrict__ codes_pv,
                     const float* __restrict__ bary_pv, const int* __restrict__ hash_code,
                     const int* __restrict__ hash_uid, const int* __restrict__ ucount,
                     const int* __restrict__ ukeys,
                     int* __restrict__ idx_pv, float* __restrict__ table,
                     int* __restrict__ nuid){
  int bid = blockIdx.x, tid = threadIdx.x;
  if (bid < BATCH * NPTS / 4){
    __shared__ int   us[4][8];
    __shared__ float wbs[4][8];
    int w = tid >> 6, lane = tid & 63;
    int p = bid * 4 + w;
    int b = p >> 10;
    float v = dat_t[((size_t)p << 6) + lane];
    if (lane < NVERT){
      int code = codes_pv[p * NVERT + lane];
      const int* hc = hash_code + b * CAP;
      uint32_t h = hslot(code);
      while (hc[h] != code) h = (h + 1) & CAPMASK;
      int uid = hash_uid[b * CAP + h];
      us[w][lane]  = uid;
      wbs[w][lane] = bary_pv[p * NVERT + lane];
      idx_pv[p * NVERT + lane] = uid;
    }
    __syncthreads();
    int rot = p % NVERT;
    #pragma unroll
    for (int kq = 0; kq < NVERT; kq++){
      int kk = kq + rot; if (kk >= NVERT) kk -= NVERT;
      atomicAdd(&table[(((size_t)(b * M0 + us[w][kk])) << 6) + lane], v * wbs[w][kk]);
    }
  } else {
    int e = (bid - BATCH * NPTS / 4) * 256 + tid;
    int f = e & 31;
    int idx = e >> 5;
    int b = idx / M0, m = idx - b * M0;
    int g = ZROW;
    if (f < NF && m < ucount[b]){
      const int* uk = ukeys + ((size_t)idx) * DD;
      int pc = __popc(f);
      int code = 0;
      #pragma unroll
      for (int j = 0; j < DD; j++){
        int key = uk[j] + 5 * ((f >> j) & 1) - pc;
        key = min(63, max(-64, key));
        code += (key + 64) << (7 * j);
      }
      const int* hc = hash_code + b * CAP;
      uint32_t h = hslot(code);
      while (true){
        int v = hc[h];
        if (v == code){ g = b * M0 + hash_uid[b * CAP + h]; break; }
        if (v == SENTV) break;
        h = (h + 1) & CAPMASK;
      }
    }
    nuid[e] = g;
  }
}

// ============ table fp32 -> bf16 (+ zero row) ==============================
__global__ void k_tobf(const float* __restrict__ table, unsigned short* __restrict__ table_bf){
  int g = blockIdx.x * blockDim.x + threadIdx.x;
  size_t base = (size_t)g * 8;
  const float4* s4 = (const float4*)(table + base);
  float4 x = s4[0], y = s4[1];
  bf16x8 v;
  v[0] = (short)f2bf(x.x); v[1] = (short)f2bf(x.y);
  v[2] = (short)f2bf(x.z); v[3] = (short)f2bf(x.w);
  v[4] = (short)f2bf(y.x); v[5] = (short)f2bf(y.y);
  v[6] = (short)f2bf(y.z); v[7] = (short)f2bf(y.w);
  *(bf16x8*)(table_bf + base) = v;
  if (g < 8){
    bf16x8 z = {0,0,0,0,0,0,0,0};
    *(bf16x8*)(table_bf + ((size_t)ZROW << 6) + g * 8) = z;
  }
}

// ============ conv: 16 waves, 4-way f-split, fragment-ordered B ===========
__launch_bounds__(1024, 4)
__global__ void k_conv(const int* __restrict__ ucount, const int* __restrict__ nuid,
                       const unsigned short* __restrict__ table_bf,
                       const unsigned short* __restrict__ bpf,
                       float* __restrict__ out_lat){
  __shared__ int gidx_s[64 * 33];
  __shared__ float red[3][4][64][17];

  int blk = blockIdx.x;
  int b   = blk / (M0 / 64);
  int m0  = (blk % (M0 / 64)) * 64;
  if (m0 >= ucount[b]) return;

  int tid = threadIdx.x;
  {
    int base = (b * M0 + m0) << 5;
    #pragma unroll
    for (int i = 0; i < 2; i++){
      int idx = tid + i * 1024;
      gidx_s[(idx >> 5) * 33 + (idx & 31)] = nuid[base + idx];
    }
  }
  __syncthreads();

  int lane = tid & 63, wave = tid >> 6;
  int wm = wave & 1, wo = (wave >> 1) & 1, wk = wave >> 2;
  int arow = wm * 32 + (lane & 15);
  int acol = (lane >> 4) * 8;
  int wo2 = wo * 2;
  const unsigned short* bf_lane = bpf + ((size_t)lane << 3);

  f32x4 acc00 = {0.f,0.f,0.f,0.f}, acc01 = {0.f,0.f,0.f,0.f};
  f32x4 acc10 = {0.f,0.f,0.f,0.f}, acc11 = {0.f,0.f,0.f,0.f};

  const int kfs[5] = {0, 8, 16, 24, 31};
  int f0 = kfs[wk], f1 = kfs[wk + 1], flast = f1 - 1;

  // prefetch iteration f0: both rows x both 32-col halves (4 independent gathers)
  const unsigned short* r0p = table_bf + (((size_t)gidx_s[arow * 33 + f0]) << 6) + acol;
  const unsigned short* r1p = table_bf + (((size_t)gidx_s[(arow + 16) * 33 + f0]) << 6) + acol;
  bf16x8 A00 = *(const bf16x8*)(r0p);
  bf16x8 A01 = *(const bf16x8*)(r0p + 32);
  bf16x8 A10 = *(const bf16x8*)(r1p);
  bf16x8 A11 = *(const bf16x8*)(r1p + 32);

  #pragma unroll 2
  for (int f = f0; f < f1; f++){
    bf16x8 c00 = A00, c01 = A01, c10 = A10, c11 = A11;
    // batched branch-free prefetch of next f (clamped; last iter reloads itself)
    int fn = f + 1 > flast ? flast : f + 1;
    const unsigned short* n0p = table_bf + (((size_t)gidx_s[arow * 33 + fn]) << 6) + acol;
    const unsigned short* n1p = table_bf + (((size_t)gidx_s[(arow + 16) * 33 + fn]) << 6) + acol;
    A00 = *(const bf16x8*)(n0p);
    A01 = *(const bf16x8*)(n0p + 32);
    A10 = *(const bf16x8*)(n1p);
    A11 = *(const bf16x8*)(n1p + 32);

    // fragment-ordered B: frag = f*8 + h*4 + g ; contiguous 1KB per wave
    int fr = f << 3;
    bf16x8 B00 = *(const bf16x8*)(bf_lane + ((size_t)(fr + wo2)     << 9));  // h0,g=wo2
    bf16x8 B01 = *(const bf16x8*)(bf_lane + ((size_t)(fr + 4 + wo2) << 9));  // h1,g=wo2
    bf16x8 B10 = *(const bf16x8*)(bf_lane + ((size_t)(fr + wo2 + 1) << 9));  // h0,g=wo2+1
    bf16x8 B11 = *(const bf16x8*)(bf_lane + ((size_t)(fr + 4 + wo2 + 1) << 9));

    acc00 = __builtin_amdgcn_mfma_f32_16x16x32_bf16(c00, B00, acc00, 0, 0, 0);
    acc00 = __builtin_amdgcn_mfma_f32_16x16x32_bf16(c01, B01, acc00, 0, 0, 0);
    acc01 = __builtin_amdgcn_mfma_f32_16x16x32_bf16(c00, B10, acc01, 0, 0, 0);
    acc01 = __builtin_amdgcn_mfma_f32_16x16x32_bf16(c01, B11, acc01, 0, 0, 0);
    acc10 = __builtin_amdgcn_mfma_f32_16x16x32_bf16(c10, B00, acc10, 0, 0, 0);
    acc10 = __builtin_amdgcn_mfma_f32_16x16x32_bf16(c11, B01, acc10, 0, 0, 0);
    acc11 = __builtin_amdgcn_mfma_f32_16x16x32_bf16(c10, B10, acc11, 0, 0, 0);
    acc11 = __builtin_amdgcn_mfma_f32_16x16x32_bf16(c11, B11, acc11, 0, 0, 0);
  }

  int quad = wm * 2 + wo;
  if (wk > 0){
    #pragma unroll
    for (int q = 0; q < 4; q++){
      red[wk - 1][quad][lane][q]      = acc00[q];
      red[wk - 1][quad][lane][4 + q]  = acc01[q];
      red[wk - 1][quad][lane][8 + q]  = acc10[q];
      red[wk - 1][quad][lane][12 + q] = acc11[q];
    }
  }
  __syncthreads();
  if (wk == 0){
    #pragma unroll
    for (int r = 0; r < 3; r++){
      #pragma unroll
      for (int q = 0; q < 4; q++){
        acc00[q] += red[r][quad][lane][q];
        acc01[q] += red[r][quad][lane][4 + q];
        acc10[q] += red[r][quad][lane][8 + q];
        acc11[q] += red[r][quad][lane][12 + q];
      }
    }
    // C/D layout: col = lane&15, row = (lane>>4)*4 + q (m89-verified)
    int q4 = (lane >> 4) * 4, col = lane & 15;
    #pragma unroll
    for (int i = 0; i < 2; i++){
      f32x4 ai0 = (i == 0) ? acc00 : acc10;
      f32x4 ai1 = (i == 0) ? acc01 : acc11;
      #pragma unroll
      for (int q = 0; q < 4; q++){
        int m = m0 + wm * 32 + i * 16 + q4 + q;
        float* orow = out_lat + (((size_t)(b * M0 + m)) << 6);
        orow[wo * 32 + col]      = ai0[q];
        orow[wo * 32 + 16 + col] = ai1[q];
      }
    }
  }
}

// ============ slice + bias + transpose to [b][o][n], 32-row tiles =========
__global__ void k_slice(const float* __restrict__ bary_pv, const int* __restrict__ idx_pv,
                        const float* __restrict__ out_lat, const float* __restrict__ bias,
                        const float* __restrict__ bmul, float* __restrict__ out){
  __shared__ float tile[32][65];
  int b = blockIdx.x >> 5, n0 = (blockIdx.x & 31) * 32;
  int tid = threadIdx.x;
  int wave = tid >> 6, o = tid & 63;
  float bo = bias[o];
  #pragma unroll
  for (int i = 0; i < 8; i++){
    int n = wave * 8 + i;
    int p = (b << 10) + n0 + n;
    float acc = bo * bmul[n0 + n];
    int base = p * NVERT;
    #pragma unroll
    for (int kk = 0; kk < NVERT; kk++){
      int u = idx_pv[base + kk];
      acc += bary_pv[base + kk] * out_lat[(((size_t)(b * M0 + u)) << 6) + o];
    }
    tile[n][o] = acc;
  }
  __syncthreads();
  int nl = tid & 31, ob = (tid >> 5) * 8;
  #pragma unroll
  for (int i = 0; i < 8; i++){
    int o2 = ob + i;
    out[(((size_t)b * 64 + o2) << 10) + n0 + nl] = tile[nl][o2];
  }
}

extern "C" void kernel_launch(void* const* d_in, const int* in_sizes, int n_in,
                              void* d_out, int out_size, void* d_ws, size_t ws_size,
                              hipStream_t stream){
  const float* data = (const float*)d_in[0];
  const float* feat = (const float*)d_in[1];
  const float* wk   = (const float*)d_in[2];
  const float* bias = (const float*)d_in[3];
  const float* bmul = (const float*)d_in[4];
  float* out = (float*)d_out;

  char* ws = (char*)d_ws;
  size_t off = 0;
  auto alloc = [&](size_t bytes){
    void* p = ws + off;
    off = (off + bytes + 255) & ~(size_t)255;
    return p;
  };
  int*   codes_pv = (int*)  alloc((size_t)BATCH * M0 * 4);
  float* bary_pv  = (float*)alloc((size_t)BATCH * M0 * 4);
  int*   idx_pv   = (int*)  alloc((size_t)BATCH * M0 * 4);
  int*   hash_code= (int*)  alloc((size_t)BATCH * CAP * 4);
  int*   hash_uid = (int*)  alloc((size_t)BATCH * CAP * 4);
  int*   ucount   = (int*)  alloc(256);
  int*   ukeys    = (int*)  alloc((size_t)BATCH * M0 * DD * 4);
  float* table    = (float*)alloc((size_t)BATCH * M0 * CIN * 4);
  float* out_lat  = (float*)alloc((size_t)BATCH * M0 * COUT * 4);
  unsigned short* bpf      = (unsigned short*)alloc((size_t)COUT * KTOT * 2);
  unsigned short* table_bf = (unsigned short*)alloc(((size_t)BATCH * M0 + 8) * CIN * 2);
  float* dat_t    = (float*)alloc((size_t)BATCH * NPTS * CIN * 4);
  int*   nuid     = (int*)  alloc((size_t)BATCH * M0 * 32 * 4);

  k_a     <<<1024, 256, 0, stream>>>(wk, data, feat, hash_code, hash_uid, ucount,
                                     (float4*)table, bpf, dat_t, codes_pv, bary_pv);
  k_insert<<<BATCH * M0 / 256, 256, 0, stream>>>(codes_pv, hash_code, hash_uid, ucount, ukeys);
  k_sn    <<<BATCH * NPTS / 4 + BATCH * M0 * 32 / 256, 256, 0, stream>>>(
            dat_t, codes_pv, bary_pv, hash_code, hash_uid, ucount, ukeys,
            idx_pv, table, nuid);
  k_tobf  <<<BATCH * M0 * CIN / 8 / 256, 256, 0, stream>>>(table, table_bf);
  k_conv  <<<BATCH * (M0 / 64), 1024, 0, stream>>>(ucount, nuid, table_bf, bpf, out_lat);
  k_slice <<<BATCH * 32, 256, 0, stream>>>(bary_pv, idx_pv, out_lat, bias, bmul, out);
}

// Round 14
// 48.314 us; speedup vs baseline: 4.5032x; 1.0848x over previous
//
#include <hip/hip_runtime.h>
#include <hip/hip_bf16.h>
#include <stdint.h>

#define DD 4
#define NVERT 5
#define NPTS 1024
#define BATCH 4
#define M0 5120           /* NPTS*NVERT */
#define CIN 64
#define COUT 64
#define NF 31
#define KTOT 1984         /* NF*CIN */
#define CAP 16384
#define CAPMASK (CAP-1)
#define SENTV 1073741824  /* 2^30, > any valid code (<128^4) */
#define ZROW (BATCH*M0)   /* zero row index in table_bf */

using bf16x8 = __attribute__((ext_vector_type(8))) short;
using f32x4  = __attribute__((ext_vector_type(4))) float;

__device__ __forceinline__ unsigned short f2bf(float x){
  unsigned int u = __float_as_uint(x);
  u = (u + 0x7FFFu + ((u >> 16) & 1u)) >> 16;
  return (unsigned short)u;
}

__device__ __forceinline__ uint32_t hslot(int code){
  return (((uint32_t)code * 2654435761u) >> 18) & CAPMASK;
}

// ---- shared simplex math ----
__device__ __forceinline__ void pv_math(const float* feat, int g, int* code_out, float* bary_out){
  int p = g / NVERT, kk = g % NVERT;
  int b = p >> 10, n = p & 1023;
  const float* fb = feat + (size_t)b * DD * NPTS + n;
  float f0 = fb[0], f1 = fb[NPTS], f2 = fb[2 * NPTS], f3 = fb[3 * NPTS];

  float elev[5];
  elev[0] =  f0 * 2.886751345948129f  + f1 * 1.6666666666666667f + f2 * 1.1785113019775793f + f3 * 0.9128709291752769f;
  elev[1] = -f0 * 2.886751345948129f  + f1 * 1.6666666666666667f + f2 * 1.1785113019775793f + f3 * 0.9128709291752769f;
  elev[2] =  f1 * -3.3333333333333335f + f2 * 1.1785113019775793f + f3 * 0.9128709291752769f;
  elev[3] =  f2 * -3.535533905932738f  + f3 * 0.9128709291752769f;
  elev[4] =  f3 * -3.6514837167011076f;

  int gi[5]; float diff[5]; int sum = 0;
  #pragma unroll
  for (int i = 0; i < 5; i++){
    float gg = rintf(elev[i] * 0.2f) * 5.0f;
    gi[i] = (int)rintf(gg);
    sum += gi[i];
    diff[i] = elev[i] - gg;
  }
  int s = sum / 5;

  int rank[5];
  #pragma unroll
  for (int i = 0; i < 5; i++){
    int r = 0;
    #pragma unroll
    for (int j = 0; j < 5; j++)
      r += (diff[j] > diff[i]) || (diff[j] == diff[i] && j < i);
    rank[i] = r + s;
  }
  #pragma unroll
  for (int i = 0; i < 5; i++){
    if (rank[i] < 0)      { rank[i] += NVERT; gi[i] += NVERT; }
    else if (rank[i] > DD){ rank[i] -= NVERT; gi[i] -= NVERT; }
  }

  float bary[6] = {0.f,0.f,0.f,0.f,0.f,0.f};
  #pragma unroll
  for (int i = 0; i < 5; i++){
    float tt = (elev[i] - (float)gi[i]) * 0.2f;
    bary[DD - rank[i]]    += tt;
    bary[NVERT - rank[i]] += 1.0f - tt;
  }
  bary[0] += 1.0f + bary[5];

  float bk = bary[0];
  #pragma unroll
  for (int i = 1; i < 5; i++) if (i == kk) bk = bary[i];

  int code = 0;
  #pragma unroll
  for (int j = 0; j < DD; j++){
    int add = (rank[j] >= NVERT - kk) ? (kk - NVERT) : kk;
    int key = gi[j] + add;
    key = min(63, max(-64, key));
    code += (key + 64) << (7 * j);
  }
  *code_out = code;
  *bary_out = bk;
}

// ============ A: init + bpf + dat_t + pmath (disjoint block ranges) =======
__global__ void k_a(const float* __restrict__ wk, const float* __restrict__ data,
                    const float* __restrict__ feat,
                    int* __restrict__ hc, int* __restrict__ hu, int* __restrict__ uc,
                    float4* __restrict__ table4, unsigned short* __restrict__ bpf,
                    float* __restrict__ dat_t,
                    int* __restrict__ codes_pv, float* __restrict__ bary_pv){
  int bid = blockIdx.x, tid = threadIdx.x;
  if (bid < 64){
    __shared__ float tile[64][65];
    int b = bid >> 4, n0 = (bid & 15) * 64;
    int nl = tid & 63;
    #pragma unroll
    for (int i = 0; i < 16; i++){
      int c = (tid >> 6) * 16 + i;
      tile[c][nl] = data[(((size_t)b * 64 + c) << 10) + n0 + nl];
    }
    __syncthreads();
    #pragma unroll
    for (int i = 0; i < 16; i++){
      int nn = (tid >> 6) * 16 + i;
      dat_t[(((size_t)b << 10) + n0 + nn) * 64 + (tid & 63)] = tile[tid & 63][nn];
    }
  } else if (bid < 144){
    int g = (bid - 64) * 256 + tid;
    int code; float bk;
    pv_math(feat, g, &code, &bk);
    codes_pv[g] = code;
    bary_pv[g]  = bk;
  } else if (bid < 640){
    // weights -> fragment-ordered bpf
    int e = (bid - 144) * 256 + tid;
    int frag = e >> 9, l = (e >> 3) & 63, j = e & 7;
    int f = frag >> 3, h = (frag >> 2) & 1, g = frag & 3;
    int col = g * 16 + (l & 15);
    int c = h * 32 + ((l >> 4) << 3) + j;
    bpf[e] = f2bf(wk[(col * CIN + c) * NF + f]);
  } else {
    int g = (bid - 640) * 256 + tid;
    int stride = 384 * 256;
    for (int i = g; i < BATCH * CAP; i += stride){ hc[i] = SENTV; hu[i] = -1; }
    if (g < BATCH) uc[g] = 0;
    float4 z = {0.f,0.f,0.f,0.f};
    for (int i = g; i < BATCH * M0 * CIN / 4; i += stride) table4[i] = z;
  }
}

// ============ insert: LDS dedupe + global CAS + wave-aggregated uid =======
__global__ void k_insert(const int* __restrict__ codes_pv,
                         int* __restrict__ hash_code, int* __restrict__ hash_uid,
                         int* __restrict__ ucount, int* __restrict__ ukeys){
  __shared__ int lhash[512];
  int tid = threadIdx.x;
  lhash[tid] = SENTV; lhash[tid + 256] = SENTV;
  __syncthreads();

  int g = blockIdx.x * 256 + tid;
  int b = g / M0;
  int code = codes_pv[g];

  uint32_t lh = (((uint32_t)code * 2654435761u) >> 21) & 511;
  bool rep = false;
  while (true){
    int prev = atomicCAS(&lhash[lh], SENTV, code);
    if (prev == SENTV){ rep = true; break; }
    if (prev == code) break;
    lh = (lh + 1) & 511;
  }

  int myslot = -1;
  if (rep){
    int* hc = hash_code + b * CAP;
    uint32_t h = hslot(code);
    while (true){
      int prev = atomicCAS(&hc[h], SENTV, code);
      if (prev == SENTV){ myslot = (int)h; break; }
      if (prev == code) break;
      h = (h + 1) & CAPMASK;
    }
  }

  unsigned long long mask = __ballot(myslot >= 0);
  if (mask){
    int lane = tid & 63;
    int cnt = __popcll(mask);
    int leader = __ffsll((unsigned long long)mask) - 1;
    int base = 0;
    if (lane == leader) base = atomicAdd(&ucount[b], cnt);
    base = __shfl(base, leader);
    if (myslot >= 0){
      int rank = __popcll(mask & ((1ull << lane) - 1ull));
      int uid = base + rank;
      hash_uid[b * CAP + myslot] = uid;
      int* uk = ukeys + ((size_t)(b * M0 + uid)) * DD;
      #pragma unroll
      for (int j = 0; j < DD; j++) uk[j] = ((code >> (7 * j)) & 127) - 64;
    }
  }
}

// ============ fused: splat (blocks < 1024) + neighbor lookups (rest) ======
__global__ void k_sn(const float* __restrict__ dat_t, const int* __restrict__ codes_pv,
                     const float* __restrict__ bary_pv, const int* __restrict__ hash_code,
                     const int* __restrict__ hash_uid, const int* __restrict__ ucount,
                     const int* __restrict__ ukeys,
                     int* __restrict__ idx_pv, float* __restrict__ table,
                     int* __restrict__ nuid){
  int bid = blockIdx.x, tid = threadIdx.x;
  if (bid < BATCH * NPTS / 4){
    __shared__ int   us[4][8];
    __shared__ float wbs[4][8];
    int w = tid >> 6, lane = tid & 63;
    int p = bid * 4 + w;
    int b = p >> 10;
    float v = dat_t[((size_t)p << 6) + lane];
    if (lane < NVERT){
      int code = codes_pv[p * NVERT + lane];
      const int* hc = hash_code + b * CAP;
      uint32_t h = hslot(code);
      while (hc[h] != code) h = (h + 1) & CAPMASK;
      int uid = hash_uid[b * CAP + h];
      us[w][lane]  = uid;
      wbs[w][lane] = bary_pv[p * NVERT + lane];
      idx_pv[p * NVERT + lane] = uid;
    }
    __syncthreads();
    int rot = p % NVERT;
    #pragma unroll
    for (int kq = 0; kq < NVERT; kq++){
      int kk = kq + rot; if (kk >= NVERT) kk -= NVERT;
      atomicAdd(&table[(((size_t)(b * M0 + us[w][kk])) << 6) + lane], v * wbs[w][kk]);
    }
  } else {
    int e = (bid - BATCH * NPTS / 4) * 256 + tid;
    int f = e & 31;
    int idx = e >> 5;
    int b = idx / M0, m = idx - b * M0;
    int g = ZROW;
    if (f < NF && m < ucount[b]){
      const int* uk = ukeys + ((size_t)idx) * DD;
      int pc = __popc(f);
      int code = 0;
      #pragma unroll
      for (int j = 0; j < DD; j++){
        int key = uk[j] + 5 * ((f >> j) & 1) - pc;
        key = min(63, max(-64, key));
        code += (key + 64) << (7 * j);
      }
      const int* hc = hash_code + b * CAP;
      uint32_t h = hslot(code);
      while (true){
        int v = hc[h];
        if (v == code){ g = b * M0 + hash_uid[b * CAP + h]; break; }
        if (v == SENTV) break;
        h = (h + 1) & CAPMASK;
      }
    }
    nuid[e] = g;
  }
}

// ============ table fp32 -> bf16 (+ zero row) ==============================
__global__ void k_tobf(const float* __restrict__ table, unsigned short* __restrict__ table_bf){
  int g = blockIdx.x * blockDim.x + threadIdx.x;
  size_t base = (size_t)g * 8;
  const float4* s4 = (const float4*)(table + base);
  float4 x = s4[0], y = s4[1];
  bf16x8 v;
  v[0] = (short)f2bf(x.x); v[1] = (short)f2bf(x.y);
  v[2] = (short)f2bf(x.z); v[3] = (short)f2bf(x.w);
  v[4] = (short)f2bf(y.x); v[5] = (short)f2bf(y.y);
  v[6] = (short)f2bf(y.z); v[7] = (short)f2bf(y.w);
  *(bf16x8*)(table_bf + base) = v;
  if (g < 8){
    bf16x8 z = {0,0,0,0,0,0,0,0};
    *(bf16x8*)(table_bf + ((size_t)ZROW << 6) + g * 8) = z;
  }
}

// ============ conv: 8 waves (wm x wk4), full-width B, dedup'd A gathers ===
__launch_bounds__(512, 4)
__global__ void k_conv(const int* __restrict__ ucount, const int* __restrict__ nuid,
                       const unsigned short* __restrict__ table_bf,
                       const unsigned short* __restrict__ bpf,
                       float* __restrict__ out_lat){
  __shared__ int gidx_s[64 * 33];
  __shared__ float red[3][2][64][33];   // [wk-1][wm][lane][32 vals + pad]

  int blk = blockIdx.x;
  int b   = blk / (M0 / 64);
  int m0  = (blk % (M0 / 64)) * 64;
  if (m0 >= ucount[b]) return;

  int tid = threadIdx.x;
  {
    int base = (b * M0 + m0) << 5;
    #pragma unroll
    for (int i = 0; i < 4; i++){
      int idx = tid + i * 512;
      gidx_s[(idx >> 5) * 33 + (idx & 31)] = nuid[base + idx];
    }
  }
  __syncthreads();

  int lane = tid & 63, wave = tid >> 6;
  int wm = wave & 1, wk = wave >> 1;        // wk in 0..3
  int arow = wm * 32 + (lane & 15);
  int acol = (lane >> 4) * 8;
  const unsigned short* bf_lane = bpf + ((size_t)lane << 3);

  f32x4 acc0[4], acc1[4];
  #pragma unroll
  for (int g = 0; g < 4; g++){
    acc0[g] = (f32x4){0.f,0.f,0.f,0.f};
    acc1[g] = (f32x4){0.f,0.f,0.f,0.f};
  }

  const int kfs[5] = {0, 8, 16, 24, 31};
  int f0 = kfs[wk], f1 = kfs[wk + 1], flast = f1 - 1;

  // prefetch iteration f0: both rows x both 32-col halves (4 independent gathers)
  const unsigned short* r0p = table_bf + (((size_t)gidx_s[arow * 33 + f0]) << 6) + acol;
  const unsigned short* r1p = table_bf + (((size_t)gidx_s[(arow + 16) * 33 + f0]) << 6) + acol;
  bf16x8 A00 = *(const bf16x8*)(r0p);
  bf16x8 A01 = *(const bf16x8*)(r0p + 32);
  bf16x8 A10 = *(const bf16x8*)(r1p);
  bf16x8 A11 = *(const bf16x8*)(r1p + 32);

  #pragma unroll 2
  for (int f = f0; f < f1; f++){
    bf16x8 c00 = A00, c01 = A01, c10 = A10, c11 = A11;
    int fn = f + 1 > flast ? flast : f + 1;
    const unsigned short* n0p = table_bf + (((size_t)gidx_s[arow * 33 + fn]) << 6) + acol;
    const unsigned short* n1p = table_bf + (((size_t)gidx_s[(arow + 16) * 33 + fn]) << 6) + acol;
    A00 = *(const bf16x8*)(n0p);
    A01 = *(const bf16x8*)(n0p + 32);
    A10 = *(const bf16x8*)(n1p);
    A11 = *(const bf16x8*)(n1p + 32);

    int fr = f << 3;
    #pragma unroll
    for (int g = 0; g < 4; g++){
      bf16x8 B0 = *(const bf16x8*)(bf_lane + ((size_t)(fr + g)     << 9));  // h=0
      bf16x8 B1 = *(const bf16x8*)(bf_lane + ((size_t)(fr + 4 + g) << 9));  // h=1
      acc0[g] = __builtin_amdgcn_mfma_f32_16x16x32_bf16(c00, B0, acc0[g], 0, 0, 0);
      acc0[g] = __builtin_amdgcn_mfma_f32_16x16x32_bf16(c01, B1, acc0[g], 0, 0, 0);
      acc1[g] = __builtin_amdgcn_mfma_f32_16x16x32_bf16(c10, B0, acc1[g], 0, 0, 0);
      acc1[g] = __builtin_amdgcn_mfma_f32_16x16x32_bf16(c11, B1, acc1[g], 0, 0, 0);
    }
  }

  if (wk > 0){
    #pragma unroll
    for (int g = 0; g < 4; g++){
      #pragma unroll
      for (int q = 0; q < 4; q++){
        red[wk - 1][wm][lane][g * 4 + q]      = acc0[g][q];
        red[wk - 1][wm][lane][16 + g * 4 + q] = acc1[g][q];
      }
    }
  }
  __syncthreads();
  if (wk == 0){
    #pragma unroll
    for (int r = 0; r < 3; r++){
      #pragma unroll
      for (int g = 0; g < 4; g++){
        #pragma unroll
        for (int q = 0; q < 4; q++){
          acc0[g][q] += red[r][wm][lane][g * 4 + q];
          acc1[g][q] += red[r][wm][lane][16 + g * 4 + q];
        }
      }
    }
    // C/D layout: col = lane&15, row = (lane>>4)*4 + q (m89-verified)
    int q4 = (lane >> 4) * 4, col = lane & 15;
    #pragma unroll
    for (int i = 0; i < 2; i++){
      #pragma unroll
      for (int q = 0; q < 4; q++){
        int m = m0 + wm * 32 + i * 16 + q4 + q;
        float* orow = out_lat + (((size_t)(b * M0 + m)) << 6);
        #pragma unroll
        for (int g = 0; g < 4; g++){
          orow[g * 16 + col] = (i == 0) ? acc0[g][q] : acc1[g][q];
        }
      }
    }
  }
}

// ============ slice + bias + transpose to [b][o][n], 32-row tiles =========
__global__ void k_slice(const float* __restrict__ bary_pv, const int* __restrict__ idx_pv,
                        const float* __restrict__ out_lat, const float* __restrict__ bias,
                        const float* __restrict__ bmul, float* __restrict__ out){
  __shared__ float tile[32][65];
  int b = blockIdx.x >> 5, n0 = (blockIdx.x & 31) * 32;
  int tid = threadIdx.x;
  int wave = tid >> 6, o = tid & 63;
  float bo = bias[o];
  #pragma unroll
  for (int i = 0; i < 8; i++){
    int n = wave * 8 + i;
    int p = (b << 10) + n0 + n;
    float acc = bo * bmul[n0 + n];
    int base = p * NVERT;
    #pragma unroll
    for (int kk = 0; kk < NVERT; kk++){
      int u = idx_pv[base + kk];
      acc += bary_pv[base + kk] * out_lat[(((size_t)(b * M0 + u)) << 6) + o];
    }
    tile[n][o] = acc;
  }
  __syncthreads();
  int nl = tid & 31, ob = (tid >> 5) * 8;
  #pragma unroll
  for (int i = 0; i < 8; i++){
    int o2 = ob + i;
    out[(((size_t)b * 64 + o2) << 10) + n0 + nl] = tile[nl][o2];
  }
}

extern "C" void kernel_launch(void* const* d_in, const int* in_sizes, int n_in,
                              void* d_out, int out_size, void* d_ws, size_t ws_size,
                              hipStream_t stream){
  const float* data = (const float*)d_in[0];
  const float* feat = (const float*)d_in[1];
  const float* wk   = (const float*)d_in[2];
  const float* bias = (const float*)d_in[3];
  const float* bmul = (const float*)d_in[4];
  float* out = (float*)d_out;

  char* ws = (char*)d_ws;
  size_t off = 0;
  auto alloc = [&](size_t bytes){
    void* p = ws + off;
    off = (off + bytes + 255) & ~(size_t)255;
    return p;
  };
  int*   codes_pv = (int*)  alloc((size_t)BATCH * M0 * 4);
  float* bary_pv  = (float*)alloc((size_t)BATCH * M0 * 4);
  int*   idx_pv   = (int*)  alloc((size_t)BATCH * M0 * 4);
  int*   hash_code= (int*)  alloc((size_t)BATCH * CAP * 4);
  int*   hash_uid = (int*)  alloc((size_t)BATCH * CAP * 4);
  int*   ucount   = (int*)  alloc(256);
  int*   ukeys    = (int*)  alloc((size_t)BATCH * M0 * DD * 4);
  float* table    = (float*)alloc((size_t)BATCH * M0 * CIN * 4);
  float* out_lat  = (float*)alloc((size_t)BATCH * M0 * COUT * 4);
  unsigned short* bpf      = (unsigned short*)alloc((size_t)COUT * KTOT * 2);
  unsigned short* table_bf = (unsigned short*)alloc(((size_t)BATCH * M0 + 8) * CIN * 2);
  float* dat_t    = (float*)alloc((size_t)BATCH * NPTS * CIN * 4);
  int*   nuid     = (int*)  alloc((size_t)BATCH * M0 * 32 * 4);

  k_a     <<<1024, 256, 0, stream>>>(wk, data, feat, hash_code, hash_uid, ucount,
                                     (float4*)table, bpf, dat_t, codes_pv, bary_pv);
  k_insert<<<BATCH * M0 / 256, 256, 0, stream>>>(codes_pv, hash_code, hash_uid, ucount, ukeys);
  k_sn    <<<BATCH * NPTS / 4 + BATCH * M0 * 32 / 256, 256, 0, stream>>>(
            dat_t, codes_pv, bary_pv, hash_code, hash_uid, ucount, ukeys,
            idx_pv, table, nuid);
  k_tobf  <<<BATCH * M0 * CIN / 8 / 256, 256, 0, stream>>>(table, table_bf);
  k_conv  <<<BATCH * (M0 / 64), 512, 0, stream>>>(ucount, nuid, table_bf, bpf, out_lat);
  k_slice <<<BATCH * 32, 256, 0, stream>>>(bary_pv, idx_pv, out_lat, bias, bmul, out);
}

// Round 15
// 46.739 us; speedup vs baseline: 4.6550x; 1.0337x over previous
//
#include <hip/hip_runtime.h>
#include <hip/hip_bf16.h>
#include <stdint.h>

#define DD 4
#define NVERT 5
#define NPTS 1024
#define BATCH 4
#define M0 5120           /* NPTS*NVERT */
#define CIN 64
#define COUT 64
#define NF 31
#define KTOT 1984         /* NF*CIN */
#define CAP 16384
#define CAPMASK (CAP-1)
#define SENTV 1073741824  /* 2^30, > any valid code (<128^4) */
#define ZROW (BATCH*M0)   /* zero row index in table_bf */

using bf16x8 = __attribute__((ext_vector_type(8))) short;
using f32x4  = __attribute__((ext_vector_type(4))) float;

__device__ __forceinline__ unsigned short f2bf(float x){
  unsigned int u = __float_as_uint(x);
  u = (u + 0x7FFFu + ((u >> 16) & 1u)) >> 16;
  return (unsigned short)u;
}

__device__ __forceinline__ uint32_t hslot(int code){
  return (((uint32_t)code * 2654435761u) >> 18) & CAPMASK;
}

// ---- shared simplex math ----
__device__ __forceinline__ void pv_math(const float* feat, int g, int* code_out, float* bary_out){
  int p = g / NVERT, kk = g % NVERT;
  int b = p >> 10, n = p & 1023;
  const float* fb = feat + (size_t)b * DD * NPTS + n;
  float f0 = fb[0], f1 = fb[NPTS], f2 = fb[2 * NPTS], f3 = fb[3 * NPTS];

  float elev[5];
  elev[0] =  f0 * 2.886751345948129f  + f1 * 1.6666666666666667f + f2 * 1.1785113019775793f + f3 * 0.9128709291752769f;
  elev[1] = -f0 * 2.886751345948129f  + f1 * 1.6666666666666667f + f2 * 1.1785113019775793f + f3 * 0.9128709291752769f;
  elev[2] =  f1 * -3.3333333333333335f + f2 * 1.1785113019775793f + f3 * 0.9128709291752769f;
  elev[3] =  f2 * -3.535533905932738f  + f3 * 0.9128709291752769f;
  elev[4] =  f3 * -3.6514837167011076f;

  int gi[5]; float diff[5]; int sum = 0;
  #pragma unroll
  for (int i = 0; i < 5; i++){
    float gg = rintf(elev[i] * 0.2f) * 5.0f;
    gi[i] = (int)rintf(gg);
    sum += gi[i];
    diff[i] = elev[i] - gg;
  }
  int s = sum / 5;

  int rank[5];
  #pragma unroll
  for (int i = 0; i < 5; i++){
    int r = 0;
    #pragma unroll
    for (int j = 0; j < 5; j++)
      r += (diff[j] > diff[i]) || (diff[j] == diff[i] && j < i);
    rank[i] = r + s;
  }
  #pragma unroll
  for (int i = 0; i < 5; i++){
    if (rank[i] < 0)      { rank[i] += NVERT; gi[i] += NVERT; }
    else if (rank[i] > DD){ rank[i] -= NVERT; gi[i] -= NVERT; }
  }

  float bary[6] = {0.f,0.f,0.f,0.f,0.f,0.f};
  #pragma unroll
  for (int i = 0; i < 5; i++){
    float tt = (elev[i] - (float)gi[i]) * 0.2f;
    bary[DD - rank[i]]    += tt;
    bary[NVERT - rank[i]] += 1.0f - tt;
  }
  bary[0] += 1.0f + bary[5];

  float bk = bary[0];
  #pragma unroll
  for (int i = 1; i < 5; i++) if (i == kk) bk = bary[i];

  int code = 0;
  #pragma unroll
  for (int j = 0; j < DD; j++){
    int add = (rank[j] >= NVERT - kk) ? (kk - NVERT) : kk;
    int key = gi[j] + add;
    key = min(63, max(-64, key));
    code += (key + 64) << (7 * j);
  }
  *code_out = code;
  *bary_out = bk;
}

// ============ A: init + bpf + dat_t + pmath (disjoint block ranges) =======
__global__ void k_a(const float* __restrict__ wk, const float* __restrict__ data,
                    const float* __restrict__ feat,
                    int* __restrict__ hc, int* __restrict__ hu, int* __restrict__ uc,
                    float4* __restrict__ table4, float4* __restrict__ outlat4,
                    unsigned short* __restrict__ bpf, float* __restrict__ dat_t,
                    int* __restrict__ codes_pv, float* __restrict__ bary_pv){
  int bid = blockIdx.x, tid = threadIdx.x;
  if (bid < 64){
    __shared__ float tile[64][65];
    int b = bid >> 4, n0 = (bid & 15) * 64;
    int nl = tid & 63;
    #pragma unroll
    for (int i = 0; i < 16; i++){
      int c = (tid >> 6) * 16 + i;
      tile[c][nl] = data[(((size_t)b * 64 + c) << 10) + n0 + nl];
    }
    __syncthreads();
    #pragma unroll
    for (int i = 0; i < 16; i++){
      int nn = (tid >> 6) * 16 + i;
      dat_t[(((size_t)b << 10) + n0 + nn) * 64 + (tid & 63)] = tile[tid & 63][nn];
    }
  } else if (bid < 144){
    int g = (bid - 64) * 256 + tid;
    int code; float bk;
    pv_math(feat, g, &code, &bk);
    codes_pv[g] = code;
    bary_pv[g]  = bk;
  } else if (bid < 640){
    // weights -> fragment-ordered bpf
    int e = (bid - 144) * 256 + tid;
    int frag = e >> 9, l = (e >> 3) & 63, j = e & 7;
    int f = frag >> 3, h = (frag >> 2) & 1, g = frag & 3;
    int col = g * 16 + (l & 15);
    int c = h * 32 + ((l >> 4) << 3) + j;
    bpf[e] = f2bf(wk[(col * CIN + c) * NF + f]);
  } else {
    int g = (bid - 640) * 256 + tid;
    int stride = 384 * 256;
    for (int i = g; i < BATCH * CAP; i += stride){ hc[i] = SENTV; hu[i] = -1; }
    if (g < BATCH) uc[g] = 0;
    float4 z = {0.f,0.f,0.f,0.f};
    for (int i = g; i < BATCH * M0 * CIN / 4; i += stride) table4[i] = z;
    for (int i = g; i < BATCH * M0 * COUT / 4; i += stride) outlat4[i] = z;
  }
}

// ============ insert: LDS dedupe + global CAS + wave-aggregated uid =======
__global__ void k_insert(const int* __restrict__ codes_pv,
                         int* __restrict__ hash_code, int* __restrict__ hash_uid,
                         int* __restrict__ ucount, int* __restrict__ ukeys){
  __shared__ int lhash[512];
  int tid = threadIdx.x;
  lhash[tid] = SENTV; lhash[tid + 256] = SENTV;
  __syncthreads();

  int g = blockIdx.x * 256 + tid;
  int b = g / M0;
  int code = codes_pv[g];

  uint32_t lh = (((uint32_t)code * 2654435761u) >> 21) & 511;
  bool rep = false;
  while (true){
    int prev = atomicCAS(&lhash[lh], SENTV, code);
    if (prev == SENTV){ rep = true; break; }
    if (prev == code) break;
    lh = (lh + 1) & 511;
  }

  int myslot = -1;
  if (rep){
    int* hc = hash_code + b * CAP;
    uint32_t h = hslot(code);
    while (true){
      int prev = atomicCAS(&hc[h], SENTV, code);
      if (prev == SENTV){ myslot = (int)h; break; }
      if (prev == code) break;
      h = (h + 1) & CAPMASK;
    }
  }

  unsigned long long mask = __ballot(myslot >= 0);
  if (mask){
    int lane = tid & 63;
    int cnt = __popcll(mask);
    int leader = __ffsll((unsigned long long)mask) - 1;
    int base = 0;
    if (lane == leader) base = atomicAdd(&ucount[b], cnt);
    base = __shfl(base, leader);
    if (myslot >= 0){
      int rank = __popcll(mask & ((1ull << lane) - 1ull));
      int uid = base + rank;
      hash_uid[b * CAP + myslot] = uid;
      int* uk = ukeys + ((size_t)(b * M0 + uid)) * DD;
      #pragma unroll
      for (int j = 0; j < DD; j++) uk[j] = ((code >> (7 * j)) & 127) - 64;
    }
  }
}

// ============ fused: splat (blocks < 1024) + neighbor lookups (rest) ======
__global__ void k_sn(const float* __restrict__ dat_t, const int* __restrict__ codes_pv,
                     const float* __restrict__ bary_pv, const int* __restrict__ hash_code,
                     const int* __restrict__ hash_uid, const int* __restrict__ ucount,
                     const int* __restrict__ ukeys,
                     int* __restrict__ idx_pv, float* __restrict__ table,
                     int* __restrict__ nuid){
  int bid = blockIdx.x, tid = threadIdx.x;
  if (bid < BATCH * NPTS / 4){
    __shared__ int   us[4][8];
    __shared__ float wbs[4][8];
    int w = tid >> 6, lane = tid & 63;
    int p = bid * 4 + w;
    int b = p >> 10;
    float v = dat_t[((size_t)p << 6) + lane];
    if (lane < NVERT){
      int code = codes_pv[p * NVERT + lane];
      const int* hc = hash_code + b * CAP;
      uint32_t h = hslot(code);
      while (hc[h] != code) h = (h + 1) & CAPMASK;
      int uid = hash_uid[b * CAP + h];
      us[w][lane]  = uid;
      wbs[w][lane] = bary_pv[p * NVERT + lane];
      idx_pv[p * NVERT + lane] = uid;
    }
    __syncthreads();
    int rot = p % NVERT;
    #pragma unroll
    for (int kq = 0; kq < NVERT; kq++){
      int kk = kq + rot; if (kk >= NVERT) kk -= NVERT;
      atomicAdd(&table[(((size_t)(b * M0 + us[w][kk])) << 6) + lane], v * wbs[w][kk]);
    }
  } else {
    int e = (bid - BATCH * NPTS / 4) * 256 + tid;
    int f = e & 31;
    int idx = e >> 5;
    int b = idx / M0, m = idx - b * M0;
    int g = ZROW;
    if (f < NF && m < ucount[b]){
      const int* uk = ukeys + ((size_t)idx) * DD;
      int pc = __popc(f);
      int code = 0;
      #pragma unroll
      for (int j = 0; j < DD; j++){
        int key = uk[j] + 5 * ((f >> j) & 1) - pc;
        key = min(63, max(-64, key));
        code += (key + 64) << (7 * j);
      }
      const int* hc = hash_code + b * CAP;
      uint32_t h = hslot(code);
      while (true){
        int v = hc[h];
        if (v == code){ g = b * M0 + hash_uid[b * CAP + h]; break; }
        if (v == SENTV) break;
        h = (h + 1) & CAPMASK;
      }
    }
    nuid[e] = g;
  }
}

// ============ table fp32 -> bf16 (+ zero row) ==============================
__global__ void k_tobf(const float* __restrict__ table, unsigned short* __restrict__ table_bf){
  int g = blockIdx.x * blockDim.x + threadIdx.x;
  size_t base = (size_t)g * 8;
  const float4* s4 = (const float4*)(table + base);
  float4 x = s4[0], y = s4[1];
  bf16x8 v;
  v[0] = (short)f2bf(x.x); v[1] = (short)f2bf(x.y);
  v[2] = (short)f2bf(x.z); v[3] = (short)f2bf(x.w);
  v[4] = (short)f2bf(y.x); v[5] = (short)f2bf(y.y);
  v[6] = (short)f2bf(y.z); v[7] = (short)f2bf(y.w);
  *(bf16x8*)(table_bf + base) = v;
  if (g < 8){
    bf16x8 z = {0,0,0,0,0,0,0,0};
    *(bf16x8*)(table_bf + ((size_t)ZROW << 6) + g * 8) = z;
  }
}

// ============ conv: 640 blocks (64-row tile x f-half), atomic epilogue ====
__launch_bounds__(512, 4)
__global__ void k_conv(const int* __restrict__ ucount, const int* __restrict__ nuid,
                       const unsigned short* __restrict__ table_bf,
                       const unsigned short* __restrict__ bpf,
                       float* __restrict__ out_lat){
  __shared__ int gidx_s[64 * 33];

  int blk = blockIdx.x;
  int b    = blk / 160;          // 160 = 80 tiles * 2 halves
  int r    = blk % 160;
  int m0   = (r >> 1) * 64;
  int half = r & 1;
  if (m0 >= ucount[b]) return;

  int tid = threadIdx.x;
  {
    int base = (b * M0 + m0) << 5;
    #pragma unroll
    for (int i = 0; i < 4; i++){
      int idx = tid + i * 512;
      gidx_s[(idx >> 5) * 33 + (idx & 31)] = nuid[base + idx];
    }
  }
  __syncthreads();

  int lane = tid & 63, wave = tid >> 6;
  int wm = wave & 1, wk = wave >> 1;        // wk in 0..3
  int arow = wm * 32 + (lane & 15);
  int acol = (lane >> 4) * 8;
  const unsigned short* bf_lane = bpf + ((size_t)lane << 3);

  f32x4 acc0[4], acc1[4];
  #pragma unroll
  for (int g = 0; g < 4; g++){
    acc0[g] = (f32x4){0.f,0.f,0.f,0.f};
    acc1[g] = (f32x4){0.f,0.f,0.f,0.f};
  }

  const int kfsA[2][5] = {{0,4,8,12,16},{16,20,24,28,31}};
  int f0 = kfsA[half][wk], f1 = kfsA[half][wk + 1], flast = f1 - 1;

  // prefetch iteration f0: both rows x both 32-col halves (4 independent gathers)
  const unsigned short* r0p = table_bf + (((size_t)gidx_s[arow * 33 + f0]) << 6) + acol;
  const unsigned short* r1p = table_bf + (((size_t)gidx_s[(arow + 16) * 33 + f0]) << 6) + acol;
  bf16x8 A00 = *(const bf16x8*)(r0p);
  bf16x8 A01 = *(const bf16x8*)(r0p + 32);
  bf16x8 A10 = *(const bf16x8*)(r1p);
  bf16x8 A11 = *(const bf16x8*)(r1p + 32);

  #pragma unroll 2
  for (int f = f0; f < f1; f++){
    bf16x8 c00 = A00, c01 = A01, c10 = A10, c11 = A11;
    int fn = f + 1 > flast ? flast : f + 1;
    const unsigned short* n0p = table_bf + (((size_t)gidx_s[arow * 33 + fn]) << 6) + acol;
    const unsigned short* n1p = table_bf + (((size_t)gidx_s[(arow + 16) * 33 + fn]) << 6) + acol;
    A00 = *(const bf16x8*)(n0p);
    A01 = *(const bf16x8*)(n0p + 32);
    A10 = *(const bf16x8*)(n1p);
    A11 = *(const bf16x8*)(n1p + 32);

    int fr = f << 3;
    #pragma unroll
    for (int g = 0; g < 4; g++){
      bf16x8 B0 = *(const bf16x8*)(bf_lane + ((size_t)(fr + g)     << 9));  // h=0
      bf16x8 B1 = *(const bf16x8*)(bf_lane + ((size_t)(fr + 4 + g) << 9));  // h=1
      acc0[g] = __builtin_amdgcn_mfma_f32_16x16x32_bf16(c00, B0, acc0[g], 0, 0, 0);
      acc0[g] = __builtin_amdgcn_mfma_f32_16x16x32_bf16(c01, B1, acc0[g], 0, 0, 0);
      acc1[g] = __builtin_amdgcn_mfma_f32_16x16x32_bf16(c10, B0, acc1[g], 0, 0, 0);
      acc1[g] = __builtin_amdgcn_mfma_f32_16x16x32_bf16(c11, B1, acc1[g], 0, 0, 0);
    }
  }

  // atomic epilogue: every wave adds its partial (out_lat pre-zeroed in k_a)
  // C/D layout: col = lane&15, row = (lane>>4)*4 + q (m89-verified)
  int q4 = (lane >> 4) * 4, col = lane & 15;
  #pragma unroll
  for (int i = 0; i < 2; i++){
    #pragma unroll
    for (int q = 0; q < 4; q++){
      int m = m0 + wm * 32 + i * 16 + q4 + q;
      float* orow = out_lat + (((size_t)(b * M0 + m)) << 6);
      #pragma unroll
      for (int g = 0; g < 4; g++){
        atomicAdd(&orow[g * 16 + col], (i == 0) ? acc0[g][q] : acc1[g][q]);
      }
    }
  }
}

// ============ slice + bias + transpose to [b][o][n], 16-row tiles =========
__global__ void k_slice(const float* __restrict__ bary_pv, const int* __restrict__ idx_pv,
                        const float* __restrict__ out_lat, const float* __restrict__ bias,
                        const float* __restrict__ bmul, float* __restrict__ out){
  __shared__ float tile[16][65];
  int b = blockIdx.x >> 6, n0 = (blockIdx.x & 63) * 16;
  int tid = threadIdx.x;
  int wave = tid >> 6, o = tid & 63;
  float bo = bias[o];
  #pragma unroll
  for (int i = 0; i < 4; i++){
    int n = wave * 4 + i;
    int p = (b << 10) + n0 + n;
    float acc = bo * bmul[n0 + n];
    int base = p * NVERT;
    #pragma unroll
    for (int kk = 0; kk < NVERT; kk++){
      int u = idx_pv[base + kk];
      acc += bary_pv[base + kk] * out_lat[(((size_t)(b * M0 + u)) << 6) + o];
    }
    tile[n][o] = acc;
  }
  __syncthreads();
  int nl = tid & 15;
  #pragma unroll
  for (int i = 0; i < 4; i++){
    int o2 = (tid >> 4) + i * 16;
    out[(((size_t)b * 64 + o2) << 10) + n0 + nl] = tile[nl][o2];
  }
}

extern "C" void kernel_launch(void* const* d_in, const int* in_sizes, int n_in,
                              void* d_out, int out_size, void* d_ws, size_t ws_size,
                              hipStream_t stream){
  const float* data = (const float*)d_in[0];
  const float* feat = (const float*)d_in[1];
  const float* wk   = (const float*)d_in[2];
  const float* bias = (const float*)d_in[3];
  const float* bmul = (const float*)d_in[4];
  float* out = (float*)d_out;

  char* ws = (char*)d_ws;
  size_t off = 0;
  auto alloc = [&](size_t bytes){
    void* p = ws + off;
    off = (off + bytes + 255) & ~(size_t)255;
    return p;
  };
  int*   codes_pv = (int*)  alloc((size_t)BATCH * M0 * 4);
  float* bary_pv  = (float*)alloc((size_t)BATCH * M0 * 4);
  int*   idx_pv   = (int*)  alloc((size_t)BATCH * M0 * 4);
  int*   hash_code= (int*)  alloc((size_t)BATCH * CAP * 4);
  int*   hash_uid = (int*)  alloc((size_t)BATCH * CAP * 4);
  int*   ucount   = (int*)  alloc(256);
  int*   ukeys    = (int*)  alloc((size_t)BATCH * M0 * DD * 4);
  float* table    = (float*)alloc((size_t)BATCH * M0 * CIN * 4);
  float* out_lat  = (float*)alloc((size_t)BATCH * M0 * COUT * 4);
  unsigned short* bpf      = (unsigned short*)alloc((size_t)COUT * KTOT * 2);
  unsigned short* table_bf = (unsigned short*)alloc(((size_t)BATCH * M0 + 8) * CIN * 2);
  float* dat_t    = (float*)alloc((size_t)BATCH * NPTS * CIN * 4);
  int*   nuid     = (int*)  alloc((size_t)BATCH * M0 * 32 * 4);

  k_a     <<<1024, 256, 0, stream>>>(wk, data, feat, hash_code, hash_uid, ucount,
                                     (float4*)table, (float4*)out_lat, bpf, dat_t,
                                     codes_pv, bary_pv);
  k_insert<<<BATCH * M0 / 256, 256, 0, stream>>>(codes_pv, hash_code, hash_uid, ucount, ukeys);
  k_sn    <<<BATCH * NPTS / 4 + BATCH * M0 * 32 / 256, 256, 0, stream>>>(
            dat_t, codes_pv, bary_pv, hash_code, hash_uid, ucount, ukeys,
            idx_pv, table, nuid);
  k_tobf  <<<BATCH * M0 * CIN / 8 / 256, 256, 0, stream>>>(table, table_bf);
  k_conv  <<<BATCH * 160, 512, 0, stream>>>(ucount, nuid, table_bf, bpf, out_lat);
  k_slice <<<BATCH * 64, 256, 0, stream>>>(bary_pv, idx_pv, out_lat, bias, bmul, out);
}

// Round 16
// 43.036 us; speedup vs baseline: 5.0554x; 1.0860x over previous
//
#include <hip/hip_runtime.h>
#include <hip/hip_bf16.h>
#include <stdint.h>

#define DD 4
#define NVERT 5
#define NPTS 1024
#define BATCH 4
#define M0 5120           /* NPTS*NVERT */
#define CIN 64
#define COUT 64
#define NF 31
#define KTOT 1984         /* NF*CIN */
#define CAP 16384
#define CAPMASK (CAP-1)
#define SENTV 1073741824  /* 2^30, > any valid code (<128^4) */
#define ZROW (BATCH*M0)   /* zero row index in table_bf */

using bf16x8 = __attribute__((ext_vector_type(8))) short;
using f32x4  = __attribute__((ext_vector_type(4))) float;

__device__ __forceinline__ unsigned short f2bf(float x){
  unsigned int u = __float_as_uint(x);
  u = (u + 0x7FFFu + ((u >> 16) & 1u)) >> 16;
  return (unsigned short)u;
}

__device__ __forceinline__ uint32_t hslot(int code){
  return (((uint32_t)code * 2654435761u) >> 18) & CAPMASK;
}

// ---- shared simplex math ----
__device__ __forceinline__ void pv_math(const float* feat, int g, int* code_out, float* bary_out){
  int p = g / NVERT, kk = g % NVERT;
  int b = p >> 10, n = p & 1023;
  const float* fb = feat + (size_t)b * DD * NPTS + n;
  float f0 = fb[0], f1 = fb[NPTS], f2 = fb[2 * NPTS], f3 = fb[3 * NPTS];

  float elev[5];
  elev[0] =  f0 * 2.886751345948129f  + f1 * 1.6666666666666667f + f2 * 1.1785113019775793f + f3 * 0.9128709291752769f;
  elev[1] = -f0 * 2.886751345948129f  + f1 * 1.6666666666666667f + f2 * 1.1785113019775793f + f3 * 0.9128709291752769f;
  elev[2] =  f1 * -3.3333333333333335f + f2 * 1.1785113019775793f + f3 * 0.9128709291752769f;
  elev[3] =  f2 * -3.535533905932738f  + f3 * 0.9128709291752769f;
  elev[4] =  f3 * -3.6514837167011076f;

  int gi[5]; float diff[5]; int sum = 0;
  #pragma unroll
  for (int i = 0; i < 5; i++){
    float gg = rintf(elev[i] * 0.2f) * 5.0f;
    gi[i] = (int)rintf(gg);
    sum += gi[i];
    diff[i] = elev[i] - gg;
  }
  int s = sum / 5;

  int rank[5];
  #pragma unroll
  for (int i = 0; i < 5; i++){
    int r = 0;
    #pragma unroll
    for (int j = 0; j < 5; j++)
      r += (diff[j] > diff[i]) || (diff[j] == diff[i] && j < i);
    rank[i] = r + s;
  }
  #pragma unroll
  for (int i = 0; i < 5; i++){
    if (rank[i] < 0)      { rank[i] += NVERT; gi[i] += NVERT; }
    else if (rank[i] > DD){ rank[i] -= NVERT; gi[i] -= NVERT; }
  }

  float bary[6] = {0.f,0.f,0.f,0.f,0.f,0.f};
  #pragma unroll
  for (int i = 0; i < 5; i++){
    float tt = (elev[i] - (float)gi[i]) * 0.2f;
    bary[DD - rank[i]]    += tt;
    bary[NVERT - rank[i]] += 1.0f - tt;
  }
  bary[0] += 1.0f + bary[5];

  float bk = bary[0];
  #pragma unroll
  for (int i = 1; i < 5; i++) if (i == kk) bk = bary[i];

  int code = 0;
  #pragma unroll
  for (int j = 0; j < DD; j++){
    int add = (rank[j] >= NVERT - kk) ? (kk - NVERT) : kk;
    int key = gi[j] + add;
    key = min(63, max(-64, key));
    code += (key + 64) << (7 * j);
  }
  *code_out = code;
  *bary_out = bk;
}

// ============ A: init + bpf + dat_t + pmath (disjoint block ranges) =======
__global__ void k_a(const float* __restrict__ wk, const float* __restrict__ data,
                    const float* __restrict__ feat,
                    int* __restrict__ hc, int* __restrict__ hu, int* __restrict__ uc,
                    float4* __restrict__ table4, float4* __restrict__ outlat4,
                    unsigned short* __restrict__ bpf, float* __restrict__ dat_t,
                    int* __restrict__ codes_pv, float* __restrict__ bary_pv){
  int bid = blockIdx.x, tid = threadIdx.x;
  if (bid < 64){
    __shared__ float tile[64][65];
    int b = bid >> 4, n0 = (bid & 15) * 64;
    int nl = tid & 63;
    #pragma unroll
    for (int i = 0; i < 16; i++){
      int c = (tid >> 6) * 16 + i;
      tile[c][nl] = data[(((size_t)b * 64 + c) << 10) + n0 + nl];
    }
    __syncthreads();
    #pragma unroll
    for (int i = 0; i < 16; i++){
      int nn = (tid >> 6) * 16 + i;
      dat_t[(((size_t)b << 10) + n0 + nn) * 64 + (tid & 63)] = tile[tid & 63][nn];
    }
  } else if (bid < 144){
    int g = (bid - 64) * 256 + tid;
    int code; float bk;
    pv_math(feat, g, &code, &bk);
    codes_pv[g] = code;
    bary_pv[g]  = bk;
  } else if (bid < 640){
    // weights -> fragment-ordered bpf
    int e = (bid - 144) * 256 + tid;
    int frag = e >> 9, l = (e >> 3) & 63, j = e & 7;
    int f = frag >> 3, h = (frag >> 2) & 1, g = frag & 3;
    int col = g * 16 + (l & 15);
    int c = h * 32 + ((l >> 4) << 3) + j;
    bpf[e] = f2bf(wk[(col * CIN + c) * NF + f]);
  } else {
    int g = (bid - 640) * 256 + tid;
    int stride = 384 * 256;
    for (int i = g; i < BATCH * CAP; i += stride){ hc[i] = SENTV; hu[i] = -1; }
    if (g < BATCH) uc[g] = 0;
    float4 z = {0.f,0.f,0.f,0.f};
    for (int i = g; i < BATCH * M0 * CIN / 4; i += stride) table4[i] = z;
    for (int i = g; i < BATCH * M0 * COUT / 4; i += stride) outlat4[i] = z;
  }
}

// ============ insert: LDS dedupe + global CAS + wave-aggregated uid =======
__global__ void k_insert(const int* __restrict__ codes_pv,
                         int* __restrict__ hash_code, int* __restrict__ hash_uid,
                         int* __restrict__ ucount, int* __restrict__ ukeys){
  __shared__ int lhash[512];
  int tid = threadIdx.x;
  lhash[tid] = SENTV; lhash[tid + 256] = SENTV;
  __syncthreads();

  int g = blockIdx.x * 256 + tid;
  int b = g / M0;
  int code = codes_pv[g];

  uint32_t lh = (((uint32_t)code * 2654435761u) >> 21) & 511;
  bool rep = false;
  while (true){
    int prev = atomicCAS(&lhash[lh], SENTV, code);
    if (prev == SENTV){ rep = true; break; }
    if (prev == code) break;
    lh = (lh + 1) & 511;
  }

  int myslot = -1;
  if (rep){
    int* hc = hash_code + b * CAP;
    uint32_t h = hslot(code);
    while (true){
      int prev = atomicCAS(&hc[h], SENTV, code);
      if (prev == SENTV){ myslot = (int)h; break; }
      if (prev == code) break;
      h = (h + 1) & CAPMASK;
    }
  }

  unsigned long long mask = __ballot(myslot >= 0);
  if (mask){
    int lane = tid & 63;
    int cnt = __popcll(mask);
    int leader = __ffsll((unsigned long long)mask) - 1;
    int base = 0;
    if (lane == leader) base = atomicAdd(&ucount[b], cnt);
    base = __shfl(base, leader);
    if (myslot >= 0){
      int rank = __popcll(mask & ((1ull << lane) - 1ull));
      int uid = base + rank;
      hash_uid[b * CAP + myslot] = uid;
      int* uk = ukeys + ((size_t)(b * M0 + uid)) * DD;
      #pragma unroll
      for (int j = 0; j < DD; j++) uk[j] = ((code >> (7 * j)) & 127) - 64;
    }
  }
}

// ============ fused: splat (blocks < 1024) + neighbor lookups (rest) ======
__global__ void k_sn(const float* __restrict__ dat_t, const int* __restrict__ codes_pv,
                     const float* __restrict__ bary_pv, const int* __restrict__ hash_code,
                     const int* __restrict__ hash_uid, const int* __restrict__ ucount,
                     const int* __restrict__ ukeys,
                     int* __restrict__ idx_pv, float* __restrict__ table,
                     int* __restrict__ nuid){
  int bid = blockIdx.x, tid = threadIdx.x;
  if (bid < BATCH * NPTS / 4){
    __shared__ int   us[4][8];
    __shared__ float wbs[4][8];
    int w = tid >> 6, lane = tid & 63;
    int p = bid * 4 + w;
    int b = p >> 10;
    float v = dat_t[((size_t)p << 6) + lane];
    if (lane < NVERT){
      int code = codes_pv[p * NVERT + lane];
      const int* hc = hash_code + b * CAP;
      uint32_t h = hslot(code);
      while (hc[h] != code) h = (h + 1) & CAPMASK;
      int uid = hash_uid[b * CAP + h];
      us[w][lane]  = uid;
      wbs[w][lane] = bary_pv[p * NVERT + lane];
      idx_pv[p * NVERT + lane] = uid;
    }
    __syncthreads();
    int rot = p % NVERT;
    #pragma unroll
    for (int kq = 0; kq < NVERT; kq++){
      int kk = kq + rot; if (kk >= NVERT) kk -= NVERT;
      atomicAdd(&table[(((size_t)(b * M0 + us[w][kk])) << 6) + lane], v * wbs[w][kk]);
    }
  } else {
    int e = (bid - BATCH * NPTS / 4) * 256 + tid;
    int f = e & 31;
    int idx = e >> 5;
    int b = idx / M0, m = idx - b * M0;
    int g = ZROW;
    if (f < NF && m < ucount[b]){
      const int* uk = ukeys + ((size_t)idx) * DD;
      int pc = __popc(f);
      int code = 0;
      #pragma unroll
      for (int j = 0; j < DD; j++){
        int key = uk[j] + 5 * ((f >> j) & 1) - pc;
        key = min(63, max(-64, key));
        code += (key + 64) << (7 * j);
      }
      const int* hc = hash_code + b * CAP;
      uint32_t h = hslot(code);
      while (true){
        int v = hc[h];
        if (v == code){ g = b * M0 + hash_uid[b * CAP + h]; break; }
        if (v == SENTV) break;
        h = (h + 1) & CAPMASK;
      }
    }
    nuid[e] = g;
  }
}

// ============ table fp32 -> bf16 (+ zero row), skip unused rows ===========
__global__ void k_tobf(const float* __restrict__ table, const int* __restrict__ ucount,
                       unsigned short* __restrict__ table_bf){
  int g = blockIdx.x * blockDim.x + threadIdx.x;
  if (g < 8){
    bf16x8 z = {0,0,0,0,0,0,0,0};
    *(bf16x8*)(table_bf + ((size_t)ZROW << 6) + g * 8) = z;
  }
  int row = g >> 3;
  int b = row / M0;
  if (row - b * M0 >= ucount[b]) return;   // unused rows never read by conv
  size_t base = (size_t)g * 8;
  const float4* s4 = (const float4*)(table + base);
  float4 x = s4[0], y = s4[1];
  bf16x8 v;
  v[0] = (short)f2bf(x.x); v[1] = (short)f2bf(x.y);
  v[2] = (short)f2bf(x.z); v[3] = (short)f2bf(x.w);
  v[4] = (short)f2bf(y.x); v[5] = (short)f2bf(y.y);
  v[6] = (short)f2bf(y.z); v[7] = (short)f2bf(y.w);
  *(bf16x8*)(table_bf + base) = v;
}

// ============ conv: 640 blocks, slim chunked LDS reduce, wk0-only atomics =
__launch_bounds__(512, 4)
__global__ void k_conv(const int* __restrict__ ucount, const int* __restrict__ nuid,
                       const unsigned short* __restrict__ table_bf,
                       const unsigned short* __restrict__ bpf,
                       float* __restrict__ out_lat){
  __shared__ int gidx_s[64 * 33];
  __shared__ float red[3][2][64][9];   // per-g chunk: [wk-1][wm][lane][8 vals + pad]

  int blk = blockIdx.x;
  int b    = blk / 160;          // 160 = 80 tiles * 2 halves
  int r    = blk % 160;
  int m0   = (r >> 1) * 64;
  int half = r & 1;
  if (m0 >= ucount[b]) return;

  int tid = threadIdx.x;
  {
    int base = (b * M0 + m0) << 5;
    #pragma unroll
    for (int i = 0; i < 4; i++){
      int idx = tid + i * 512;
      gidx_s[(idx >> 5) * 33 + (idx & 31)] = nuid[base + idx];
    }
  }
  __syncthreads();

  int lane = tid & 63, wave = tid >> 6;
  int wm = wave & 1, wk = wave >> 1;        // wk in 0..3
  int arow = wm * 32 + (lane & 15);
  int acol = (lane >> 4) * 8;
  const unsigned short* bf_lane = bpf + ((size_t)lane << 3);

  f32x4 acc0[4], acc1[4];
  #pragma unroll
  for (int g = 0; g < 4; g++){
    acc0[g] = (f32x4){0.f,0.f,0.f,0.f};
    acc1[g] = (f32x4){0.f,0.f,0.f,0.f};
  }

  const int kfsA[2][5] = {{0,4,8,12,16},{16,20,24,28,31}};
  int f0 = kfsA[half][wk], f1 = kfsA[half][wk + 1], flast = f1 - 1;

  // prefetch iteration f0: both rows x both 32-col halves (4 independent gathers)
  const unsigned short* r0p = table_bf + (((size_t)gidx_s[arow * 33 + f0]) << 6) + acol;
  const unsigned short* r1p = table_bf + (((size_t)gidx_s[(arow + 16) * 33 + f0]) << 6) + acol;
  bf16x8 A00 = *(const bf16x8*)(r0p);
  bf16x8 A01 = *(const bf16x8*)(r0p + 32);
  bf16x8 A10 = *(const bf16x8*)(r1p);
  bf16x8 A11 = *(const bf16x8*)(r1p + 32);

  #pragma unroll 2
  for (int f = f0; f < f1; f++){
    bf16x8 c00 = A00, c01 = A01, c10 = A10, c11 = A11;
    int fn = f + 1 > flast ? flast : f + 1;
    const unsigned short* n0p = table_bf + (((size_t)gidx_s[arow * 33 + fn]) << 6) + acol;
    const unsigned short* n1p = table_bf + (((size_t)gidx_s[(arow + 16) * 33 + fn]) << 6) + acol;
    A00 = *(const bf16x8*)(n0p);
    A01 = *(const bf16x8*)(n0p + 32);
    A10 = *(const bf16x8*)(n1p);
    A11 = *(const bf16x8*)(n1p + 32);

    int fr = f << 3;
    #pragma unroll
    for (int g = 0; g < 4; g++){
      bf16x8 B0 = *(const bf16x8*)(bf_lane + ((size_t)(fr + g)     << 9));  // h=0
      bf16x8 B1 = *(const bf16x8*)(bf_lane + ((size_t)(fr + 4 + g) << 9));  // h=1
      acc0[g] = __builtin_amdgcn_mfma_f32_16x16x32_bf16(c00, B0, acc0[g], 0, 0, 0);
      acc0[g] = __builtin_amdgcn_mfma_f32_16x16x32_bf16(c01, B1, acc0[g], 0, 0, 0);
      acc1[g] = __builtin_amdgcn_mfma_f32_16x16x32_bf16(c10, B0, acc1[g], 0, 0, 0);
      acc1[g] = __builtin_amdgcn_mfma_f32_16x16x32_bf16(c11, B1, acc1[g], 0, 0, 0);
    }
  }

  // chunked LDS reduction across wk (one g at a time, slim buffer)
  #pragma unroll
  for (int g = 0; g < 4; g++){
    if (wk > 0){
      #pragma unroll
      for (int q = 0; q < 4; q++){
        red[wk - 1][wm][lane][q]     = acc0[g][q];
        red[wk - 1][wm][lane][4 + q] = acc1[g][q];
      }
    }
    __syncthreads();
    if (wk == 0){
      #pragma unroll
      for (int rr = 0; rr < 3; rr++){
        #pragma unroll
        for (int q = 0; q < 4; q++){
          acc0[g][q] += red[rr][wm][lane][q];
          acc1[g][q] += red[rr][wm][lane][4 + q];
        }
      }
    }
    __syncthreads();
  }

  // wk0-only atomic epilogue: one add per output per half-block
  // C/D layout: col = lane&15, row = (lane>>4)*4 + q (m89-verified)
  if (wk == 0){
    int q4 = (lane >> 4) * 4, col = lane & 15;
    #pragma unroll
    for (int i = 0; i < 2; i++){
      #pragma unroll
      for (int q = 0; q < 4; q++){
        int m = m0 + wm * 32 + i * 16 + q4 + q;
        float* orow = out_lat + (((size_t)(b * M0 + m)) << 6);
        #pragma unroll
        for (int g = 0; g < 4; g++){
          atomicAdd(&orow[g * 16 + col], (i == 0) ? acc0[g][q] : acc1[g][q]);
        }
      }
    }
  }
}

// ============ slice + bias + transpose to [b][o][n], 16-row tiles =========
__global__ void k_slice(const float* __restrict__ bary_pv, const int* __restrict__ idx_pv,
                        const float* __restrict__ out_lat, const float* __restrict__ bias,
                        const float* __restrict__ bmul, float* __restrict__ out){
  __shared__ float tile[16][65];
  int b = blockIdx.x >> 6, n0 = (blockIdx.x & 63) * 16;
  int tid = threadIdx.x;
  int wave = tid >> 6, o = tid & 63;
  float bo = bias[o];
  #pragma unroll
  for (int i = 0; i < 4; i++){
    int n = wave * 4 + i;
    int p = (b << 10) + n0 + n;
    float acc = bo * bmul[n0 + n];
    int base = p * NVERT;
    #pragma unroll
    for (int kk = 0; kk < NVERT; kk++){
      int u = idx_pv[base + kk];
      acc += bary_pv[base + kk] * out_lat[(((size_t)(b * M0 + u)) << 6) + o];
    }
    tile[n][o] = acc;
  }
  __syncthreads();
  int nl = tid & 15;
  #pragma unroll
  for (int i = 0; i < 4; i++){
    int o2 = (tid >> 4) + i * 16;
    out[(((size_t)b * 64 + o2) << 10) + n0 + nl] = tile[nl][o2];
  }
}

extern "C" void kernel_launch(void* const* d_in, const int* in_sizes, int n_in,
                              void* d_out, int out_size, void* d_ws, size_t ws_size,
                              hipStream_t stream){
  const float* data = (const float*)d_in[0];
  const float* feat = (const float*)d_in[1];
  const float* wk   = (const float*)d_in[2];
  const float* bias = (const float*)d_in[3];
  const float* bmul = (const float*)d_in[4];
  float* out = (float*)d_out;

  char* ws = (char*)d_ws;
  size_t off = 0;
  auto alloc = [&](size_t bytes){
    void* p = ws + off;
    off = (off + bytes + 255) & ~(size_t)255;
    return p;
  };
  int*   codes_pv = (int*)  alloc((size_t)BATCH * M0 * 4);
  float* bary_pv  = (float*)alloc((size_t)BATCH * M0 * 4);
  int*   idx_pv   = (int*)  alloc((size_t)BATCH * M0 * 4);
  int*   hash_code= (int*)  alloc((size_t)BATCH * CAP * 4);
  int*   hash_uid = (int*)  alloc((size_t)BATCH * CAP * 4);
  int*   ucount   = (int*)  alloc(256);
  int*   ukeys    = (int*)  alloc((size_t)BATCH * M0 * DD * 4);
  float* table    = (float*)alloc((size_t)BATCH * M0 * CIN * 4);
  float* out_lat  = (float*)alloc((size_t)BATCH * M0 * COUT * 4);
  unsigned short* bpf      = (unsigned short*)alloc((size_t)COUT * KTOT * 2);
  unsigned short* table_bf = (unsigned short*)alloc(((size_t)BATCH * M0 + 8) * CIN * 2);
  float* dat_t    = (float*)alloc((size_t)BATCH * NPTS * CIN * 4);
  int*   nuid     = (int*)  alloc((size_t)BATCH * M0 * 32 * 4);

  k_a     <<<1024, 256, 0, stream>>>(wk, data, feat, hash_code, hash_uid, ucount,
                                     (float4*)table, (float4*)out_lat, bpf, dat_t,
                                     codes_pv, bary_pv);
  k_insert<<<BATCH * M0 / 256, 256, 0, stream>>>(codes_pv, hash_code, hash_uid, ucount, ukeys);
  k_sn    <<<BATCH * NPTS / 4 + BATCH * M0 * 32 / 256, 256, 0, stream>>>(
            dat_t, codes_pv, bary_pv, hash_code, hash_uid, ucount, ukeys,
            idx_pv, table, nuid);
  k_tobf  <<<BATCH * M0 * CIN / 8 / 256, 256, 0, stream>>>(table, ucount, table_bf);
  k_conv  <<<BATCH * 160, 512, 0, stream>>>(ucount, nuid, table_bf, bpf, out_lat);
  k_slice <<<BATCH * 64, 256, 0, stream>>>(bary_pv, idx_pv, out_lat, bias, bmul, out);
}

// Round 18
// 42.265 us; speedup vs baseline: 5.1477x; 1.0182x over previous
//
#include <hip/hip_runtime.h>
#include <hip/hip_bf16.h>
#include <stdint.h>

#define DD 4
#define NVERT 5
#define NPTS 1024
#define BATCH 4
#define M0 5120           /* NPTS*NVERT */
#define CIN 64
#define COUT 64
#define NF 31
#define KTOT 1984         /* NF*CIN */
#define CAP 16384
#define CAPMASK (CAP-1)
#define SENTV 1073741824  /* 2^30, > any valid code (<128^4) */
#define ZROW (BATCH*M0)   /* zero row index in table_bf */

using bf16x8 = __attribute__((ext_vector_type(8))) short;
using f32x4  = __attribute__((ext_vector_type(4))) float;

__device__ __forceinline__ unsigned short f2bf(float x){
  unsigned int u = __float_as_uint(x);
  u = (u + 0x7FFFu + ((u >> 16) & 1u)) >> 16;
  return (unsigned short)u;
}

__device__ __forceinline__ uint32_t hslot(int code){
  return (((uint32_t)code * 2654435761u) >> 18) & CAPMASK;
}

// ---- shared simplex math ----
__device__ __forceinline__ void pv_math(const float* feat, int g, int* code_out, float* bary_out){
  int p = g / NVERT, kk = g % NVERT;
  int b = p >> 10, n = p & 1023;
  const float* fb = feat + (size_t)b * DD * NPTS + n;
  float f0 = fb[0], f1 = fb[NPTS], f2 = fb[2 * NPTS], f3 = fb[3 * NPTS];

  float elev[5];
  elev[0] =  f0 * 2.886751345948129f  + f1 * 1.6666666666666667f + f2 * 1.1785113019775793f + f3 * 0.9128709291752769f;
  elev[1] = -f0 * 2.886751345948129f  + f1 * 1.6666666666666667f + f2 * 1.1785113019775793f + f3 * 0.9128709291752769f;
  elev[2] =  f1 * -3.3333333333333335f + f2 * 1.1785113019775793f + f3 * 0.9128709291752769f;
  elev[3] =  f2 * -3.535533905932738f  + f3 * 0.9128709291752769f;
  elev[4] =  f3 * -3.6514837167011076f;

  int gi[5]; float diff[5]; int sum = 0;
  #pragma unroll
  for (int i = 0; i < 5; i++){
    float gg = rintf(elev[i] * 0.2f) * 5.0f;
    gi[i] = (int)rintf(gg);
    sum += gi[i];
    diff[i] = elev[i] - gg;
  }
  int s = sum / 5;

  int rank[5];
  #pragma unroll
  for (int i = 0; i < 5; i++){
    int r = 0;
    #pragma unroll
    for (int j = 0; j < 5; j++)
      r += (diff[j] > diff[i]) || (diff[j] == diff[i] && j < i);
    rank[i] = r + s;
  }
  #pragma unroll
  for (int i = 0; i < 5; i++){
    if (rank[i] < 0)      { rank[i] += NVERT; gi[i] += NVERT; }
    else if (rank[i] > DD){ rank[i] -= NVERT; gi[i] -= NVERT; }
  }

  float bary[6] = {0.f,0.f,0.f,0.f,0.f,0.f};
  #pragma unroll
  for (int i = 0; i < 5; i++){
    float tt = (elev[i] - (float)gi[i]) * 0.2f;
    bary[DD - rank[i]]    += tt;
    bary[NVERT - rank[i]] += 1.0f - tt;
  }
  bary[0] += 1.0f + bary[5];

  float bk = bary[0];
  #pragma unroll
  for (int i = 1; i < 5; i++) if (i == kk) bk = bary[i];

  int code = 0;
  #pragma unroll
  for (int j = 0; j < DD; j++){
    int add = (rank[j] >= NVERT - kk) ? (kk - NVERT) : kk;
    int key = gi[j] + add;
    key = min(63, max(-64, key));
    code += (key + 64) << (7 * j);
  }
  *code_out = code;
  *bary_out = bk;
}

// ============ A: init + bpf + dat_t + pmath (disjoint block ranges) =======
__global__ void k_a(const float* __restrict__ wk, const float* __restrict__ data,
                    const float* __restrict__ feat,
                    int* __restrict__ hc, int* __restrict__ hu, int* __restrict__ uc,
                    float4* __restrict__ table4, float4* __restrict__ outlat4,
                    unsigned short* __restrict__ bpf, float* __restrict__ dat_t,
                    int* __restrict__ codes_pv, float* __restrict__ bary_pv){
  int bid = blockIdx.x, tid = threadIdx.x;
  if (bid < 64){
    __shared__ float tile[64][65];
    int b = bid >> 4, n0 = (bid & 15) * 64;
    int nl = tid & 63;
    #pragma unroll
    for (int i = 0; i < 16; i++){
      int c = (tid >> 6) * 16 + i;
      tile[c][nl] = data[(((size_t)b * 64 + c) << 10) + n0 + nl];
    }
    __syncthreads();
    #pragma unroll
    for (int i = 0; i < 16; i++){
      int nn = (tid >> 6) * 16 + i;
      dat_t[(((size_t)b << 10) + n0 + nn) * 64 + (tid & 63)] = tile[tid & 63][nn];
    }
  } else if (bid < 144){
    int g = (bid - 64) * 256 + tid;
    int code; float bk;
    pv_math(feat, g, &code, &bk);
    codes_pv[g] = code;
    bary_pv[g]  = bk;
  } else if (bid < 640){
    // weights -> fragment-ordered bpf
    int e = (bid - 144) * 256 + tid;
    int frag = e >> 9, l = (e >> 3) & 63, j = e & 7;
    int f = frag >> 3, h = (frag >> 2) & 1, g = frag & 3;
    int col = g * 16 + (l & 15);
    int c = h * 32 + ((l >> 4) << 3) + j;
    bpf[e] = f2bf(wk[(col * CIN + c) * NF + f]);
  } else {
    int g = (bid - 640) * 256 + tid;
    int stride = 384 * 256;
    for (int i = g; i < BATCH * CAP; i += stride){ hc[i] = SENTV; hu[i] = -1; }
    if (g < BATCH) uc[g] = 0;
    float4 z = {0.f,0.f,0.f,0.f};
    for (int i = g; i < BATCH * M0 * CIN / 4; i += stride) table4[i] = z;
    for (int i = g; i < BATCH * M0 * COUT / 4; i += stride) outlat4[i] = z;
  }
}

// ============ insert: LDS dedupe + global CAS + wave-aggregated uid =======
__global__ void k_insert(const int* __restrict__ codes_pv,
                         int* __restrict__ hash_code, int* __restrict__ hash_uid,
                         int* __restrict__ ucount, int* __restrict__ ukeys){
  __shared__ int lhash[512];
  int tid = threadIdx.x;
  lhash[tid] = SENTV; lhash[tid + 256] = SENTV;
  __syncthreads();

  int g = blockIdx.x * 256 + tid;
  int b = g / M0;
  int code = codes_pv[g];

  uint32_t lh = (((uint32_t)code * 2654435761u) >> 21) & 511;
  bool rep = false;
  while (true){
    int prev = atomicCAS(&lhash[lh], SENTV, code);
    if (prev == SENTV){ rep = true; break; }
    if (prev == code) break;
    lh = (lh + 1) & 511;
  }

  int myslot = -1;
  if (rep){
    int* hc = hash_code + b * CAP;
    uint32_t h = hslot(code);
    while (true){
      int prev = atomicCAS(&hc[h], SENTV, code);
      if (prev == SENTV){ myslot = (int)h; break; }
      if (prev == code) break;
      h = (h + 1) & CAPMASK;
    }
  }

  unsigned long long mask = __ballot(myslot >= 0);
  if (mask){
    int lane = tid & 63;
    int cnt = __popcll(mask);
    int leader = __ffsll((unsigned long long)mask) - 1;
    int base = 0;
    if (lane == leader) base = atomicAdd(&ucount[b], cnt);
    base = __shfl(base, leader);
    if (myslot >= 0){
      int rank = __popcll(mask & ((1ull << lane) - 1ull));
      int uid = base + rank;
      hash_uid[b * CAP + myslot] = uid;
      int* uk = ukeys + ((size_t)(b * M0 + uid)) * DD;
      #pragma unroll
      for (int j = 0; j < DD; j++) uk[j] = ((code >> (7 * j)) & 127) - 64;
    }
  }
}

// ============ fused: splat (blocks < 1024) + neighbor lookups (rest) ======
__global__ void k_sn(const float* __restrict__ dat_t, const int* __restrict__ codes_pv,
                     const float* __restrict__ bary_pv, const int* __restrict__ hash_code,
                     const int* __restrict__ hash_uid, const int* __restrict__ ucount,
                     const int* __restrict__ ukeys,
                     int* __restrict__ idx_pv, float* __restrict__ table,
                     int* __restrict__ nuid){
  int bid = blockIdx.x, tid = threadIdx.x;
  if (bid < BATCH * NPTS / 4){
    __shared__ int   us[4][8];
    __shared__ float wbs[4][8];
    int w = tid >> 6, lane = tid & 63;
    int p = bid * 4 + w;
    int b = p >> 10;
    float v = dat_t[((size_t)p << 6) + lane];
    if (lane < NVERT){
      int code = codes_pv[p * NVERT + lane];
      const int* hc = hash_code + b * CAP;
      uint32_t h = hslot(code);
      while (hc[h] != code) h = (h + 1) & CAPMASK;
      int uid = hash_uid[b * CAP + h];
      us[w][lane]  = uid;
      wbs[w][lane] = bary_pv[p * NVERT + lane];
      idx_pv[p * NVERT + lane] = uid;
    }
    __syncthreads();
    int rot = p % NVERT;
    #pragma unroll
    for (int kq = 0; kq < NVERT; kq++){
      int kk = kq + rot; if (kk >= NVERT) kk -= NVERT;
      atomicAdd(&table[(((size_t)(b * M0 + us[w][kk])) << 6) + lane], v * wbs[w][kk]);
    }
  } else {
    int e = (bid - BATCH * NPTS / 4) * 256 + tid;
    int f = e & 31;
    int idx = e >> 5;
    int b = idx / M0, m = idx - b * M0;
    int g = ZROW;
    if (f < NF && m < ucount[b]){
      const int* uk = ukeys + ((size_t)idx) * DD;
      int pc = __popc(f);
      int code = 0;
      #pragma unroll
      for (int j = 0; j < DD; j++){
        int key = uk[j] + 5 * ((f >> j) & 1) - pc;
        key = min(63, max(-64, key));
        code += (key + 64) << (7 * j);
      }
      const int* hc = hash_code + b * CAP;
      uint32_t h = hslot(code);
      while (true){
        int v = hc[h];
        if (v == code){ g = b * M0 + hash_uid[b * CAP + h]; break; }
        if (v == SENTV) break;
        h = (h + 1) & CAPMASK;
      }
    }
    nuid[e] = g;
  }
}

// ============ table fp32 -> bf16 (+ zero row), skip unused rows ===========
__global__ void k_tobf(const float* __restrict__ table, const int* __restrict__ ucount,
                       unsigned short* __restrict__ table_bf){
  int g = blockIdx.x * blockDim.x + threadIdx.x;
  if (g < 8){
    bf16x8 z = {0,0,0,0,0,0,0,0};
    *(bf16x8*)(table_bf + ((size_t)ZROW << 6) + g * 8) = z;
  }
  int row = g >> 3;
  int b = row / M0;
  if (row - b * M0 >= ucount[b]) return;   // unused rows never read by conv
  size_t base = (size_t)g * 8;
  const float4* s4 = (const float4*)(table + base);
  float4 x = s4[0], y = s4[1];
  bf16x8 v;
  v[0] = (short)f2bf(x.x); v[1] = (short)f2bf(x.y);
  v[2] = (short)f2bf(x.z); v[3] = (short)f2bf(x.w);
  v[4] = (short)f2bf(y.x); v[5] = (short)f2bf(y.y);
  v[6] = (short)f2bf(y.z); v[7] = (short)f2bf(y.w);
  *(bf16x8*)(table_bf + base) = v;
}

// ============ conv: 640 blocks, depth-2 A prefetch, slim LDS reduce =======
__launch_bounds__(512, 4)
__global__ void k_conv(const int* __restrict__ ucount, const int* __restrict__ nuid,
                       const unsigned short* __restrict__ table_bf,
                       const unsigned short* __restrict__ bpf,
                       float* __restrict__ out_lat){
  __shared__ int gidx_s[64 * 33];
  __shared__ float red[3][2][64][9];   // per-g chunk: [wk-1][wm][lane][8 vals + pad]

  int blk = blockIdx.x;
  int b    = blk / 160;          // 160 = 80 tiles * 2 halves
  int r    = blk % 160;
  int m0   = (r >> 1) * 64;
  int half = r & 1;
  if (m0 >= ucount[b]) return;

  int tid = threadIdx.x;
  {
    int base = (b * M0 + m0) << 5;
    #pragma unroll
    for (int i = 0; i < 4; i++){
      int idx = tid + i * 512;
      gidx_s[(idx >> 5) * 33 + (idx & 31)] = nuid[base + idx];
    }
  }
  __syncthreads();

  int lane = tid & 63, wave = tid >> 6;
  int wm = wave & 1, wk = wave >> 1;        // wk in 0..3
  int arow = wm * 32 + (lane & 15);
  int acol = (lane >> 4) * 8;
  const unsigned short* bf_lane = bpf + ((size_t)lane << 3);

  f32x4 acc0[4], acc1[4];
  #pragma unroll
  for (int g = 0; g < 4; g++){
    acc0[g] = (f32x4){0.f,0.f,0.f,0.f};
    acc1[g] = (f32x4){0.f,0.f,0.f,0.f};
  }

  const int kfsA[2][5] = {{0,4,8,12,16},{16,20,24,28,31}};
  int f0 = kfsA[half][wk], f1 = kfsA[half][wk + 1], flast = f1 - 1;

  #define LOADA(P00,P01,P10,P11,FF) {                                                   \
    const unsigned short* _r0 = table_bf + (((size_t)gidx_s[arow * 33 + (FF)]) << 6) + acol;        \
    const unsigned short* _r1 = table_bf + (((size_t)gidx_s[(arow + 16) * 33 + (FF)]) << 6) + acol; \
    P00 = *(const bf16x8*)(_r0);       P01 = *(const bf16x8*)(_r0 + 32);                \
    P10 = *(const bf16x8*)(_r1);       P11 = *(const bf16x8*)(_r1 + 32); }

  #define DOMFMA(C00,C01,C10,C11,FF) {                                                  \
    int _fr = (FF) << 3;                                                                \
    _Pragma("unroll")                                                                   \
    for (int g = 0; g < 4; g++){                                                        \
      bf16x8 B0 = *(const bf16x8*)(bf_lane + ((size_t)(_fr + g)     << 9));             \
      bf16x8 B1 = *(const bf16x8*)(bf_lane + ((size_t)(_fr + 4 + g) << 9));             \
      acc0[g] = __builtin_amdgcn_mfma_f32_16x16x32_bf16(C00, B0, acc0[g], 0, 0, 0);     \
      acc0[g] = __builtin_amdgcn_mfma_f32_16x16x32_bf16(C01, B1, acc0[g], 0, 0, 0);     \
      acc1[g] = __builtin_amdgcn_mfma_f32_16x16x32_bf16(C10, B0, acc1[g], 0, 0, 0);     \
      acc1[g] = __builtin_amdgcn_mfma_f32_16x16x32_bf16(C11, B1, acc1[g], 0, 0, 0); } }

  // depth-2 prefetch: P holds data for f, Q for f+1 (named regs, rule #20)
  bf16x8 P00, P01, P10, P11, Q00, Q01, Q10, Q11;
  LOADA(P00, P01, P10, P11, f0);
  {
    int fq = f0 + 1 > flast ? flast : f0 + 1;
    LOADA(Q00, Q01, Q10, Q11, fq);
  }

  for (int f = f0; f < f1; f += 2){
    // iter A: consume P, refill P <- f+2 (clamped)
    {
      bf16x8 c00 = P00, c01 = P01, c10 = P10, c11 = P11;
      int fp = f + 2 > flast ? flast : f + 2;
      LOADA(P00, P01, P10, P11, fp);
      DOMFMA(c00, c01, c10, c11, f);
    }
    // iter B: consume Q, refill Q <- f+3 (clamped); wave-uniform guard
    if (f + 1 < f1){
      bf16x8 c00 = Q00, c01 = Q01, c10 = Q10, c11 = Q11;
      int fq = f + 3 > flast ? flast : f + 3;
      LOADA(Q00, Q01, Q10, Q11, fq);
      DOMFMA(c00, c01, c10, c11, f + 1);
    }
  }
  #undef LOADA
  #undef DOMFMA

  // chunked LDS reduction across wk (one g at a time, slim buffer)
  #pragma unroll
  for (int g = 0; g < 4; g++){
    if (wk > 0){
      #pragma unroll
      for (int q = 0; q < 4; q++){
        red[wk - 1][wm][lane][q]     = acc0[g][q];
        red[wk - 1][wm][lane][4 + q] = acc1[g][q];
      }
    }
    __syncthreads();
    if (wk == 0){
      #pragma unroll
      for (int rr = 0; rr < 3; rr++){
        #pragma unroll
        for (int q = 0; q < 4; q++){
          acc0[g][q] += red[rr][wm][lane][q];
          acc1[g][q] += red[rr][wm][lane][4 + q];
        }
      }
    }
    __syncthreads();
  }

  // wk0-only atomic epilogue: one add per output per half-block
  // C/D layout: col = lane&15, row = (lane>>4)*4 + q (m89-verified)
  if (wk == 0){
    int q4 = (lane >> 4) * 4, col = lane & 15;
    #pragma unroll
    for (int i = 0; i < 2; i++){
      #pragma unroll
      for (int q = 0; q < 4; q++){
        int m = m0 + wm * 32 + i * 16 + q4 + q;
        float* orow = out_lat + (((size_t)(b * M0 + m)) << 6);
        #pragma unroll
        for (int g = 0; g < 4; g++){
          atomicAdd(&orow[g * 16 + col], (i == 0) ? acc0[g][q] : acc1[g][q]);
        }
      }
    }
  }
}

// ============ slice + bias + transpose to [b][o][n], 16-row tiles =========
__global__ void k_slice(const float* __restrict__ bary_pv, const int* __restrict__ idx_pv,
                        const float* __restrict__ out_lat, const float* __restrict__ bias,
                        const float* __restrict__ bmul, float* __restrict__ out){
  __shared__ float tile[16][65];
  int b = blockIdx.x >> 6, n0 = (blockIdx.x & 63) * 16;
  int tid = threadIdx.x;
  int wave = tid >> 6, o = tid & 63;
  float bo = bias[o];
  #pragma unroll
  for (int i = 0; i < 4; i++){
    int n = wave * 4 + i;
    int p = (b << 10) + n0 + n;
    float acc = bo * bmul[n0 + n];
    int base = p * NVERT;
    #pragma unroll
    for (int kk = 0; kk < NVERT; kk++){
      int u = idx_pv[base + kk];
      acc += bary_pv[base + kk] * out_lat[(((size_t)(b * M0 + u)) << 6) + o];
    }
    tile[n][o] = acc;
  }
  __syncthreads();
  int nl = tid & 15;
  #pragma unroll
  for (int i = 0; i < 4; i++){
    int o2 = (tid >> 4) + i * 16;
    out[(((size_t)b * 64 + o2) << 10) + n0 + nl] = tile[nl][o2];
  }
}

extern "C" void kernel_launch(void* const* d_in, const int* in_sizes, int n_in,
                              void* d_out, int out_size, void* d_ws, size_t ws_size,
                              hipStream_t stream){
  const float* data = (const float*)d_in[0];
  const float* feat = (const float*)d_in[1];
  const float* wk   = (const float*)d_in[2];
  const float* bias = (const float*)d_in[3];
  const float* bmul = (const float*)d_in[4];
  float* out = (float*)d_out;

  char* ws = (char*)d_ws;
  size_t off = 0;
  auto alloc = [&](size_t bytes){
    void* p = ws + off;
    off = (off + bytes + 255) & ~(size_t)255;
    return p;
  };
  int*   codes_pv = (int*)  alloc((size_t)BATCH * M0 * 4);
  float* bary_pv  = (float*)alloc((size_t)BATCH * M0 * 4);
  int*   idx_pv   = (int*)  alloc((size_t)BATCH * M0 * 4);
  int*   hash_code= (int*)  alloc((size_t)BATCH * CAP * 4);
  int*   hash_uid = (int*)  alloc((size_t)BATCH * CAP * 4);
  int*   ucount   = (int*)  alloc(256);
  int*   ukeys    = (int*)  alloc((size_t)BATCH * M0 * DD * 4);
  float* table    = (float*)alloc((size_t)BATCH * M0 * CIN * 4);
  float* out_lat  = (float*)alloc((size_t)BATCH * M0 * COUT * 4);
  unsigned short* bpf      = (unsigned short*)alloc((size_t)COUT * KTOT * 2);
  unsigned short* table_bf = (unsigned short*)alloc(((size_t)BATCH * M0 + 8) * CIN * 2);
  float* dat_t    = (float*)alloc((size_t)BATCH * NPTS * CIN * 4);
  int*   nuid     = (int*)  alloc((size_t)BATCH * M0 * 32 * 4);

  k_a     <<<1024, 256, 0, stream>>>(wk, data, feat, hash_code, hash_uid, ucount,
                                     (float4*)table, (float4*)out_lat, bpf, dat_t,
                                     codes_pv, bary_pv);
  k_insert<<<BATCH * M0 / 256, 256, 0, stream>>>(codes_pv, hash_code, hash_uid, ucount, ukeys);
  k_sn    <<<BATCH * NPTS / 4 + BATCH * M0 * 32 / 256, 256, 0, stream>>>(
            dat_t, codes_pv, bary_pv, hash_code, hash_uid, ucount, ukeys,
            idx_pv, table, nuid);
  k_tobf  <<<BATCH * M0 * CIN / 8 / 256, 256, 0, stream>>>(table, ucount, table_bf);
  k_conv  <<<BATCH * 160, 512, 0, stream>>>(ucount, nuid, table_bf, bpf, out_lat);
  k_slice <<<BATCH * 64, 256, 0, stream>>>(bary_pv, idx_pv, out_lat, bias, bmul, out);
}

// Round 19
// 41.894 us; speedup vs baseline: 5.1932x; 1.0089x over previous
//
#include <hip/hip_runtime.h>
#include <hip/hip_bf16.h>
#include <stdint.h>

#define DD 4
#define NVERT 5
#define NPTS 1024
#define BATCH 4
#define M0 5120           /* NPTS*NVERT */
#define CIN 64
#define COUT 64
#define NF 31
#define KTOT 1984         /* NF*CIN */
#define CAP 16384
#define CAPMASK (CAP-1)
#define SENTV 1073741824  /* 2^30, > any valid code (<128^4) */
#define ZROW (BATCH*M0)   /* zero row index in table_bf */

using bf16x8 = __attribute__((ext_vector_type(8))) short;
using f32x4  = __attribute__((ext_vector_type(4))) float;

__device__ __forceinline__ unsigned short f2bf(float x){
  unsigned int u = __float_as_uint(x);
  u = (u + 0x7FFFu + ((u >> 16) & 1u)) >> 16;
  return (unsigned short)u;
}

__device__ __forceinline__ uint32_t hslot(int code){
  return (((uint32_t)code * 2654435761u) >> 18) & CAPMASK;
}

// ---- shared simplex math ----
__device__ __forceinline__ void pv_math(const float* feat, int g, int* code_out, float* bary_out){
  int p = g / NVERT, kk = g % NVERT;
  int b = p >> 10, n = p & 1023;
  const float* fb = feat + (size_t)b * DD * NPTS + n;
  float f0 = fb[0], f1 = fb[NPTS], f2 = fb[2 * NPTS], f3 = fb[3 * NPTS];

  float elev[5];
  elev[0] =  f0 * 2.886751345948129f  + f1 * 1.6666666666666667f + f2 * 1.1785113019775793f + f3 * 0.9128709291752769f;
  elev[1] = -f0 * 2.886751345948129f  + f1 * 1.6666666666666667f + f2 * 1.1785113019775793f + f3 * 0.9128709291752769f;
  elev[2] =  f1 * -3.3333333333333335f + f2 * 1.1785113019775793f + f3 * 0.9128709291752769f;
  elev[3] =  f2 * -3.535533905932738f  + f3 * 0.9128709291752769f;
  elev[4] =  f3 * -3.6514837167011076f;

  int gi[5]; float diff[5]; int sum = 0;
  #pragma unroll
  for (int i = 0; i < 5; i++){
    float gg = rintf(elev[i] * 0.2f) * 5.0f;
    gi[i] = (int)rintf(gg);
    sum += gi[i];
    diff[i] = elev[i] - gg;
  }
  int s = sum / 5;

  int rank[5];
  #pragma unroll
  for (int i = 0; i < 5; i++){
    int r = 0;
    #pragma unroll
    for (int j = 0; j < 5; j++)
      r += (diff[j] > diff[i]) || (diff[j] == diff[i] && j < i);
    rank[i] = r + s;
  }
  #pragma unroll
  for (int i = 0; i < 5; i++){
    if (rank[i] < 0)      { rank[i] += NVERT; gi[i] += NVERT; }
    else if (rank[i] > DD){ rank[i] -= NVERT; gi[i] -= NVERT; }
  }

  float bary[6] = {0.f,0.f,0.f,0.f,0.f,0.f};
  #pragma unroll
  for (int i = 0; i < 5; i++){
    float tt = (elev[i] - (float)gi[i]) * 0.2f;
    bary[DD - rank[i]]    += tt;
    bary[NVERT - rank[i]] += 1.0f - tt;
  }
  bary[0] += 1.0f + bary[5];

  float bk = bary[0];
  #pragma unroll
  for (int i = 1; i < 5; i++) if (i == kk) bk = bary[i];

  int code = 0;
  #pragma unroll
  for (int j = 0; j < DD; j++){
    int add = (rank[j] >= NVERT - kk) ? (kk - NVERT) : kk;
    int key = gi[j] + add;
    key = min(63, max(-64, key));
    code += (key + 64) << (7 * j);
  }
  *code_out = code;
  *bary_out = bk;
}

// ============ A: init + bpf + dat_t + pmath (disjoint block ranges) =======
__global__ void k_a(const float* __restrict__ wk, const float* __restrict__ data,
                    const float* __restrict__ feat,
                    int* __restrict__ hc, int* __restrict__ hu, int* __restrict__ uc,
                    float4* __restrict__ table4, float4* __restrict__ outlat4,
                    unsigned short* __restrict__ bpf, float* __restrict__ dat_t,
                    int* __restrict__ codes_pv, float* __restrict__ bary_pv){
  int bid = blockIdx.x, tid = threadIdx.x;
  if (bid < 64){
    __shared__ float tile[64][65];
    int b = bid >> 4, n0 = (bid & 15) * 64;
    int nl = tid & 63;
    #pragma unroll
    for (int i = 0; i < 16; i++){
      int c = (tid >> 6) * 16 + i;
      tile[c][nl] = data[(((size_t)b * 64 + c) << 10) + n0 + nl];
    }
    __syncthreads();
    #pragma unroll
    for (int i = 0; i < 16; i++){
      int nn = (tid >> 6) * 16 + i;
      dat_t[(((size_t)b << 10) + n0 + nn) * 64 + (tid & 63)] = tile[tid & 63][nn];
    }
  } else if (bid < 144){
    int g = (bid - 64) * 256 + tid;
    int code; float bk;
    pv_math(feat, g, &code, &bk);
    codes_pv[g] = code;
    bary_pv[g]  = bk;
  } else if (bid < 640){
    // weights -> fragment-ordered bpf
    int e = (bid - 144) * 256 + tid;
    int frag = e >> 9, l = (e >> 3) & 63, j = e & 7;
    int f = frag >> 3, h = (frag >> 2) & 1, g = frag & 3;
    int col = g * 16 + (l & 15);
    int c = h * 32 + ((l >> 4) << 3) + j;
    bpf[e] = f2bf(wk[(col * CIN + c) * NF + f]);
  } else {
    int g = (bid - 640) * 256 + tid;
    int stride = 384 * 256;
    for (int i = g; i < BATCH * CAP; i += stride){ hc[i] = SENTV; hu[i] = -1; }
    if (g < BATCH) uc[g] = 0;
    float4 z = {0.f,0.f,0.f,0.f};
    for (int i = g; i < BATCH * M0 * CIN / 4; i += stride) table4[i] = z;
    for (int i = g; i < BATCH * M0 * COUT / 4; i += stride) outlat4[i] = z;
  }
}

// ============ insert: LDS dedupe + global CAS + wave-aggregated uid =======
__global__ void k_insert(const int* __restrict__ codes_pv,
                         int* __restrict__ hash_code, int* __restrict__ hash_uid,
                         int* __restrict__ ucount, int* __restrict__ ukeys){
  __shared__ int lhash[512];
  int tid = threadIdx.x;
  lhash[tid] = SENTV; lhash[tid + 256] = SENTV;
  __syncthreads();

  int g = blockIdx.x * 256 + tid;
  int b = g / M0;
  int code = codes_pv[g];

  uint32_t lh = (((uint32_t)code * 2654435761u) >> 21) & 511;
  bool rep = false;
  while (true){
    int prev = atomicCAS(&lhash[lh], SENTV, code);
    if (prev == SENTV){ rep = true; break; }
    if (prev == code) break;
    lh = (lh + 1) & 511;
  }

  int myslot = -1;
  if (rep){
    int* hc = hash_code + b * CAP;
    uint32_t h = hslot(code);
    while (true){
      int prev = atomicCAS(&hc[h], SENTV, code);
      if (prev == SENTV){ myslot = (int)h; break; }
      if (prev == code) break;
      h = (h + 1) & CAPMASK;
    }
  }

  unsigned long long mask = __ballot(myslot >= 0);
  if (mask){
    int lane = tid & 63;
    int cnt = __popcll(mask);
    int leader = __ffsll((unsigned long long)mask) - 1;
    int base = 0;
    if (lane == leader) base = atomicAdd(&ucount[b], cnt);
    base = __shfl(base, leader);
    if (myslot >= 0){
      int rank = __popcll(mask & ((1ull << lane) - 1ull));
      int uid = base + rank;
      hash_uid[b * CAP + myslot] = uid;
      int* uk = ukeys + ((size_t)(b * M0 + uid)) * DD;
      #pragma unroll
      for (int j = 0; j < DD; j++) uk[j] = ((code >> (7 * j)) & 127) - 64;
    }
  }
}

// ============ fused: splat (blocks < 1024) + neighbor lookups (rest) ======
__global__ void k_sn(const float* __restrict__ dat_t, const int* __restrict__ codes_pv,
                     const float* __restrict__ bary_pv, const int* __restrict__ hash_code,
                     const int* __restrict__ hash_uid, const int* __restrict__ ucount,
                     const int* __restrict__ ukeys,
                     int* __restrict__ idx_pv, float* __restrict__ table,
                     int* __restrict__ nuid){
  int bid = blockIdx.x, tid = threadIdx.x;
  if (bid < BATCH * NPTS / 4){
    __shared__ int   us[4][8];
    __shared__ float wbs[4][8];
    int w = tid >> 6, lane = tid & 63;
    int p = bid * 4 + w;
    int b = p >> 10;
    float v = dat_t[((size_t)p << 6) + lane];
    if (lane < NVERT){
      int code = codes_pv[p * NVERT + lane];
      const int* hc = hash_code + b * CAP;
      uint32_t h = hslot(code);
      while (hc[h] != code) h = (h + 1) & CAPMASK;
      int uid = hash_uid[b * CAP + h];
      us[w][lane]  = uid;
      wbs[w][lane] = bary_pv[p * NVERT + lane];
      idx_pv[p * NVERT + lane] = uid;
    }
    __syncthreads();
    int rot = p % NVERT;
    #pragma unroll
    for (int kq = 0; kq < NVERT; kq++){
      int kk = kq + rot; if (kk >= NVERT) kk -= NVERT;
      atomicAdd(&table[(((size_t)(b * M0 + us[w][kk])) << 6) + lane], v * wbs[w][kk]);
    }
  } else {
    int e = (bid - BATCH * NPTS / 4) * 256 + tid;
    int f = e & 31;
    int idx = e >> 5;
    int b = idx / M0, m = idx - b * M0;
    int g = ZROW;
    if (f < NF && m < ucount[b]){
      const int* uk = ukeys + ((size_t)idx) * DD;
      int pc = __popc(f);
      int code = 0;
      #pragma unroll
      for (int j = 0; j < DD; j++){
        int key = uk[j] + 5 * ((f >> j) & 1) - pc;
        key = min(63, max(-64, key));
        code += (key + 64) << (7 * j);
      }
      const int* hc = hash_code + b * CAP;
      uint32_t h = hslot(code);
      while (true){
        int v = hc[h];
        if (v == code){ g = b * M0 + hash_uid[b * CAP + h]; break; }
        if (v == SENTV) break;
        h = (h + 1) & CAPMASK;
      }
    }
    nuid[e] = g;
  }
}

// ============ table fp32 -> bf16 (+ zero row), skip unused rows ===========
__global__ void k_tobf(const float* __restrict__ table, const int* __restrict__ ucount,
                       unsigned short* __restrict__ table_bf){
  int g = blockIdx.x * blockDim.x + threadIdx.x;
  if (g < 8){
    bf16x8 z = {0,0,0,0,0,0,0,0};
    *(bf16x8*)(table_bf + ((size_t)ZROW << 6) + g * 8) = z;
  }
  int row = g >> 3;
  int b = row / M0;
  if (row - b * M0 >= ucount[b]) return;   // unused rows never read by conv
  size_t base = (size_t)g * 8;
  const float4* s4 = (const float4*)(table + base);
  float4 x = s4[0], y = s4[1];
  bf16x8 v;
  v[0] = (short)f2bf(x.x); v[1] = (short)f2bf(x.y);
  v[2] = (short)f2bf(x.z); v[3] = (short)f2bf(x.w);
  v[4] = (short)f2bf(y.x); v[5] = (short)f2bf(y.y);
  v[6] = (short)f2bf(y.z); v[7] = (short)f2bf(y.w);
  *(bf16x8*)(table_bf + base) = v;
}

// ============ conv: 640 blocks, 8-way f-split (64 rows/wave), B dedup'd ===
__launch_bounds__(512, 4)
__global__ void k_conv(const int* __restrict__ ucount, const int* __restrict__ nuid,
                       const unsigned short* __restrict__ table_bf,
                       const unsigned short* __restrict__ bpf,
                       float* __restrict__ out_lat){
  __shared__ int gidx_s[64 * 33];
  __shared__ float red[7][64][17];   // per-rg chunk: [wave-1][lane][16 vals + pad]

  int blk = blockIdx.x;
  int b    = blk / 160;          // 160 = 80 tiles * 2 halves
  int r    = blk % 160;
  int m0   = (r >> 1) * 64;
  int half = r & 1;
  if (m0 >= ucount[b]) return;

  int tid = threadIdx.x;
  {
    int base = (b * M0 + m0) << 5;
    #pragma unroll
    for (int i = 0; i < 4; i++){
      int idx = tid + i * 512;
      gidx_s[(idx >> 5) * 33 + (idx & 31)] = nuid[base + idx];
    }
  }
  __syncthreads();

  int lane = tid & 63, wave = tid >> 6;   // wave 0..7 owns 2 f-values
  int rl = lane & 15;
  int acol = (lane >> 4) * 8;
  const unsigned short* bf_lane = bpf + ((size_t)lane << 3);

  f32x4 acc[4][4];                         // [row-group][g], 64 VGPRs
  #pragma unroll
  for (int rg = 0; rg < 4; rg++)
    #pragma unroll
    for (int g = 0; g < 4; g++)
      acc[rg][g] = (f32x4){0.f,0.f,0.f,0.f};

  int f0 = half * 16 + wave * 2;
  int f1 = f0 + 2; if (f1 > NF) f1 = NF;   // half-1 wave-7: single f=30

  for (int f = f0; f < f1; f++){
    // A: all 4 row-groups x both 32-col halves (8 independent gathers)
    bf16x8 A0_0, A0_1, A1_0, A1_1, A2_0, A2_1, A3_0, A3_1;
    {
      const unsigned short* p0 = table_bf + (((size_t)gidx_s[(rl     ) * 33 + f]) << 6) + acol;
      const unsigned short* p1 = table_bf + (((size_t)gidx_s[(rl + 16) * 33 + f]) << 6) + acol;
      const unsigned short* p2 = table_bf + (((size_t)gidx_s[(rl + 32) * 33 + f]) << 6) + acol;
      const unsigned short* p3 = table_bf + (((size_t)gidx_s[(rl + 48) * 33 + f]) << 6) + acol;
      A0_0 = *(const bf16x8*)(p0); A0_1 = *(const bf16x8*)(p0 + 32);
      A1_0 = *(const bf16x8*)(p1); A1_1 = *(const bf16x8*)(p1 + 32);
      A2_0 = *(const bf16x8*)(p2); A2_1 = *(const bf16x8*)(p2 + 32);
      A3_0 = *(const bf16x8*)(p3); A3_1 = *(const bf16x8*)(p3 + 32);
    }
    int fr = f << 3;
    #pragma unroll
    for (int g = 0; g < 4; g++){
      bf16x8 B0 = *(const bf16x8*)(bf_lane + ((size_t)(fr + g)     << 9));  // h=0
      bf16x8 B1 = *(const bf16x8*)(bf_lane + ((size_t)(fr + 4 + g) << 9));  // h=1
      acc[0][g] = __builtin_amdgcn_mfma_f32_16x16x32_bf16(A0_0, B0, acc[0][g], 0, 0, 0);
      acc[0][g] = __builtin_amdgcn_mfma_f32_16x16x32_bf16(A0_1, B1, acc[0][g], 0, 0, 0);
      acc[1][g] = __builtin_amdgcn_mfma_f32_16x16x32_bf16(A1_0, B0, acc[1][g], 0, 0, 0);
      acc[1][g] = __builtin_amdgcn_mfma_f32_16x16x32_bf16(A1_1, B1, acc[1][g], 0, 0, 0);
      acc[2][g] = __builtin_amdgcn_mfma_f32_16x16x32_bf16(A2_0, B0, acc[2][g], 0, 0, 0);
      acc[2][g] = __builtin_amdgcn_mfma_f32_16x16x32_bf16(A2_1, B1, acc[2][g], 0, 0, 0);
      acc[3][g] = __builtin_amdgcn_mfma_f32_16x16x32_bf16(A3_0, B0, acc[3][g], 0, 0, 0);
      acc[3][g] = __builtin_amdgcn_mfma_f32_16x16x32_bf16(A3_1, B1, acc[3][g], 0, 0, 0);
    }
  }

  // chunked LDS reduction across the 8 waves (one row-group at a time)
  #pragma unroll
  for (int rg = 0; rg < 4; rg++){
    if (wave > 0){
      #pragma unroll
      for (int g = 0; g < 4; g++)
        #pragma unroll
        for (int q = 0; q < 4; q++)
          red[wave - 1][lane][g * 4 + q] = acc[rg][g][q];
    }
    __syncthreads();
    if (wave == 0){
      #pragma unroll
      for (int w = 0; w < 7; w++)
        #pragma unroll
        for (int g = 0; g < 4; g++)
          #pragma unroll
          for (int q = 0; q < 4; q++)
            acc[rg][g][q] += red[w][lane][g * 4 + q];
    }
    __syncthreads();
  }

  // wave0-only atomic epilogue: one add per output per half-block
  // C/D layout: col = lane&15, row = (lane>>4)*4 + q (m89-verified)
  if (wave == 0){
    int q4 = (lane >> 4) * 4, col = lane & 15;
    #pragma unroll
    for (int rg = 0; rg < 4; rg++){
      #pragma unroll
      for (int q = 0; q < 4; q++){
        int m = m0 + rg * 16 + q4 + q;
        float* orow = out_lat + (((size_t)(b * M0 + m)) << 6);
        #pragma unroll
        for (int g = 0; g < 4; g++){
          atomicAdd(&orow[g * 16 + col], acc[rg][g][q]);
        }
      }
    }
  }
}

// ============ slice + bias + transpose to [b][o][n], 16-row tiles =========
__global__ void k_slice(const float* __restrict__ bary_pv, const int* __restrict__ idx_pv,
                        const float* __restrict__ out_lat, const float* __restrict__ bias,
                        const float* __restrict__ bmul, float* __restrict__ out){
  __shared__ float tile[16][65];
  int b = blockIdx.x >> 6, n0 = (blockIdx.x & 63) * 16;
  int tid = threadIdx.x;
  int wave = tid >> 6, o = tid & 63;
  float bo = bias[o];
  #pragma unroll
  for (int i = 0; i < 4; i++){
    int n = wave * 4 + i;
    int p = (b << 10) + n0 + n;
    float acc = bo * bmul[n0 + n];
    int base = p * NVERT;
    #pragma unroll
    for (int kk = 0; kk < NVERT; kk++){
      int u = idx_pv[base + kk];
      acc += bary_pv[base + kk] * out_lat[(((size_t)(b * M0 + u)) << 6) + o];
    }
    tile[n][o] = acc;
  }
  __syncthreads();
  int nl = tid & 15;
  #pragma unroll
  for (int i = 0; i < 4; i++){
    int o2 = (tid >> 4) + i * 16;
    out[(((size_t)b * 64 + o2) << 10) + n0 + nl] = tile[nl][o2];
  }
}

extern "C" void kernel_launch(void* const* d_in, const int* in_sizes, int n_in,
                              void* d_out, int out_size, void* d_ws, size_t ws_size,
                              hipStream_t stream){
  const float* data = (const float*)d_in[0];
  const float* feat = (const float*)d_in[1];
  const float* wk   = (const float*)d_in[2];
  const float* bias = (const float*)d_in[3];
  const float* bmul = (const float*)d_in[4];
  float* out = (float*)d_out;

  char* ws = (char*)d_ws;
  size_t off = 0;
  auto alloc = [&](size_t bytes){
    void* p = ws + off;
    off = (off + bytes + 255) & ~(size_t)255;
    return p;
  };
  int*   codes_pv = (int*)  alloc((size_t)BATCH * M0 * 4);
  float* bary_pv  = (float*)alloc((size_t)BATCH * M0 * 4);
  int*   idx_pv   = (int*)  alloc((size_t)BATCH * M0 * 4);
  int*   hash_code= (int*)  alloc((size_t)BATCH * CAP * 4);
  int*   hash_uid = (int*)  alloc((size_t)BATCH * CAP * 4);
  int*   ucount   = (int*)  alloc(256);
  int*   ukeys    = (int*)  alloc((size_t)BATCH * M0 * DD * 4);
  float* table    = (float*)alloc((size_t)BATCH * M0 * CIN * 4);
  float* out_lat  = (float*)alloc((size_t)BATCH * M0 * COUT * 4);
  unsigned short* bpf      = (unsigned short*)alloc((size_t)COUT * KTOT * 2);
  unsigned short* table_bf = (unsigned short*)alloc(((size_t)BATCH * M0 + 8) * CIN * 2);
  float* dat_t    = (float*)alloc((size_t)BATCH * NPTS * CIN * 4);
  int*   nuid     = (int*)  alloc((size_t)BATCH * M0 * 32 * 4);

  k_a     <<<1024, 256, 0, stream>>>(wk, data, feat, hash_code, hash_uid, ucount,
                                     (float4*)table, (float4*)out_lat, bpf, dat_t,
                                     codes_pv, bary_pv);
  k_insert<<<BATCH * M0 / 256, 256, 0, stream>>>(codes_pv, hash_code, hash_uid, ucount, ukeys);
  k_sn    <<<BATCH * NPTS / 4 + BATCH * M0 * 32 / 256, 256, 0, stream>>>(
            dat_t, codes_pv, bary_pv, hash_code, hash_uid, ucount, ukeys,
            idx_pv, table, nuid);
  k_tobf  <<<BATCH * M0 * CIN / 8 / 256, 256, 0, stream>>>(table, ucount, table_bf);
  k_conv  <<<BATCH * 160, 512, 0, stream>>>(ucount, nuid, table_bf, bpf, out_lat);
  k_slice <<<BATCH * 64, 256, 0, stream>>>(bary_pv, idx_pv, out_lat, bias, bmul, out);
}